// Round 1
// baseline (1970.150 us; speedup 1.0000x reference)
//
#include <hip/hip_runtime.h>
#include <hip/hip_bf16.h>

// Problem dims
// x:    (2,256,64,64)   skip: (2,128,128,128)
// w_up: (256,128,2,2)   w_ref:(128,256,3,3)   w_offh:(18,128,1,15)
// w_offv:(18,128,15,1)  w_mask:(9,128,3,3)    w_def:(128,128,3,3)
// out:  (2,128,128,128) fp32

// ---------------- K1: transposed-conv 2x2 s2 (writes cat channels 0..127) ----
__global__ void k_upsample(const float* __restrict__ x, const float* __restrict__ w_up,
                           const float* __restrict__ b_up, float* __restrict__ cat) {
  int bid = blockIdx.x;            // 2 * 64 * 8 = 1024
  int wt = bid & 7;
  int hh = (bid >> 3) & 63;
  int b  = bid >> 9;
  int t = threadIdx.x;
  __shared__ float xs[256][8];
  int ww0 = wt * 8;
  int pix = t & 7, icb = t >> 3;
  #pragma unroll
  for (int r = 0; r < 8; ++r) {
    int ic = r * 32 + icb;
    xs[ic][pix] = x[((b * 256 + ic) * 64 + hh) * 64 + ww0 + pix];
  }
  __syncthreads();
  int oc = t & 127, g = t >> 7;    // g = kh
  float bias = b_up[oc];
  float acc0[8], acc1[8];
  #pragma unroll
  for (int p = 0; p < 8; ++p) { acc0[p] = bias; acc1[p] = bias; }
  for (int i = 0; i < 256; ++i) {
    float wv0 = w_up[((i * 128 + oc) * 2 + g) * 2 + 0];
    float wv1 = w_up[((i * 128 + oc) * 2 + g) * 2 + 1];
    #pragma unroll
    for (int p = 0; p < 8; ++p) {
      float xv = xs[i][p];
      acc0[p] += xv * wv0;
      acc1[p] += xv * wv1;
    }
  }
  int h = 2 * hh + g;
  long base = ((long)(b * 256 + oc) * 128 + h) * 128;
  #pragma unroll
  for (int p = 0; p < 8; ++p) {
    int w0c = 2 * (ww0 + p);
    cat[base + w0c]     = acc0[p];
    cat[base + w0c + 1] = acc1[p];
  }
}

// ---------------- K1b: copy skip into cat channels 128..255 -----------------
__global__ void k_skipcopy(const float4* __restrict__ skip, float4* __restrict__ cat) {
  int i = blockIdx.x * 256 + threadIdx.x;  // over 1,048,576 float4
  if (i < 1048576) {
    int b = i >> 19;                        // 524288 float4 per batch of skip
    cat[i + ((b + 1) << 19)] = skip[i];
  }
}

// ---------------- K2: 3x3 conv 256->128, pad 1 ------------------------------
__global__ void k_conv3(const float* __restrict__ cat, const float* __restrict__ wr,
                        const float* __restrict__ br, float* __restrict__ out) {
  int bid = blockIdx.x;            // 2 * 16 * 16 = 512
  int ocg  = bid & 15;
  int tile = (bid >> 4) & 15;
  int b    = bid >> 8;
  int ty0 = (tile >> 2) * 32, tx0 = (tile & 3) * 32;
  int oc0 = ocg * 8;
  int t = threadIdx.x;
  int tx = t & 15, ty = t >> 4;
  __shared__ __align__(16) float ts[34][36];
  __shared__ __align__(16) float wsm[8][12];
  float acc[8][4];
  #pragma unroll
  for (int o = 0; o < 8; ++o)
    #pragma unroll
    for (int p = 0; p < 4; ++p) acc[o][p] = 0.f;
  const float* srcbase = cat + ((long)(b * 256) << 14);
  for (int ic = 0; ic < 256; ++ic) {
    const float* src = srcbase + ((long)ic << 14);
    __syncthreads();
    for (int idx = t; idx < 1156; idx += 256) {
      int r = idx / 34, c = idx - r * 34;
      int gy = ty0 + r - 1, gx = tx0 + c - 1;
      float v = 0.f;
      if ((unsigned)gy < 128u && (unsigned)gx < 128u) v = src[(gy << 7) + gx];
      ts[r][c] = v;
    }
    if (t < 72) { int o = t / 9, k = t - o * 9; wsm[o][k] = wr[((oc0 + o) * 256 + ic) * 9 + k]; }
    __syncthreads();
    float v[16];
    #pragma unroll
    for (int dy = 0; dy < 4; ++dy)
      #pragma unroll
      for (int dx = 0; dx < 4; ++dx)
        v[dy * 4 + dx] = ts[ty * 2 + dy][tx * 2 + dx];
    #pragma unroll
    for (int o = 0; o < 8; ++o) {
      float4 wa = *(const float4*)&wsm[o][0];
      float4 wb = *(const float4*)&wsm[o][4];
      float wc9 = wsm[o][8];
      #pragma unroll
      for (int oy = 0; oy < 2; ++oy)
        #pragma unroll
        for (int ox = 0; ox < 2; ++ox) {
          acc[o][oy * 2 + ox] +=
              wa.x * v[(oy+0)*4+ox+0] + wa.y * v[(oy+0)*4+ox+1] + wa.z * v[(oy+0)*4+ox+2]
            + wa.w * v[(oy+1)*4+ox+0] + wb.x * v[(oy+1)*4+ox+1] + wb.y * v[(oy+1)*4+ox+2]
            + wb.z * v[(oy+2)*4+ox+0] + wb.w * v[(oy+2)*4+ox+1] + wc9  * v[(oy+2)*4+ox+2];
        }
    }
  }
  int py = ty0 + ty * 2, px = tx0 + tx * 2;
  #pragma unroll
  for (int o = 0; o < 8; ++o) {
    float bias = br[oc0 + o];
    long obase = (((long)(b * 128 + oc0 + o) << 7) + py) * 128 + px;
    out[obase]       = acc[o][0] + bias;
    out[obase + 1]   = acc[o][1] + bias;
    out[obase + 128] = acc[o][2] + bias;
    out[obase + 129] = acc[o][3] + bias;
  }
}

// ---------------- K3/K7: per-channel batch-norm stats -----------------------
__global__ void k_bnstats(const float* __restrict__ src, float* __restrict__ mean,
                          float* __restrict__ rstd) {
  int c = blockIdx.x, t = threadIdx.x;
  float s = 0.f, s2 = 0.f;
  for (int b = 0; b < 2; ++b) {
    const float4* p4 = (const float4*)(src + ((long)(b * 128 + c) << 14));
    for (int i = t; i < 4096; i += 256) {
      float4 v = p4[i];
      s  += v.x + v.y + v.z + v.w;
      s2 += v.x * v.x + v.y * v.y + v.z * v.z + v.w * v.w;
    }
  }
  #pragma unroll
  for (int off = 32; off; off >>= 1) {
    s  += __shfl_down(s, off);
    s2 += __shfl_down(s2, off);
  }
  __shared__ float as[4], as2[4];
  int wid = t >> 6;
  if ((t & 63) == 0) { as[wid] = s; as2[wid] = s2; }
  __syncthreads();
  if (t == 0) {
    float S = as[0] + as[1] + as[2] + as[3];
    float S2 = as2[0] + as2[1] + as2[2] + as2[3];
    float m = S / 32768.f;
    float var = S2 / 32768.f - m * m;
    mean[c] = m;
    rstd[c] = rsqrtf(var + 1e-5f);
  }
}

// ---------------- K4/K8: normalize + affine + relu --------------------------
__global__ void k_bnrelu(const float4* __restrict__ src, const float* __restrict__ mean,
                         const float* __restrict__ rstd, const float* __restrict__ g,
                         const float* __restrict__ be, float4* __restrict__ dst) {
  int i = blockIdx.x * 256 + threadIdx.x;   // over 1,048,576 float4
  if (i >= 1048576) return;
  int c = (i >> 12) & 127;
  float sc = rstd[c] * g[c];
  float bb = be[c] - mean[c] * sc;
  float4 v = src[i];
  v.x = fmaxf(v.x * sc + bb, 0.f);
  v.y = fmaxf(v.y * sc + bb, 0.f);
  v.z = fmaxf(v.z * sc + bb, 0.f);
  v.w = fmaxf(v.w * sc + bb, 0.f);
  dst[i] = v;
}

// ---------------- K5: offset (1x15 + 15x1) and mask (3x3, sigmoid) ----------
__global__ void k_offmask(const float* __restrict__ hb,
                          const float* __restrict__ wh, const float* __restrict__ bh,
                          const float* __restrict__ wv, const float* __restrict__ bv,
                          const float* __restrict__ wm, const float* __restrict__ bm,
                          float* __restrict__ off, float* __restrict__ msk) {
  int bid = blockIdx.x;            // 2 * 128 = 256
  int b = bid >> 7, h = bid & 127;
  int t = threadIdx.x;
  int w = t & 127, par = t >> 7;
  __shared__ float smem[4320];
  float* strip = smem + par * 2160;   // [15][144]
  float accH[18], accV[18], accM[9];
  #pragma unroll
  for (int j = 0; j < 18; ++j) { accH[j] = 0.f; accV[j] = 0.f; }
  #pragma unroll
  for (int j = 0; j < 9; ++j) accM[j] = 0.f;
  for (int icp = 0; icp < 64; ++icp) {
    int ic = __builtin_amdgcn_readfirstlane(icp * 2 + par);
    __syncthreads();
    const float* src = hb + ((long)(b * 128 + ic) << 14);
    for (int idx = w; idx < 2130; idx += 128) {     // 15 x 142
      int r = idx / 142, c = idx - r * 142;
      int gh = h + r - 7, gw = c - 7;
      float v = 0.f;
      if ((unsigned)gh < 128u && (unsigned)gw < 128u) v = src[(gh << 7) + gw];
      strip[r * 144 + c] = v;
    }
    __syncthreads();
    float rowv[15], colv[15], mv[9];
    #pragma unroll
    for (int k = 0; k < 15; ++k) rowv[k] = strip[7 * 144 + w + k];
    #pragma unroll
    for (int k = 0; k < 15; ++k) colv[k] = strip[k * 144 + w + 7];
    #pragma unroll
    for (int d = 0; d < 9; ++d) mv[d] = strip[(6 + d / 3) * 144 + w + 6 + d % 3];
    #pragma unroll
    for (int j = 0; j < 18; ++j) {
      const float* p = wh + (j * 128 + ic) * 15;
      const float* q = wv + (j * 128 + ic) * 15;
      float sH = accH[j], sV = accV[j];
      #pragma unroll
      for (int k = 0; k < 15; ++k) { sH += p[k] * rowv[k]; sV += q[k] * colv[k]; }
      accH[j] = sH; accV[j] = sV;
    }
    #pragma unroll
    for (int j = 0; j < 9; ++j) {
      const float* p = wm + (j * 128 + ic) * 9;
      float sM = accM[j];
      #pragma unroll
      for (int k = 0; k < 9; ++k) sM += p[k] * mv[k];
      accM[j] = sM;
    }
  }
  __syncthreads();
  if (par == 1) {
    #pragma unroll
    for (int j = 0; j < 18; ++j) smem[j * 128 + w] = accH[j] + accV[j];
    #pragma unroll
    for (int j = 0; j < 9; ++j) smem[(18 + j) * 128 + w] = accM[j];
  }
  __syncthreads();
  if (par == 0) {
    int sp = (h << 7) + w;
    #pragma unroll
    for (int j = 0; j < 18; ++j) {
      float v = accH[j] + accV[j] + smem[j * 128 + w] + bh[j] + bv[j];
      off[((long)(b * 18 + j) << 14) + sp] = v;
    }
    #pragma unroll
    for (int j = 0; j < 9; ++j) {
      float v = accM[j] + smem[(18 + j) * 128 + w] + bm[j];
      msk[((long)(b * 9 + j) << 14) + sp] = 1.f / (1.f + expf(-v));
    }
  }
}

// ---------------- K6: deformable 3x3 conv -----------------------------------
__global__ void k_deform(const float* __restrict__ hbuf, const float* __restrict__ off,
                         const float* __restrict__ msk, const float* __restrict__ wdef,
                         float* __restrict__ out) {
  int bid = blockIdx.x;            // 2 * 128 * 16 = 4096
  int wt = bid & 15;
  int h  = (bid >> 4) & 127;
  int b  = bid >> 11;
  int w0 = wt * 8;
  int t = threadIdx.x;
  __shared__ __align__(16) float sm[9216];   // [ck=1152][pix=8]
  __shared__ __align__(16) float red[1024];
  __shared__ int   p_y0[72], p_x0[72];
  __shared__ float p_wy[72], p_wx[72], p_m[72];
  if (t < 72) {
    int k = t >> 3, p = t & 7, w = w0 + p;
    int sp = (h << 7) + w;
    float dy = off[((long)(b * 18 + 2 * k) << 14) + sp];
    float dx = off[((long)(b * 18 + 2 * k + 1) << 14) + sp];
    float m  = msk[((long)(b * 9 + k) << 14) + sp];
    float y  = dy + (float)(h + k / 3 - 1);
    float xx = dx + (float)(w + k % 3 - 1);
    float y0f = floorf(y), x0f = floorf(xx);
    p_y0[t] = (int)y0f; p_x0[t] = (int)x0f;
    p_wy[t] = y - y0f;  p_wx[t] = xx - x0f; p_m[t] = m;
  }
  __syncthreads();
  for (int j = t; j < 9216; j += 256) {
    int p = j & 7;
    int rest = j >> 3;
    int k = rest % 9;
    int c = rest / 9;
    int kp = k * 8 + p;
    int y0 = p_y0[kp], x0 = p_x0[kp];
    float wy = p_wy[kp], wx = p_wx[kp], m = p_m[kp];
    const float* hp = hbuf + ((long)(b * 128 + c) << 14);
    float v00 = 0.f, v01 = 0.f, v10 = 0.f, v11 = 0.f;
    bool yi0 = (unsigned)y0 < 128u, yi1 = (unsigned)(y0 + 1) < 128u;
    bool xi0 = (unsigned)x0 < 128u, xi1 = (unsigned)(x0 + 1) < 128u;
    int base = (y0 << 7) + x0;
    if (yi0 && xi0) v00 = hp[base];
    if (yi0 && xi1) v01 = hp[base + 1];
    if (yi1 && xi0) v10 = hp[base + 128];
    if (yi1 && xi1) v11 = hp[base + 129];
    float s = (v00 * (1.f - wx) + v01 * wx) * (1.f - wy)
            + (v10 * (1.f - wx) + v11 * wx) * wy;
    sm[j] = s * m;
  }
  __syncthreads();
  int oc = t & 127, g = t >> 7;
  const float4* wd4 = (const float4*)(wdef + oc * 1152 + g * 576);
  const float4* smq = ((const float4*)sm) + g * 1152;
  float acc0 = 0.f, acc1 = 0.f, acc2 = 0.f, acc3 = 0.f;
  float acc4 = 0.f, acc5 = 0.f, acc6 = 0.f, acc7 = 0.f;
#define ACC8(we, ri) { float4 sa = smq[ri]; float4 sb = smq[(ri) + 1];          \
    acc0 += (we) * sa.x; acc1 += (we) * sa.y; acc2 += (we) * sa.z; acc3 += (we) * sa.w; \
    acc4 += (we) * sb.x; acc5 += (we) * sb.y; acc6 += (we) * sb.z; acc7 += (we) * sb.w; }
  #pragma unroll 4
  for (int q = 0; q < 144; ++q) {
    float4 wv = wd4[q];
    ACC8(wv.x, q * 8 + 0);
    ACC8(wv.y, q * 8 + 2);
    ACC8(wv.z, q * 8 + 4);
    ACC8(wv.w, q * 8 + 6);
  }
#undef ACC8
  if (g == 1) {
    float4* r4 = (float4*)red;
    r4[oc * 2]     = make_float4(acc0, acc1, acc2, acc3);
    r4[oc * 2 + 1] = make_float4(acc4, acc5, acc6, acc7);
  }
  __syncthreads();
  if (g == 0) {
    const float4* r4 = (const float4*)red;
    float4 ra = r4[oc * 2], rb = r4[oc * 2 + 1];
    acc0 += ra.x; acc1 += ra.y; acc2 += ra.z; acc3 += ra.w;
    acc4 += rb.x; acc5 += rb.y; acc6 += rb.z; acc7 += rb.w;
    float4* o4 = (float4*)(out + ((long)(b * 128 + oc) << 14) + (h << 7) + w0);
    o4[0] = make_float4(acc0, acc1, acc2, acc3);
    o4[1] = make_float4(acc4, acc5, acc6, acc7);
  }
}

// ---------------- launcher --------------------------------------------------
extern "C" void kernel_launch(void* const* d_in, const int* in_sizes, int n_in,
                              void* d_out, int out_size, void* d_ws, size_t ws_size,
                              hipStream_t stream) {
  const float* x      = (const float*)d_in[0];
  const float* skip   = (const float*)d_in[1];
  const float* w_up   = (const float*)d_in[2];
  const float* b_up   = (const float*)d_in[3];
  const float* w_ref  = (const float*)d_in[4];
  const float* b_ref  = (const float*)d_in[5];
  const float* g1     = (const float*)d_in[6];
  const float* be1    = (const float*)d_in[7];
  const float* w_offh = (const float*)d_in[8];
  const float* b_offh = (const float*)d_in[9];
  const float* w_offv = (const float*)d_in[10];
  const float* b_offv = (const float*)d_in[11];
  const float* w_mask = (const float*)d_in[12];
  const float* b_mask = (const float*)d_in[13];
  const float* w_def  = (const float*)d_in[14];
  const float* g2     = (const float*)d_in[15];
  const float* be2    = (const float*)d_in[16];

  float* ws   = (float*)d_ws;
  float* cat  = ws;              // 8,388,608 floats
  float* tmp1 = ws + 8388608;    // 4,194,304
  float* hbuf = ws + 12582912;   // 4,194,304
  float* offb = ws + 16777216;   //   589,824
  float* mskb = ws + 17367040;   //   294,912
  float* stat = ws + 17661952;   //       512
  float* dpre = ws;              // alias cat (dead after k_conv3)

  hipLaunchKernelGGL(k_upsample, dim3(1024), dim3(256), 0, stream, x, w_up, b_up, cat);
  hipLaunchKernelGGL(k_skipcopy, dim3(4096), dim3(256), 0, stream,
                     (const float4*)skip, (float4*)cat);
  hipLaunchKernelGGL(k_conv3, dim3(512), dim3(256), 0, stream, cat, w_ref, b_ref, tmp1);
  hipLaunchKernelGGL(k_bnstats, dim3(128), dim3(256), 0, stream, tmp1, stat, stat + 128);
  hipLaunchKernelGGL(k_bnrelu, dim3(4096), dim3(256), 0, stream,
                     (const float4*)tmp1, stat, stat + 128, g1, be1, (float4*)hbuf);
  hipLaunchKernelGGL(k_offmask, dim3(256), dim3(256), 0, stream, hbuf,
                     w_offh, b_offh, w_offv, b_offv, w_mask, b_mask, offb, mskb);
  hipLaunchKernelGGL(k_deform, dim3(4096), dim3(256), 0, stream, hbuf, offb, mskb,
                     w_def, dpre);
  hipLaunchKernelGGL(k_bnstats, dim3(128), dim3(256), 0, stream, dpre, stat + 256, stat + 384);
  hipLaunchKernelGGL(k_bnrelu, dim3(4096), dim3(256), 0, stream,
                     (const float4*)dpre, stat + 256, stat + 384, g2, be2, (float4*)d_out);
}

// Round 2
// 678.266 us; speedup vs baseline: 2.9047x; 2.9047x over previous
//
#include <hip/hip_runtime.h>
#include <hip/hip_bf16.h>

typedef __attribute__((ext_vector_type(8))) short bf16x8;
typedef __attribute__((ext_vector_type(4))) float f32x4;
typedef __attribute__((ext_vector_type(8))) unsigned short u16x8;

static __device__ __forceinline__ unsigned short f2bf(float f) {
  union { float f; unsigned u; } v; v.f = f;
  unsigned r = v.u + 0x7fff + ((v.u >> 16) & 1);
  return (unsigned short)(r >> 16);
}

// ---------------- K1: transposed-conv 2x2 s2 -> catT chunks 0..3 (bf16) -----
__global__ void k_upsampleT(const float* __restrict__ x, const float* __restrict__ w_up,
                            const float* __restrict__ b_up, unsigned short* __restrict__ catT) {
  int bid = blockIdx.x;            // 2 * 64 * 8 = 1024
  int wt = bid & 7;
  int hh = (bid >> 3) & 63;
  int b  = bid >> 9;
  int t = threadIdx.x;
  __shared__ float xs[256][8];
  int ww0 = wt * 8;
  int pix = t & 7, icb = t >> 3;
  #pragma unroll
  for (int r = 0; r < 8; ++r) {
    int ic = r * 32 + icb;
    xs[ic][pix] = x[((b * 256 + ic) * 64 + hh) * 64 + ww0 + pix];
  }
  __syncthreads();
  int oc = t & 127, g = t >> 7;    // g = kh
  float bias = b_up[oc];
  float acc0[8], acc1[8];
  #pragma unroll
  for (int p = 0; p < 8; ++p) { acc0[p] = bias; acc1[p] = bias; }
  for (int i = 0; i < 256; ++i) {
    float wv0 = w_up[((i * 128 + oc) * 2 + g) * 2 + 0];
    float wv1 = w_up[((i * 128 + oc) * 2 + g) * 2 + 1];
    #pragma unroll
    for (int p = 0; p < 8; ++p) {
      float xv = xs[i][p];
      acc0[p] += xv * wv0;
      acc1[p] += xv * wv1;
    }
  }
  int h = 2 * hh + g;
  int cg = oc >> 5, icl = oc & 31;
  long plane = ((long)(b * 8 + cg) << 14) + (h << 7);
  #pragma unroll
  for (int p = 0; p < 8; ++p) {
    int w0c = 2 * (ww0 + p);
    catT[((plane + w0c) << 5) + icl]     = f2bf(acc0[p]);
    catT[((plane + w0c + 1) << 5) + icl] = f2bf(acc1[p]);
  }
}

// ---------------- K1b: skip -> catT chunks 4..7 (bf16, LDS transpose) -------
__global__ void k_skipT(const float* __restrict__ skip, unsigned short* __restrict__ catT) {
  int bid = blockIdx.x;            // 2 * 4 * 128 * 2 = 2048
  int xb = bid & 1;
  int y  = (bid >> 1) & 127;
  int cg = (bid >> 8) & 3;
  int b  = bid >> 10;
  int t = threadIdx.x;
  __shared__ float ts[32][65];
  int x = t & 63, c4 = t >> 6, x0 = xb * 64;
  #pragma unroll
  for (int p = 0; p < 8; ++p) {
    int c = p * 4 + c4;
    ts[c][x] = skip[(((long)(b * 128 + cg * 32 + c)) << 14) + (y << 7) + x0 + x];
  }
  __syncthreads();
  int ic = t & 31, xg = t >> 5;
  long plane = ((long)(b * 8 + 4 + cg) << 14) + (y << 7) + x0;
  #pragma unroll
  for (int q = 0; q < 8; ++q) {
    int xx = xg * 8 + q;
    catT[((plane + xx) << 5) + ic] = f2bf(ts[ic][xx]);
  }
}

// ---------------- weight repack: w_ref -> wbT[tap][oc][ic] bf16 -------------
__global__ void k_wrefT(const float* __restrict__ wr, unsigned short* __restrict__ wbT) {
  int idx = blockIdx.x * 256 + threadIdx.x;   // 294,912
  int tap = idx >> 15;
  int rem = idx & 32767;
  int oc = rem >> 8, ic = rem & 255;
  wbT[idx] = f2bf(wr[(oc * 256 + ic) * 9 + tap]);
}

// ---------------- weight build: wOM[39][48][128] bf16 -----------------------
__global__ void k_womT(const float* __restrict__ wh, const float* __restrict__ wv,
                       const float* __restrict__ wm, unsigned short* __restrict__ wOM) {
  int idx = blockIdx.x * 256 + threadIdx.x;   // 239,616 = 39*48*128
  int tap = idx / 6144;
  int rem = idx - tap * 6144;
  int j = rem >> 7, ic = rem & 127;
  float v = 0.f;
  if (tap < 15) {
    if (j < 18) v = wh[(j * 128 + ic) * 15 + tap];
  } else if (tap < 30) {
    if (j < 18) v = wv[(j * 128 + ic) * 15 + (tap - 15)];
  } else {
    if (j >= 18 && j < 27) v = wm[((j - 18) * 128 + ic) * 9 + (tap - 30)];
  }
  wOM[idx] = f2bf(v);
}

// ---------------- K2: 3x3 conv 256->128 via MFMA bf16 -----------------------
__global__ __launch_bounds__(256, 2)
void k_conv3m(const unsigned short* __restrict__ catT, const unsigned short* __restrict__ wbT,
              const float* __restrict__ br, float* __restrict__ out) {
  int bid = blockIdx.x;            // 2 * 128 * 2 = 512
  int xt = bid & 1;
  int y  = (bid >> 1) & 127;
  int b  = bid >> 8;
  int x0 = xt * 64;
  int t = threadIdx.x;
  int l = t & 63, w = t >> 6;
  __shared__ unsigned short xs[3 * 66 * 40];   // [r][c][ic pad 40] 15,840 B
  f32x4 acc[2][4];
  #pragma unroll
  for (int m = 0; m < 2; ++m)
    #pragma unroll
    for (int n = 0; n < 4; ++n)
      #pragma unroll
      for (int r = 0; r < 4; ++r) acc[m][n][r] = 0.f;
  const unsigned short* catb = catT + ((long)b << 22);   // b*8*16384*32
  int lan15 = l & 15, lhi = l >> 4;
  for (int cg = 0; cg < 8; ++cg) {
    __syncthreads();
    for (int j = t; j < 792; j += 256) {       // 3*66*4 granules
      int g = j & 3;
      int rc = j >> 2;
      int c = rc % 66, r = rc / 66;
      int gy = y + r - 1, gx = x0 + c - 1;
      u16x8 v = {0, 0, 0, 0, 0, 0, 0, 0};
      if ((unsigned)gy < 128u && (unsigned)gx < 128u)
        v = *(const u16x8*)(catb + ((((long)cg << 14) + (gy << 7) + gx) << 5) + g * 8);
      *(u16x8*)(xs + (r * 66 + c) * 40 + g * 8) = v;
    }
    bf16x8 af[2][9];
    int kbase = cg * 32 + lhi * 8;
    #pragma unroll
    for (int mt = 0; mt < 2; ++mt)
      #pragma unroll
      for (int tap = 0; tap < 9; ++tap)
        af[mt][tap] = *(const bf16x8*)(wbT + ((tap * 128 + w * 32 + mt * 16 + lan15) * 256 + kbase));
    __syncthreads();
    #pragma unroll
    for (int tap = 0; tap < 9; ++tap) {
      int ky = tap / 3, kx = tap % 3;
      #pragma unroll
      for (int nt = 0; nt < 4; ++nt) {
        int c = nt * 16 + lan15 + kx;
        bf16x8 bfv = *(const bf16x8*)(xs + ((ky * 66 + c) * 40) + lhi * 8);
        acc[0][nt] = __builtin_amdgcn_mfma_f32_16x16x32_bf16(af[0][tap], bfv, acc[0][nt], 0, 0, 0);
        acc[1][nt] = __builtin_amdgcn_mfma_f32_16x16x32_bf16(af[1][tap], bfv, acc[1][nt], 0, 0, 0);
      }
    }
  }
  #pragma unroll
  for (int mt = 0; mt < 2; ++mt)
    #pragma unroll
    for (int reg = 0; reg < 4; ++reg) {
      int oc = w * 32 + mt * 16 + lhi * 4 + reg;
      float bias = br[oc];
      long obase = ((long)(b * 128 + oc) << 14) + (y << 7);
      #pragma unroll
      for (int nt = 0; nt < 4; ++nt)
        out[obase + x0 + nt * 16 + lan15] = acc[mt][nt][reg] + bias;
    }
}

// ---------------- K3/K7: per-channel batch-norm stats -----------------------
__global__ void k_bnstats(const float* __restrict__ src, float* __restrict__ mean,
                          float* __restrict__ rstd) {
  int c = blockIdx.x, t = threadIdx.x;
  float s = 0.f, s2 = 0.f;
  for (int b = 0; b < 2; ++b) {
    const float4* p4 = (const float4*)(src + ((long)(b * 128 + c) << 14));
    for (int i = t; i < 4096; i += 256) {
      float4 v = p4[i];
      s  += v.x + v.y + v.z + v.w;
      s2 += v.x * v.x + v.y * v.y + v.z * v.z + v.w * v.w;
    }
  }
  #pragma unroll
  for (int off = 32; off; off >>= 1) {
    s  += __shfl_down(s, off);
    s2 += __shfl_down(s2, off);
  }
  __shared__ float as[4], as2[4];
  int wid = t >> 6;
  if ((t & 63) == 0) { as[wid] = s; as2[wid] = s2; }
  __syncthreads();
  if (t == 0) {
    float S = as[0] + as[1] + as[2] + as[3];
    float S2 = as2[0] + as2[1] + as2[2] + as2[3];
    float m = S / 32768.f;
    float var = S2 / 32768.f - m * m;
    mean[c] = m;
    rstd[c] = rsqrtf(var + 1e-5f);
  }
}

// ---------------- K4: bn+relu -> hbuf fp32 AND hbufT bf16 chunked -----------
__global__ void k_bnrelu2(const float* __restrict__ tmp1, const float* __restrict__ mean,
                          const float* __restrict__ rstd, const float* __restrict__ g,
                          const float* __restrict__ be, float* __restrict__ hbuf,
                          unsigned short* __restrict__ hbufT) {
  int bid = blockIdx.x;            // 2048
  int xb = bid & 1;
  int y  = (bid >> 1) & 127;
  int cg = (bid >> 8) & 3;
  int b  = bid >> 10;
  int t = threadIdx.x;
  __shared__ float ts[32][65];
  int x = t & 63, c4 = t >> 6, x0 = xb * 64;
  #pragma unroll
  for (int p = 0; p < 8; ++p) {
    int c = p * 4 + c4;
    int ch = cg * 32 + c;
    float sc = rstd[ch] * g[ch];
    float bb = be[ch] - mean[ch] * sc;
    long idx = ((long)(b * 128 + ch) << 14) + (y << 7) + x0 + x;
    float v = fmaxf(tmp1[idx] * sc + bb, 0.f);
    hbuf[idx] = v;
    ts[c][x] = v;
  }
  __syncthreads();
  int ic = t & 31, xg = t >> 5;
  long plane = ((long)(b * 4 + cg) << 14) + (y << 7) + x0;
  #pragma unroll
  for (int q = 0; q < 8; ++q) {
    int xx = xg * 8 + q;
    hbufT[((plane + xx) << 5) + ic] = f2bf(ts[ic][xx]);
  }
}

// ---------------- K5: offsets + mask via MFMA bf16 --------------------------
__global__ __launch_bounds__(256, 2)
void k_offmaskm(const unsigned short* __restrict__ hbufT, const unsigned short* __restrict__ wOM,
                const float* __restrict__ bh, const float* __restrict__ bv,
                const float* __restrict__ bm,
                float* __restrict__ off, float* __restrict__ msk) {
  int bid = blockIdx.x;            // 2 * 64 * 4 = 512
  int xb = bid & 3;
  int yb = (bid >> 2) & 63;
  int b  = bid >> 8;
  int y0 = yb * 2, x0 = xb * 32;
  int t = threadIdx.x;
  int l = t & 63, w = t >> 6;
  int row = w >> 1, xcol = (w & 1) * 16;
  int lan15 = l & 15, lhi = l >> 4;
  __shared__ unsigned short xs[16 * 46 * 40];   // 58,880 B
  f32x4 acc[3];
  #pragma unroll
  for (int m = 0; m < 3; ++m)
    #pragma unroll
    for (int r = 0; r < 4; ++r) acc[m][r] = 0.f;
  const unsigned short* hb = hbufT + ((long)b << 21);   // b*4*16384*32
  for (int cg = 0; cg < 4; ++cg) {
    __syncthreads();
    for (int j = t; j < 2944; j += 256) {     // 16*46*4 granules
      int g = j & 3;
      int rc = j >> 2;
      int c = rc % 46, r = rc / 46;
      int gy = y0 + r - 7, gx = x0 + c - 7;
      u16x8 v = {0, 0, 0, 0, 0, 0, 0, 0};
      if ((unsigned)gy < 128u && (unsigned)gx < 128u)
        v = *(const u16x8*)(hb + ((((long)cg << 14) + (gy << 7) + gx) << 5) + g * 8);
      *(u16x8*)(xs + (r * 46 + c) * 40 + g * 8) = v;
    }
    __syncthreads();
    int kbase = cg * 32 + lhi * 8;
    #pragma unroll
    for (int tap = 0; tap < 39; ++tap) {
      int ky = (tap < 15) ? 0 : ((tap < 30) ? (tap - 22) : ((tap - 30) / 3 - 1));
      int kx = (tap < 15) ? (tap - 7) : ((tap < 30) ? 0 : ((tap - 30) % 3 - 1));
      bf16x8 a0 = *(const bf16x8*)(wOM + ((tap * 48 + 0  + lan15) * 128 + kbase));
      bf16x8 a1 = *(const bf16x8*)(wOM + ((tap * 48 + 16 + lan15) * 128 + kbase));
      bf16x8 a2 = *(const bf16x8*)(wOM + ((tap * 48 + 32 + lan15) * 128 + kbase));
      int c = xcol + lan15 + kx + 7;
      int r = row + ky + 7;
      bf16x8 bfv = *(const bf16x8*)(xs + (r * 46 + c) * 40 + lhi * 8);
      acc[0] = __builtin_amdgcn_mfma_f32_16x16x32_bf16(a0, bfv, acc[0], 0, 0, 0);
      acc[1] = __builtin_amdgcn_mfma_f32_16x16x32_bf16(a1, bfv, acc[1], 0, 0, 0);
      acc[2] = __builtin_amdgcn_mfma_f32_16x16x32_bf16(a2, bfv, acc[2], 0, 0, 0);
    }
  }
  int y = y0 + row;
  int x = x0 + xcol + lan15;
  #pragma unroll
  for (int mt = 0; mt < 3; ++mt)
    #pragma unroll
    for (int reg = 0; reg < 4; ++reg) {
      int j = mt * 16 + lhi * 4 + reg;
      float v = acc[mt][reg];
      if (j < 18) {
        off[((long)(b * 18 + j) << 14) + (y << 7) + x] = v + bh[j] + bv[j];
      } else if (j < 27) {
        int jm = j - 18;
        msk[((long)(b * 9 + jm) << 14) + (y << 7) + x] = 1.f / (1.f + expf(-(v + bm[jm])));
      }
    }
}

// ---------------- K6: deformable 3x3 conv -----------------------------------
__global__ void k_deform(const float* __restrict__ hbuf, const float* __restrict__ off,
                         const float* __restrict__ msk, const float* __restrict__ wdef,
                         float* __restrict__ out) {
  int bid = blockIdx.x;            // 2 * 128 * 16 = 4096
  int wt = bid & 15;
  int h  = (bid >> 4) & 127;
  int b  = bid >> 11;
  int w0 = wt * 8;
  int t = threadIdx.x;
  __shared__ __align__(16) float sm[9216];   // [ck=1152][pix=8]
  __shared__ __align__(16) float red[1024];
  __shared__ int   p_y0[72], p_x0[72];
  __shared__ float p_wy[72], p_wx[72], p_m[72];
  if (t < 72) {
    int k = t >> 3, p = t & 7, w = w0 + p;
    int sp = (h << 7) + w;
    float dy = off[((long)(b * 18 + 2 * k) << 14) + sp];
    float dx = off[((long)(b * 18 + 2 * k + 1) << 14) + sp];
    float m  = msk[((long)(b * 9 + k) << 14) + sp];
    float y  = dy + (float)(h + k / 3 - 1);
    float xx = dx + (float)(w + k % 3 - 1);
    float y0f = floorf(y), x0f = floorf(xx);
    p_y0[t] = (int)y0f; p_x0[t] = (int)x0f;
    p_wy[t] = y - y0f;  p_wx[t] = xx - x0f; p_m[t] = m;
  }
  __syncthreads();
  for (int j = t; j < 9216; j += 256) {
    int p = j & 7;
    int rest = j >> 3;
    int k = rest % 9;
    int c = rest / 9;
    int kp = k * 8 + p;
    int y0 = p_y0[kp], x0 = p_x0[kp];
    float wy = p_wy[kp], wx = p_wx[kp], m = p_m[kp];
    const float* hp = hbuf + ((long)(b * 128 + c) << 14);
    float v00 = 0.f, v01 = 0.f, v10 = 0.f, v11 = 0.f;
    bool yi0 = (unsigned)y0 < 128u, yi1 = (unsigned)(y0 + 1) < 128u;
    bool xi0 = (unsigned)x0 < 128u, xi1 = (unsigned)(x0 + 1) < 128u;
    int base = (y0 << 7) + x0;
    if (yi0 && xi0) v00 = hp[base];
    if (yi0 && xi1) v01 = hp[base + 1];
    if (yi1 && xi0) v10 = hp[base + 128];
    if (yi1 && xi1) v11 = hp[base + 129];
    float s = (v00 * (1.f - wx) + v01 * wx) * (1.f - wy)
            + (v10 * (1.f - wx) + v11 * wx) * wy;
    sm[j] = s * m;
  }
  __syncthreads();
  int oc = t & 127, g = t >> 7;
  const float4* wd4 = (const float4*)(wdef + oc * 1152 + g * 576);
  const float4* smq = ((const float4*)sm) + g * 1152;
  float acc0 = 0.f, acc1 = 0.f, acc2 = 0.f, acc3 = 0.f;
  float acc4 = 0.f, acc5 = 0.f, acc6 = 0.f, acc7 = 0.f;
#define ACC8(we, ri) { float4 sa = smq[ri]; float4 sb = smq[(ri) + 1];          \
    acc0 += (we) * sa.x; acc1 += (we) * sa.y; acc2 += (we) * sa.z; acc3 += (we) * sa.w; \
    acc4 += (we) * sb.x; acc5 += (we) * sb.y; acc6 += (we) * sb.z; acc7 += (we) * sb.w; }
  #pragma unroll 4
  for (int q = 0; q < 144; ++q) {
    float4 wv = wd4[q];
    ACC8(wv.x, q * 8 + 0);
    ACC8(wv.y, q * 8 + 2);
    ACC8(wv.z, q * 8 + 4);
    ACC8(wv.w, q * 8 + 6);
  }
#undef ACC8
  if (g == 1) {
    float4* r4 = (float4*)red;
    r4[oc * 2]     = make_float4(acc0, acc1, acc2, acc3);
    r4[oc * 2 + 1] = make_float4(acc4, acc5, acc6, acc7);
  }
  __syncthreads();
  if (g == 0) {
    const float4* r4 = (const float4*)red;
    float4 ra = r4[oc * 2], rb = r4[oc * 2 + 1];
    acc0 += ra.x; acc1 += ra.y; acc2 += ra.z; acc3 += ra.w;
    acc4 += rb.x; acc5 += rb.y; acc6 += rb.z; acc7 += rb.w;
    float4* o4 = (float4*)(out + ((long)(b * 128 + oc) << 14) + (h << 7) + w0);
    o4[0] = make_float4(acc0, acc1, acc2, acc3);
    o4[1] = make_float4(acc4, acc5, acc6, acc7);
  }
}

// ---------------- K8: plain bn+relu (final output) --------------------------
__global__ void k_bnrelu(const float4* __restrict__ src, const float* __restrict__ mean,
                         const float* __restrict__ rstd, const float* __restrict__ g,
                         const float* __restrict__ be, float4* __restrict__ dst) {
  int i = blockIdx.x * 256 + threadIdx.x;   // over 1,048,576 float4
  if (i >= 1048576) return;
  int c = (i >> 12) & 127;
  float sc = rstd[c] * g[c];
  float bb = be[c] - mean[c] * sc;
  float4 v = src[i];
  v.x = fmaxf(v.x * sc + bb, 0.f);
  v.y = fmaxf(v.y * sc + bb, 0.f);
  v.z = fmaxf(v.z * sc + bb, 0.f);
  v.w = fmaxf(v.w * sc + bb, 0.f);
  dst[i] = v;
}

// ---------------- launcher --------------------------------------------------
extern "C" void kernel_launch(void* const* d_in, const int* in_sizes, int n_in,
                              void* d_out, int out_size, void* d_ws, size_t ws_size,
                              hipStream_t stream) {
  const float* x      = (const float*)d_in[0];
  const float* skip   = (const float*)d_in[1];
  const float* w_up   = (const float*)d_in[2];
  const float* b_up   = (const float*)d_in[3];
  const float* w_ref  = (const float*)d_in[4];
  const float* b_ref  = (const float*)d_in[5];
  const float* g1     = (const float*)d_in[6];
  const float* be1    = (const float*)d_in[7];
  const float* w_offh = (const float*)d_in[8];
  const float* b_offh = (const float*)d_in[9];
  const float* w_offv = (const float*)d_in[10];
  const float* b_offv = (const float*)d_in[11];
  const float* w_mask = (const float*)d_in[12];
  const float* b_mask = (const float*)d_in[13];
  const float* w_def  = (const float*)d_in[14];
  const float* g2     = (const float*)d_in[15];
  const float* be2    = (const float*)d_in[16];

  char* W = (char*)d_ws;
  unsigned short* catT  = (unsigned short*)W;                 // 16,777,216 B
  float*          tmp1  = (float*)(W + 16777216);             // 16 MB
  float*          hbuf  = (float*)(W + 33554432);             // 16 MB
  unsigned short* hbufT = (unsigned short*)(W + 50331648);    // 8,388,608 B
  float*          offb  = (float*)(W + 58720256);             // 2,359,296 B
  float*          mskb  = (float*)(W + 61079552);             // 1,179,648 B
  float*          stat  = (float*)(W + 62259200);             // 2,048 B
  unsigned short* wbT   = (unsigned short*)(W + 62261248);    // 589,824 B
  unsigned short* wOM   = (unsigned short*)(W + 62851072);    // 479,232 B
  float*          dpre  = (float*)W;                          // alias catT (dead)

  hipLaunchKernelGGL(k_upsampleT, dim3(1024), dim3(256), 0, stream, x, w_up, b_up, catT);
  hipLaunchKernelGGL(k_skipT, dim3(2048), dim3(256), 0, stream, skip, catT);
  hipLaunchKernelGGL(k_wrefT, dim3(1152), dim3(256), 0, stream, w_ref, wbT);
  hipLaunchKernelGGL(k_womT, dim3(936), dim3(256), 0, stream, w_offh, w_offv, w_mask, wOM);
  hipLaunchKernelGGL(k_conv3m, dim3(512), dim3(256), 0, stream, catT, wbT, b_ref, tmp1);
  hipLaunchKernelGGL(k_bnstats, dim3(128), dim3(256), 0, stream, tmp1, stat, stat + 128);
  hipLaunchKernelGGL(k_bnrelu2, dim3(2048), dim3(256), 0, stream, tmp1, stat, stat + 128,
                     g1, be1, hbuf, hbufT);
  hipLaunchKernelGGL(k_offmaskm, dim3(512), dim3(256), 0, stream, hbufT, wOM,
                     b_offh, b_offv, b_mask, offb, mskb);
  hipLaunchKernelGGL(k_deform, dim3(4096), dim3(256), 0, stream, hbuf, offb, mskb,
                     w_def, dpre);
  hipLaunchKernelGGL(k_bnstats, dim3(128), dim3(256), 0, stream, dpre, stat + 256, stat + 384);
  hipLaunchKernelGGL(k_bnrelu, dim3(4096), dim3(256), 0, stream,
                     (const float4*)dpre, stat + 256, stat + 384, g2, be2, (float4*)d_out);
}

// Round 3
// 279.715 us; speedup vs baseline: 7.0434x; 2.4248x over previous
//
#include <hip/hip_runtime.h>
#include <hip/hip_bf16.h>

typedef __attribute__((ext_vector_type(8))) short bf16x8;
typedef __attribute__((ext_vector_type(4))) float f32x4;
typedef __attribute__((ext_vector_type(8))) unsigned short u16x8;

static __device__ __forceinline__ unsigned short f2bf(float f) {
  union { float f; unsigned u; } v; v.f = f;
  unsigned r = v.u + 0x7fff + ((v.u >> 16) & 1);
  return (unsigned short)(r >> 16);
}

// ---------------- K1: transposed-conv 2x2 s2 -> catT chunks 0..3 (bf16) -----
__global__ void k_upsampleT(const float* __restrict__ x, const float* __restrict__ w_up,
                            const float* __restrict__ b_up, unsigned short* __restrict__ catT) {
  int bid = blockIdx.x;            // 2 * 64 * 8 = 1024
  int wt = bid & 7;
  int hh = (bid >> 3) & 63;
  int b  = bid >> 9;
  int t = threadIdx.x;
  __shared__ float xs[256][8];
  int ww0 = wt * 8;
  int pix = t & 7, icb = t >> 3;
  #pragma unroll
  for (int r = 0; r < 8; ++r) {
    int ic = r * 32 + icb;
    xs[ic][pix] = x[((b * 256 + ic) * 64 + hh) * 64 + ww0 + pix];
  }
  __syncthreads();
  int oc = t & 127, g = t >> 7;    // g = kh
  float bias = b_up[oc];
  float acc0[8], acc1[8];
  #pragma unroll
  for (int p = 0; p < 8; ++p) { acc0[p] = bias; acc1[p] = bias; }
  for (int i = 0; i < 256; ++i) {
    float wv0 = w_up[((i * 128 + oc) * 2 + g) * 2 + 0];
    float wv1 = w_up[((i * 128 + oc) * 2 + g) * 2 + 1];
    #pragma unroll
    for (int p = 0; p < 8; ++p) {
      float xv = xs[i][p];
      acc0[p] += xv * wv0;
      acc1[p] += xv * wv1;
    }
  }
  int h = 2 * hh + g;
  int cg = oc >> 5, icl = oc & 31;
  long plane = ((long)(b * 8 + cg) << 14) + (h << 7);
  #pragma unroll
  for (int p = 0; p < 8; ++p) {
    int w0c = 2 * (ww0 + p);
    catT[((plane + w0c) << 5) + icl]     = f2bf(acc0[p]);
    catT[((plane + w0c + 1) << 5) + icl] = f2bf(acc1[p]);
  }
}

// ---------------- K1b: skip -> catT chunks 4..7 (bf16, LDS transpose) -------
__global__ void k_skipT(const float* __restrict__ skip, unsigned short* __restrict__ catT) {
  int bid = blockIdx.x;            // 2 * 4 * 128 * 2 = 2048
  int xb = bid & 1;
  int y  = (bid >> 1) & 127;
  int cg = (bid >> 8) & 3;
  int b  = bid >> 10;
  int t = threadIdx.x;
  __shared__ float ts[32][65];
  int x = t & 63, c4 = t >> 6, x0 = xb * 64;
  #pragma unroll
  for (int p = 0; p < 8; ++p) {
    int c = p * 4 + c4;
    ts[c][x] = skip[(((long)(b * 128 + cg * 32 + c)) << 14) + (y << 7) + x0 + x];
  }
  __syncthreads();
  int ic = t & 31, xg = t >> 5;
  long plane = ((long)(b * 8 + 4 + cg) << 14) + (y << 7) + x0;
  #pragma unroll
  for (int q = 0; q < 8; ++q) {
    int xx = xg * 8 + q;
    catT[((plane + xx) << 5) + ic] = f2bf(ts[ic][xx]);
  }
}

// ---------------- weight repack: w_ref -> wbT[tap][oc][ic] bf16 -------------
__global__ void k_wrefT(const float* __restrict__ wr, unsigned short* __restrict__ wbT) {
  int idx = blockIdx.x * 256 + threadIdx.x;   // 294,912
  int tap = idx >> 15;
  int rem = idx & 32767;
  int oc = rem >> 8, ic = rem & 255;
  wbT[idx] = f2bf(wr[(oc * 256 + ic) * 9 + tap]);
}

// ---------------- weight build: wOM[39][48][128] bf16 -----------------------
__global__ void k_womT(const float* __restrict__ wh, const float* __restrict__ wv,
                       const float* __restrict__ wm, unsigned short* __restrict__ wOM) {
  int idx = blockIdx.x * 256 + threadIdx.x;   // 239,616 = 39*48*128
  int tap = idx / 6144;
  int rem = idx - tap * 6144;
  int j = rem >> 7, ic = rem & 127;
  float v = 0.f;
  if (tap < 15) {
    if (j < 18) v = wh[(j * 128 + ic) * 15 + tap];
  } else if (tap < 30) {
    if (j < 18) v = wv[(j * 128 + ic) * 15 + (tap - 15)];
  } else {
    if (j >= 18 && j < 27) v = wm[((j - 18) * 128 + ic) * 9 + (tap - 30)];
  }
  wOM[idx] = f2bf(v);
}

// ---------------- weight repack: w_def -> MFMA-A fragment order bf16 --------
// wdefA[((ks*4 + lhi)*128 + oc)*8 + j]  where ks = cg*9+k, channel = cg*32+lhi*8+j
__global__ void k_wdefA(const float* __restrict__ wd, unsigned short* __restrict__ wdefA) {
  int idx = blockIdx.x * 256 + threadIdx.x;   // 147,456
  if (idx >= 147456) return;
  int j   = idx & 7;
  int oc  = (idx >> 3) & 127;
  int lhi = (idx >> 10) & 3;
  int ks  = idx >> 12;               // 0..35
  int k = ks % 9, cg = ks / 9;
  int c = cg * 32 + lhi * 8 + j;
  wdefA[idx] = f2bf(wd[(oc * 128 + c) * 9 + k]);
}

// ---------------- K2: 3x3 conv 256->128 via MFMA bf16 -----------------------
__global__ __launch_bounds__(256, 2)
void k_conv3m(const unsigned short* __restrict__ catT, const unsigned short* __restrict__ wbT,
              const float* __restrict__ br, float* __restrict__ out) {
  int bid = blockIdx.x;            // 2 * 128 * 2 = 512
  int xt = bid & 1;
  int y  = (bid >> 1) & 127;
  int b  = bid >> 8;
  int x0 = xt * 64;
  int t = threadIdx.x;
  int l = t & 63, w = t >> 6;
  __shared__ unsigned short xs[3 * 66 * 40];   // [r][c][ic pad 40] 15,840 B
  f32x4 acc[2][4];
  #pragma unroll
  for (int m = 0; m < 2; ++m)
    #pragma unroll
    for (int n = 0; n < 4; ++n)
      #pragma unroll
      for (int r = 0; r < 4; ++r) acc[m][n][r] = 0.f;
  const unsigned short* catb = catT + ((long)b << 22);   // b*8*16384*32
  int lan15 = l & 15, lhi = l >> 4;
  for (int cg = 0; cg < 8; ++cg) {
    __syncthreads();
    for (int j = t; j < 792; j += 256) {       // 3*66*4 granules
      int g = j & 3;
      int rc = j >> 2;
      int c = rc % 66, r = rc / 66;
      int gy = y + r - 1, gx = x0 + c - 1;
      u16x8 v = {0, 0, 0, 0, 0, 0, 0, 0};
      if ((unsigned)gy < 128u && (unsigned)gx < 128u)
        v = *(const u16x8*)(catb + ((((long)cg << 14) + (gy << 7) + gx) << 5) + g * 8);
      *(u16x8*)(xs + (r * 66 + c) * 40 + g * 8) = v;
    }
    bf16x8 af[2][9];
    int kbase = cg * 32 + lhi * 8;
    #pragma unroll
    for (int mt = 0; mt < 2; ++mt)
      #pragma unroll
      for (int tap = 0; tap < 9; ++tap)
        af[mt][tap] = *(const bf16x8*)(wbT + ((tap * 128 + w * 32 + mt * 16 + lan15) * 256 + kbase));
    __syncthreads();
    #pragma unroll
    for (int tap = 0; tap < 9; ++tap) {
      int ky = tap / 3, kx = tap % 3;
      #pragma unroll
      for (int nt = 0; nt < 4; ++nt) {
        int c = nt * 16 + lan15 + kx;
        bf16x8 bfv = *(const bf16x8*)(xs + ((ky * 66 + c) * 40) + lhi * 8);
        acc[0][nt] = __builtin_amdgcn_mfma_f32_16x16x32_bf16(af[0][tap], bfv, acc[0][nt], 0, 0, 0);
        acc[1][nt] = __builtin_amdgcn_mfma_f32_16x16x32_bf16(af[1][tap], bfv, acc[1][nt], 0, 0, 0);
      }
    }
  }
  #pragma unroll
  for (int mt = 0; mt < 2; ++mt)
    #pragma unroll
    for (int reg = 0; reg < 4; ++reg) {
      int oc = w * 32 + mt * 16 + lhi * 4 + reg;
      float bias = br[oc];
      long obase = ((long)(b * 128 + oc) << 14) + (y << 7);
      #pragma unroll
      for (int nt = 0; nt < 4; ++nt)
        out[obase + x0 + nt * 16 + lan15] = acc[mt][nt][reg] + bias;
    }
}

// ---------------- K3/K7: per-channel batch-norm stats -----------------------
__global__ void k_bnstats(const float* __restrict__ src, float* __restrict__ mean,
                          float* __restrict__ rstd) {
  int c = blockIdx.x, t = threadIdx.x;
  float s = 0.f, s2 = 0.f;
  for (int b = 0; b < 2; ++b) {
    const float4* p4 = (const float4*)(src + ((long)(b * 128 + c) << 14));
    for (int i = t; i < 4096; i += 256) {
      float4 v = p4[i];
      s  += v.x + v.y + v.z + v.w;
      s2 += v.x * v.x + v.y * v.y + v.z * v.z + v.w * v.w;
    }
  }
  #pragma unroll
  for (int off = 32; off; off >>= 1) {
    s  += __shfl_down(s, off);
    s2 += __shfl_down(s2, off);
  }
  __shared__ float as[4], as2[4];
  int wid = t >> 6;
  if ((t & 63) == 0) { as[wid] = s; as2[wid] = s2; }
  __syncthreads();
  if (t == 0) {
    float S = as[0] + as[1] + as[2] + as[3];
    float S2 = as2[0] + as2[1] + as2[2] + as2[3];
    float m = S / 32768.f;
    float var = S2 / 32768.f - m * m;
    mean[c] = m;
    rstd[c] = rsqrtf(var + 1e-5f);
  }
}

// ---------------- K4: bn+relu -> hbufT bf16 chunked only --------------------
__global__ void k_bnrelu2(const float* __restrict__ tmp1, const float* __restrict__ mean,
                          const float* __restrict__ rstd, const float* __restrict__ g,
                          const float* __restrict__ be, unsigned short* __restrict__ hbufT) {
  int bid = blockIdx.x;            // 2048
  int xb = bid & 1;
  int y  = (bid >> 1) & 127;
  int cg = (bid >> 8) & 3;
  int b  = bid >> 10;
  int t = threadIdx.x;
  __shared__ float ts[32][65];
  int x = t & 63, c4 = t >> 6, x0 = xb * 64;
  #pragma unroll
  for (int p = 0; p < 8; ++p) {
    int c = p * 4 + c4;
    int ch = cg * 32 + c;
    float sc = rstd[ch] * g[ch];
    float bb = be[ch] - mean[ch] * sc;
    long idx = ((long)(b * 128 + ch) << 14) + (y << 7) + x0 + x;
    ts[c][x] = fmaxf(tmp1[idx] * sc + bb, 0.f);
  }
  __syncthreads();
  int ic = t & 31, xg = t >> 5;
  long plane = ((long)(b * 4 + cg) << 14) + (y << 7) + x0;
  #pragma unroll
  for (int q = 0; q < 8; ++q) {
    int xx = xg * 8 + q;
    hbufT[((plane + xx) << 5) + ic] = f2bf(ts[ic][xx]);
  }
}

// ---------------- K5: offsets + mask via MFMA bf16 --------------------------
__global__ __launch_bounds__(256, 2)
void k_offmaskm(const unsigned short* __restrict__ hbufT, const unsigned short* __restrict__ wOM,
                const float* __restrict__ bh, const float* __restrict__ bv,
                const float* __restrict__ bm,
                float* __restrict__ off, float* __restrict__ msk) {
  int bid = blockIdx.x;            // 2 * 64 * 4 = 512
  int xb = bid & 3;
  int yb = (bid >> 2) & 63;
  int b  = bid >> 8;
  int y0 = yb * 2, x0 = xb * 32;
  int t = threadIdx.x;
  int l = t & 63, w = t >> 6;
  int row = w >> 1, xcol = (w & 1) * 16;
  int lan15 = l & 15, lhi = l >> 4;
  __shared__ unsigned short xs[16 * 46 * 40];   // 58,880 B
  f32x4 acc[3];
  #pragma unroll
  for (int m = 0; m < 3; ++m)
    #pragma unroll
    for (int r = 0; r < 4; ++r) acc[m][r] = 0.f;
  const unsigned short* hb = hbufT + ((long)b << 21);   // b*4*16384*32
  for (int cg = 0; cg < 4; ++cg) {
    __syncthreads();
    for (int j = t; j < 2944; j += 256) {     // 16*46*4 granules
      int g = j & 3;
      int rc = j >> 2;
      int c = rc % 46, r = rc / 46;
      int gy = y0 + r - 7, gx = x0 + c - 7;
      u16x8 v = {0, 0, 0, 0, 0, 0, 0, 0};
      if ((unsigned)gy < 128u && (unsigned)gx < 128u)
        v = *(const u16x8*)(hb + ((((long)cg << 14) + (gy << 7) + gx) << 5) + g * 8);
      *(u16x8*)(xs + (r * 46 + c) * 40 + g * 8) = v;
    }
    __syncthreads();
    int kbase = cg * 32 + lhi * 8;
    #pragma unroll
    for (int tap = 0; tap < 39; ++tap) {
      int ky = (tap < 15) ? 0 : ((tap < 30) ? (tap - 22) : ((tap - 30) / 3 - 1));
      int kx = (tap < 15) ? (tap - 7) : ((tap < 30) ? 0 : ((tap - 30) % 3 - 1));
      bf16x8 a0 = *(const bf16x8*)(wOM + ((tap * 48 + 0  + lan15) * 128 + kbase));
      bf16x8 a1 = *(const bf16x8*)(wOM + ((tap * 48 + 16 + lan15) * 128 + kbase));
      bf16x8 a2 = *(const bf16x8*)(wOM + ((tap * 48 + 32 + lan15) * 128 + kbase));
      int c = xcol + lan15 + kx + 7;
      int r = row + ky + 7;
      bf16x8 bfv = *(const bf16x8*)(xs + (r * 46 + c) * 40 + lhi * 8);
      acc[0] = __builtin_amdgcn_mfma_f32_16x16x32_bf16(a0, bfv, acc[0], 0, 0, 0);
      acc[1] = __builtin_amdgcn_mfma_f32_16x16x32_bf16(a1, bfv, acc[1], 0, 0, 0);
      acc[2] = __builtin_amdgcn_mfma_f32_16x16x32_bf16(a2, bfv, acc[2], 0, 0, 0);
    }
  }
  int y = y0 + row;
  int x = x0 + xcol + lan15;
  #pragma unroll
  for (int mt = 0; mt < 3; ++mt)
    #pragma unroll
    for (int reg = 0; reg < 4; ++reg) {
      int j = mt * 16 + lhi * 4 + reg;
      float v = acc[mt][reg];
      if (j < 18) {
        off[((long)(b * 18 + j) << 14) + (y << 7) + x] = v + bh[j] + bv[j];
      } else if (j < 27) {
        int jm = j - 18;
        msk[((long)(b * 9 + jm) << 14) + (y << 7) + x] = 1.f / (1.f + expf(-(v + bm[jm])));
      }
    }
}

// ---------------- K6: deformable 3x3 conv via MFMA bf16 ---------------------
__global__ __launch_bounds__(256, 2)
void k_deformm(const unsigned short* __restrict__ hbufT, const float* __restrict__ off,
               const float* __restrict__ msk, const unsigned short* __restrict__ wdefA,
               float* __restrict__ out) {
  int bid = blockIdx.x;            // 2 * 128 * 4 = 1024
  int xt = bid & 3;
  int h  = (bid >> 2) & 127;
  int b  = bid >> 9;
  int w0 = xt * 32;
  int t = threadIdx.x;
  int l = t & 63, w = t >> 6;
  int lan15 = l & 15, lhi = l >> 4;

  __shared__ __align__(16) unsigned short S[9][32][40];  // 23,040 B
  __shared__ int   p_y0[288], p_x0[288];
  __shared__ float p_w00[288], p_w01[288], p_w10[288], p_w11[288];

  for (int idx = t; idx < 288; idx += 256) {
    int k = idx >> 5, pix = idx & 31;
    int sp = (h << 7) + w0 + pix;
    float dy = off[((long)(b * 18 + 2 * k) << 14) + sp];
    float dx = off[((long)(b * 18 + 2 * k + 1) << 14) + sp];
    float m  = msk[((long)(b * 9 + k) << 14) + sp];
    float y  = dy + (float)(h + k / 3 - 1);
    float xx = dx + (float)(w0 + pix + (k % 3) - 1);
    float y0f = floorf(y), x0f = floorf(xx);
    float wy = y - y0f, wx = xx - x0f;
    p_y0[idx] = (int)y0f; p_x0[idx] = (int)x0f;
    p_w00[idx] = (1.f - wy) * (1.f - wx) * m;
    p_w01[idx] = (1.f - wy) * wx * m;
    p_w10[idx] = wy * (1.f - wx) * m;
    p_w11[idx] = wy * wx * m;
  }

  f32x4 acc[2][2];
  #pragma unroll
  for (int m = 0; m < 2; ++m)
    #pragma unroll
    for (int n = 0; n < 2; ++n)
      #pragma unroll
      for (int r = 0; r < 4; ++r) acc[m][n][r] = 0.f;

  for (int cg = 0; cg < 4; ++cg) {
    __syncthreads();   // offsets ready (cg=0); previous MFMA reads done (cg>0)
    const unsigned short* hb = hbufT + (((long)(b * 4 + cg)) << 19);
    for (int idx = t; idx < 1152; idx += 256) {   // 9k * 32pix * 4cq
      int cq = idx & 3, pix = (idx >> 2) & 31, k = idx >> 7;
      int kp = (k << 5) + pix;
      int y0 = p_y0[kp], x0 = p_x0[kp];
      float c00 = p_w00[kp], c01 = p_w01[kp], c10 = p_w10[kp], c11 = p_w11[kp];
      bool yi0 = (unsigned)y0 < 128u, yi1 = (unsigned)(y0 + 1) < 128u;
      bool xi0 = (unsigned)x0 < 128u, xi1 = (unsigned)(x0 + 1) < 128u;
      const unsigned short* pbase = hb + ((((long)(y0 << 7) + x0) << 5) + cq * 8);
      u16x8 z = {0, 0, 0, 0, 0, 0, 0, 0};
      u16x8 v00 = (yi0 && xi0) ? *(const u16x8*)pbase          : z;
      u16x8 v01 = (yi0 && xi1) ? *(const u16x8*)(pbase + 32)   : z;
      u16x8 v10 = (yi1 && xi0) ? *(const u16x8*)(pbase + 4096) : z;
      u16x8 v11 = (yi1 && xi1) ? *(const u16x8*)(pbase + 4128) : z;
      u16x8 o;
      #pragma unroll
      for (int j = 0; j < 8; ++j) {
        float s = c00 * __uint_as_float((unsigned)(unsigned short)v00[j] << 16)
                + c01 * __uint_as_float((unsigned)(unsigned short)v01[j] << 16)
                + c10 * __uint_as_float((unsigned)(unsigned short)v10[j] << 16)
                + c11 * __uint_as_float((unsigned)(unsigned short)v11[j] << 16);
        o[j] = f2bf(s);
      }
      *(u16x8*)(&S[k][pix][cq * 8]) = o;
    }
    bf16x8 af0[9], af1[9];
    #pragma unroll
    for (int k = 0; k < 9; ++k) {
      long wbase = ((((long)(cg * 9 + k) * 4 + lhi) * 128) + w * 32 + lan15) * 8;
      af0[k] = *(const bf16x8*)(wdefA + wbase);
      af1[k] = *(const bf16x8*)(wdefA + wbase + 128);   // +16 oc
    }
    __syncthreads();
    #pragma unroll
    for (int k = 0; k < 9; ++k) {
      #pragma unroll
      for (int nt = 0; nt < 2; ++nt) {
        bf16x8 bfv = *(const bf16x8*)(&S[k][nt * 16 + lan15][lhi * 8]);
        acc[0][nt] = __builtin_amdgcn_mfma_f32_16x16x32_bf16(af0[k], bfv, acc[0][nt], 0, 0, 0);
        acc[1][nt] = __builtin_amdgcn_mfma_f32_16x16x32_bf16(af1[k], bfv, acc[1][nt], 0, 0, 0);
      }
    }
  }
  #pragma unroll
  for (int mt = 0; mt < 2; ++mt)
    #pragma unroll
    for (int reg = 0; reg < 4; ++reg) {
      int oc = w * 32 + mt * 16 + lhi * 4 + reg;
      long obase = ((long)(b * 128 + oc) << 14) + (h << 7) + w0;
      out[obase + lan15]      = acc[mt][0][reg];
      out[obase + 16 + lan15] = acc[mt][1][reg];
    }
}

// ---------------- K8: plain bn+relu (final output) --------------------------
__global__ void k_bnrelu(const float4* __restrict__ src, const float* __restrict__ mean,
                         const float* __restrict__ rstd, const float* __restrict__ g,
                         const float* __restrict__ be, float4* __restrict__ dst) {
  int i = blockIdx.x * 256 + threadIdx.x;   // over 1,048,576 float4
  if (i >= 1048576) return;
  int c = (i >> 12) & 127;
  float sc = rstd[c] * g[c];
  float bb = be[c] - mean[c] * sc;
  float4 v = src[i];
  v.x = fmaxf(v.x * sc + bb, 0.f);
  v.y = fmaxf(v.y * sc + bb, 0.f);
  v.z = fmaxf(v.z * sc + bb, 0.f);
  v.w = fmaxf(v.w * sc + bb, 0.f);
  dst[i] = v;
}

// ---------------- launcher --------------------------------------------------
extern "C" void kernel_launch(void* const* d_in, const int* in_sizes, int n_in,
                              void* d_out, int out_size, void* d_ws, size_t ws_size,
                              hipStream_t stream) {
  const float* x      = (const float*)d_in[0];
  const float* skip   = (const float*)d_in[1];
  const float* w_up   = (const float*)d_in[2];
  const float* b_up   = (const float*)d_in[3];
  const float* w_ref  = (const float*)d_in[4];
  const float* b_ref  = (const float*)d_in[5];
  const float* g1     = (const float*)d_in[6];
  const float* be1    = (const float*)d_in[7];
  const float* w_offh = (const float*)d_in[8];
  const float* b_offh = (const float*)d_in[9];
  const float* w_offv = (const float*)d_in[10];
  const float* b_offv = (const float*)d_in[11];
  const float* w_mask = (const float*)d_in[12];
  const float* b_mask = (const float*)d_in[13];
  const float* w_def  = (const float*)d_in[14];
  const float* g2     = (const float*)d_in[15];
  const float* be2    = (const float*)d_in[16];

  char* W = (char*)d_ws;
  unsigned short* catT  = (unsigned short*)W;                 // 16,777,216 B
  float*          tmp1  = (float*)(W + 16777216);             // 16 MB
  unsigned short* hbufT = (unsigned short*)(W + 33554432);    // 8,388,608 B
  float*          offb  = (float*)(W + 41943040);             // 2,359,296 B
  float*          mskb  = (float*)(W + 44302336);             // 1,179,648 B
  float*          stat  = (float*)(W + 45481984);             // 2,048 B
  unsigned short* wbT   = (unsigned short*)(W + 45484032);    // 589,824 B
  unsigned short* wOM   = (unsigned short*)(W + 46073856);    // 479,232 B
  unsigned short* wdefA = (unsigned short*)(W + 46553088);    // 294,912 B
  float*          dpre  = (float*)W;                          // alias catT (dead)

  hipLaunchKernelGGL(k_wrefT, dim3(1152), dim3(256), 0, stream, w_ref, wbT);
  hipLaunchKernelGGL(k_womT, dim3(936), dim3(256), 0, stream, w_offh, w_offv, w_mask, wOM);
  hipLaunchKernelGGL(k_wdefA, dim3(576), dim3(256), 0, stream, w_def, wdefA);
  hipLaunchKernelGGL(k_upsampleT, dim3(1024), dim3(256), 0, stream, x, w_up, b_up, catT);
  hipLaunchKernelGGL(k_skipT, dim3(2048), dim3(256), 0, stream, skip, catT);
  hipLaunchKernelGGL(k_conv3m, dim3(512), dim3(256), 0, stream, catT, wbT, b_ref, tmp1);
  hipLaunchKernelGGL(k_bnstats, dim3(128), dim3(256), 0, stream, tmp1, stat, stat + 128);
  hipLaunchKernelGGL(k_bnrelu2, dim3(2048), dim3(256), 0, stream, tmp1, stat, stat + 128,
                     g1, be1, hbufT);
  hipLaunchKernelGGL(k_offmaskm, dim3(512), dim3(256), 0, stream, hbufT, wOM,
                     b_offh, b_offv, b_mask, offb, mskb);
  hipLaunchKernelGGL(k_deformm, dim3(1024), dim3(256), 0, stream, hbufT, offb, mskb,
                     wdefA, dpre);
  hipLaunchKernelGGL(k_bnstats, dim3(128), dim3(256), 0, stream, dpre, stat + 256, stat + 384);
  hipLaunchKernelGGL(k_bnrelu, dim3(4096), dim3(256), 0, stream,
                     (const float4*)dpre, stat + 256, stat + 384, g2, be2, (float4*)d_out);
}

// Round 5
// 245.630 us; speedup vs baseline: 8.0208x; 1.1388x over previous
//
#include <hip/hip_runtime.h>
#include <hip/hip_bf16.h>

typedef __attribute__((ext_vector_type(8))) short bf16x8;
typedef __attribute__((ext_vector_type(4))) float f32x4;
typedef __attribute__((ext_vector_type(8))) unsigned short u16x8;

static __device__ __forceinline__ unsigned short f2bf(float f) {
  union { float f; unsigned u; } v; v.f = f;
  unsigned r = v.u + 0x7fff + ((v.u >> 16) & 1);
  return (unsigned short)(r >> 16);
}

// ---------------- K1: transposed-conv 2x2 s2 -> catT chunks 0..3 (bf16) -----
__global__ void k_upsampleT(const float* __restrict__ x, const float* __restrict__ w_up,
                            const float* __restrict__ b_up, unsigned short* __restrict__ catT) {
  int bid = blockIdx.x;            // 2 * 64 * 8 = 1024
  int wt = bid & 7;
  int hh = (bid >> 3) & 63;
  int b  = bid >> 9;
  int t = threadIdx.x;
  __shared__ float xs[256][8];
  int ww0 = wt * 8;
  int pix = t & 7, icb = t >> 3;
  #pragma unroll
  for (int r = 0; r < 8; ++r) {
    int ic = r * 32 + icb;
    xs[ic][pix] = x[((b * 256 + ic) * 64 + hh) * 64 + ww0 + pix];
  }
  __syncthreads();
  int oc = t & 127, g = t >> 7;    // g = kh
  float bias = b_up[oc];
  float acc0[8], acc1[8];
  #pragma unroll
  for (int p = 0; p < 8; ++p) { acc0[p] = bias; acc1[p] = bias; }
  for (int i = 0; i < 256; ++i) {
    float wv0 = w_up[((i * 128 + oc) * 2 + g) * 2 + 0];
    float wv1 = w_up[((i * 128 + oc) * 2 + g) * 2 + 1];
    #pragma unroll
    for (int p = 0; p < 8; ++p) {
      float xv = xs[i][p];
      acc0[p] += xv * wv0;
      acc1[p] += xv * wv1;
    }
  }
  int h = 2 * hh + g;
  int cg = oc >> 5, icl = oc & 31;
  long plane = ((long)(b * 8 + cg) << 14) + (h << 7);
  #pragma unroll
  for (int p = 0; p < 8; ++p) {
    int w0c = 2 * (ww0 + p);
    catT[((plane + w0c) << 5) + icl]     = f2bf(acc0[p]);
    catT[((plane + w0c + 1) << 5) + icl] = f2bf(acc1[p]);
  }
}

// ---------------- K1b: skip -> catT chunks 4..7 (bf16, LDS transpose) -------
__global__ void k_skipT(const float* __restrict__ skip, unsigned short* __restrict__ catT) {
  int bid = blockIdx.x;            // 2 * 4 * 128 * 2 = 2048
  int xb = bid & 1;
  int y  = (bid >> 1) & 127;
  int cg = (bid >> 8) & 3;
  int b  = bid >> 10;
  int t = threadIdx.x;
  __shared__ float ts[32][65];
  int x = t & 63, c4 = t >> 6, x0 = xb * 64;
  #pragma unroll
  for (int p = 0; p < 8; ++p) {
    int c = p * 4 + c4;
    ts[c][x] = skip[(((long)(b * 128 + cg * 32 + c)) << 14) + (y << 7) + x0 + x];
  }
  __syncthreads();
  int ic = t & 31, xg = t >> 5;
  long plane = ((long)(b * 8 + 4 + cg) << 14) + (y << 7) + x0;
  #pragma unroll
  for (int q = 0; q < 8; ++q) {
    int xx = xg * 8 + q;
    catT[((plane + xx) << 5) + ic] = f2bf(ts[ic][xx]);
  }
}

// ---------------- weight repack: w_ref -> wbT[tap][oc][ic] bf16 -------------
__global__ void k_wrefT(const float* __restrict__ wr, unsigned short* __restrict__ wbT) {
  int idx = blockIdx.x * 256 + threadIdx.x;   // 294,912
  int tap = idx >> 15;
  int rem = idx & 32767;
  int oc = rem >> 8, ic = rem & 255;
  wbT[idx] = f2bf(wr[(oc * 256 + ic) * 9 + tap]);
}

// ---------------- weight build: wOM[39][48][128] bf16 -----------------------
__global__ void k_womT(const float* __restrict__ wh, const float* __restrict__ wv,
                       const float* __restrict__ wm, unsigned short* __restrict__ wOM) {
  int idx = blockIdx.x * 256 + threadIdx.x;   // 239,616 = 39*48*128
  int tap = idx / 6144;
  int rem = idx - tap * 6144;
  int j = rem >> 7, ic = rem & 127;
  float v = 0.f;
  if (tap < 15) {
    if (j < 18) v = wh[(j * 128 + ic) * 15 + tap];
  } else if (tap < 30) {
    if (j < 18) v = wv[(j * 128 + ic) * 15 + (tap - 15)];
  } else {
    if (j >= 18 && j < 27) v = wm[((j - 18) * 128 + ic) * 9 + (tap - 30)];
  }
  wOM[idx] = f2bf(v);
}

// ---------------- weight repack: w_def -> MFMA-A fragment order bf16 --------
// wdefA[((ks*4 + lhi)*128 + oc)*8 + j]  where ks = cg*9+k, channel = cg*32+lhi*8+j
__global__ void k_wdefA(const float* __restrict__ wd, unsigned short* __restrict__ wdefA) {
  int idx = blockIdx.x * 256 + threadIdx.x;   // 147,456
  if (idx >= 147456) return;
  int j   = idx & 7;
  int oc  = (idx >> 3) & 127;
  int lhi = (idx >> 10) & 3;
  int ks  = idx >> 12;               // 0..35
  int k = ks % 9, cg = ks / 9;
  int c = cg * 32 + lhi * 8 + j;
  wdefA[idx] = f2bf(wd[(oc * 128 + c) * 9 + k]);
}

// ---------------- K2: 3x3 conv 256->128 via MFMA bf16 -----------------------
__global__ __launch_bounds__(256, 2)
void k_conv3m(const unsigned short* __restrict__ catT, const unsigned short* __restrict__ wbT,
              const float* __restrict__ br, float* __restrict__ out) {
  int bid = blockIdx.x;            // 2 * 128 * 2 = 512
  int xt = bid & 1;
  int y  = (bid >> 1) & 127;
  int b  = bid >> 8;
  int x0 = xt * 64;
  int t = threadIdx.x;
  int l = t & 63, w = t >> 6;
  __shared__ unsigned short xs[3 * 66 * 40];   // [r][c][ic pad 40] 15,840 B
  f32x4 acc[2][4];
  #pragma unroll
  for (int m = 0; m < 2; ++m)
    #pragma unroll
    for (int n = 0; n < 4; ++n)
      #pragma unroll
      for (int r = 0; r < 4; ++r) acc[m][n][r] = 0.f;
  const unsigned short* catb = catT + ((long)b << 22);   // b*8*16384*32
  int lan15 = l & 15, lhi = l >> 4;
  for (int cg = 0; cg < 8; ++cg) {
    __syncthreads();
    for (int j = t; j < 792; j += 256) {       // 3*66*4 granules
      int g = j & 3;
      int rc = j >> 2;
      int c = rc % 66, r = rc / 66;
      int gy = y + r - 1, gx = x0 + c - 1;
      u16x8 v = {0, 0, 0, 0, 0, 0, 0, 0};
      if ((unsigned)gy < 128u && (unsigned)gx < 128u)
        v = *(const u16x8*)(catb + ((((long)cg << 14) + (gy << 7) + gx) << 5) + g * 8);
      *(u16x8*)(xs + (r * 66 + c) * 40 + g * 8) = v;
    }
    bf16x8 af[2][9];
    int kbase = cg * 32 + lhi * 8;
    #pragma unroll
    for (int mt = 0; mt < 2; ++mt)
      #pragma unroll
      for (int tap = 0; tap < 9; ++tap)
        af[mt][tap] = *(const bf16x8*)(wbT + ((tap * 128 + w * 32 + mt * 16 + lan15) * 256 + kbase));
    __syncthreads();
    #pragma unroll
    for (int tap = 0; tap < 9; ++tap) {
      int ky = tap / 3, kx = tap % 3;
      #pragma unroll
      for (int nt = 0; nt < 4; ++nt) {
        int c = nt * 16 + lan15 + kx;
        bf16x8 bfv = *(const bf16x8*)(xs + ((ky * 66 + c) * 40) + lhi * 8);
        acc[0][nt] = __builtin_amdgcn_mfma_f32_16x16x32_bf16(af[0][tap], bfv, acc[0][nt], 0, 0, 0);
        acc[1][nt] = __builtin_amdgcn_mfma_f32_16x16x32_bf16(af[1][tap], bfv, acc[1][nt], 0, 0, 0);
      }
    }
  }
  #pragma unroll
  for (int mt = 0; mt < 2; ++mt)
    #pragma unroll
    for (int reg = 0; reg < 4; ++reg) {
      int oc = w * 32 + mt * 16 + lhi * 4 + reg;
      float bias = br[oc];
      long obase = ((long)(b * 128 + oc) << 14) + (y << 7);
      #pragma unroll
      for (int nt = 0; nt < 4; ++nt)
        out[obase + x0 + nt * 16 + lan15] = acc[mt][nt][reg] + bias;
    }
}

// ---------------- K3/K7: per-channel batch-norm stats -----------------------
__global__ void k_bnstats(const float* __restrict__ src, float* __restrict__ mean,
                          float* __restrict__ rstd) {
  int c = blockIdx.x, t = threadIdx.x;
  float s = 0.f, s2 = 0.f;
  for (int b = 0; b < 2; ++b) {
    const float4* p4 = (const float4*)(src + ((long)(b * 128 + c) << 14));
    for (int i = t; i < 4096; i += 256) {
      float4 v = p4[i];
      s  += v.x + v.y + v.z + v.w;
      s2 += v.x * v.x + v.y * v.y + v.z * v.z + v.w * v.w;
    }
  }
  #pragma unroll
  for (int off = 32; off; off >>= 1) {
    s  += __shfl_down(s, off);
    s2 += __shfl_down(s2, off);
  }
  __shared__ float as[4], as2[4];
  int wid = t >> 6;
  if ((t & 63) == 0) { as[wid] = s; as2[wid] = s2; }
  __syncthreads();
  if (t == 0) {
    float S = as[0] + as[1] + as[2] + as[3];
    float S2 = as2[0] + as2[1] + as2[2] + as2[3];
    float m = S / 32768.f;
    float var = S2 / 32768.f - m * m;
    mean[c] = m;
    rstd[c] = rsqrtf(var + 1e-5f);
  }
}

// ---------------- K4: bn+relu -> hbufT bf16 chunked only --------------------
__global__ void k_bnrelu2(const float* __restrict__ tmp1, const float* __restrict__ mean,
                          const float* __restrict__ rstd, const float* __restrict__ g,
                          const float* __restrict__ be, unsigned short* __restrict__ hbufT) {
  int bid = blockIdx.x;            // 2048
  int xb = bid & 1;
  int y  = (bid >> 1) & 127;
  int cg = (bid >> 8) & 3;
  int b  = bid >> 10;
  int t = threadIdx.x;
  __shared__ float ts[32][65];
  int x = t & 63, c4 = t >> 6, x0 = xb * 64;
  #pragma unroll
  for (int p = 0; p < 8; ++p) {
    int c = p * 4 + c4;
    int ch = cg * 32 + c;
    float sc = rstd[ch] * g[ch];
    float bb = be[ch] - mean[ch] * sc;
    long idx = ((long)(b * 128 + ch) << 14) + (y << 7) + x0 + x;
    ts[c][x] = fmaxf(tmp1[idx] * sc + bb, 0.f);
  }
  __syncthreads();
  int ic = t & 31, xg = t >> 5;
  long plane = ((long)(b * 4 + cg) << 14) + (y << 7) + x0;
  #pragma unroll
  for (int q = 0; q < 8; ++q) {
    int xx = xg * 8 + q;
    hbufT[((plane + xx) << 5) + ic] = f2bf(ts[ic][xx]);
  }
}

// ---------------- K5: offsets + mask via MFMA bf16, direct-from-global ------
__global__ __launch_bounds__(256, 4)
void k_offmaskd(const unsigned short* __restrict__ hbufT, const unsigned short* __restrict__ wOM,
                const float* __restrict__ bh, const float* __restrict__ bv,
                const float* __restrict__ bm,
                float* __restrict__ off, float* __restrict__ msk) {
  int bid = blockIdx.x;            // 512 = 2 batches * 256; block = 64 px (4 waves x 16)
  int t = threadIdx.x;
  int l = t & 63, w = t >> 6;
  int lan15 = l & 15, lhi = l >> 4;
  int b = bid >> 8;
  int px0 = (bid & 255) * 64 + w * 16;
  int y = px0 >> 7, x0 = px0 & 127;
  int x = x0 + lan15;

  f32x4 acc0, acc1;
  #pragma unroll
  for (int r = 0; r < 4; ++r) { acc0[r] = 0.f; acc1[r] = 0.f; }

  const unsigned short* hb = hbufT + ((long)b << 21);
  const u16x8 z = {0, 0, 0, 0, 0, 0, 0, 0};

  #pragma unroll
  for (int tap = 0; tap < 39; ++tap) {
    int ky = (tap < 15) ? 0 : ((tap < 30) ? (tap - 22) : ((tap - 30) / 3 - 1));
    int kx = (tap < 15) ? (tap - 7) : ((tap < 30) ? 0 : ((tap - 30) % 3 - 1));
    int gy = y + ky, gx = x + kx;
    bool valid = ((unsigned)gy < 128u) & ((unsigned)gx < 128u);
    const unsigned short* bp = hb + ((((long)(gy << 7) + gx) << 5) + lhi * 8);
    const unsigned short* ap = wOM + (tap * 48 + lan15) * 128 + lhi * 8;
    #pragma unroll
    for (int cg = 0; cg < 4; ++cg) {
      u16x8 bv8 = valid ? *(const u16x8*)(bp + ((long)cg << 19)) : z;
      bf16x8 bf = (bf16x8)bv8;
      bf16x8 a1 = *(const bf16x8*)(ap + 16 * 128 + cg * 32);
      acc1 = __builtin_amdgcn_mfma_f32_16x16x32_bf16(a1, bf, acc1, 0, 0, 0);
      if (tap < 30) {          // j rows 0-15 only nonzero for offset taps
        bf16x8 a0 = *(const bf16x8*)(ap + cg * 32);
        acc0 = __builtin_amdgcn_mfma_f32_16x16x32_bf16(a0, bf, acc0, 0, 0, 0);
      }
    }
  }

  int sp = (y << 7) + x;
  #pragma unroll
  for (int reg = 0; reg < 4; ++reg) {
    int j0 = lhi * 4 + reg;        // 0..15, all offsets
    off[((long)(b * 18 + j0) << 14) + sp] = acc0[reg] + bh[j0] + bv[j0];
    int j1 = 16 + lhi * 4 + reg;   // 16..31
    float v = acc1[reg];
    if (j1 < 18) {
      off[((long)(b * 18 + j1) << 14) + sp] = v + bh[j1] + bv[j1];
    } else if (j1 < 27) {
      int jm = j1 - 18;
      msk[((long)(b * 9 + jm) << 14) + sp] = 1.f / (1.f + expf(-(v + bm[jm])));
    }
  }
}

// ---------------- K6: deformable 3x3 conv via MFMA bf16 ---------------------
__global__ __launch_bounds__(256, 2)
void k_deformm(const unsigned short* __restrict__ hbufT, const float* __restrict__ off,
               const float* __restrict__ msk, const unsigned short* __restrict__ wdefA,
               float* __restrict__ out) {
  int bid = blockIdx.x;            // 2 * 128 * 4 = 1024
  int xt = bid & 3;
  int h  = (bid >> 2) & 127;
  int b  = bid >> 9;
  int w0 = xt * 32;
  int t = threadIdx.x;
  int l = t & 63, w = t >> 6;
  int lan15 = l & 15, lhi = l >> 4;

  __shared__ __align__(16) unsigned short S[9][32][40];  // 23,040 B
  __shared__ int   p_y0[288], p_x0[288];
  __shared__ float p_w00[288], p_w01[288], p_w10[288], p_w11[288];

  for (int idx = t; idx < 288; idx += 256) {
    int k = idx >> 5, pix = idx & 31;
    int sp = (h << 7) + w0 + pix;
    float dy = off[((long)(b * 18 + 2 * k) << 14) + sp];
    float dx = off[((long)(b * 18 + 2 * k + 1) << 14) + sp];
    float m  = msk[((long)(b * 9 + k) << 14) + sp];
    float y  = dy + (float)(h + k / 3 - 1);
    float xx = dx + (float)(w0 + pix + (k % 3) - 1);
    float y0f = floorf(y), x0f = floorf(xx);
    float wy = y - y0f, wx = xx - x0f;
    p_y0[idx] = (int)y0f; p_x0[idx] = (int)x0f;
    p_w00[idx] = (1.f - wy) * (1.f - wx) * m;
    p_w01[idx] = (1.f - wy) * wx * m;
    p_w10[idx] = wy * (1.f - wx) * m;
    p_w11[idx] = wy * wx * m;
  }

  f32x4 acc[2][2];
  #pragma unroll
  for (int m = 0; m < 2; ++m)
    #pragma unroll
    for (int n = 0; n < 2; ++n)
      #pragma unroll
      for (int r = 0; r < 4; ++r) acc[m][n][r] = 0.f;

  for (int cg = 0; cg < 4; ++cg) {
    __syncthreads();   // offsets ready (cg=0); previous MFMA reads done (cg>0)
    const unsigned short* hb = hbufT + (((long)(b * 4 + cg)) << 19);
    for (int idx = t; idx < 1152; idx += 256) {   // 9k * 32pix * 4cq
      int cq = idx & 3, pix = (idx >> 2) & 31, k = idx >> 7;
      int kp = (k << 5) + pix;
      int y0 = p_y0[kp], x0 = p_x0[kp];
      float c00 = p_w00[kp], c01 = p_w01[kp], c10 = p_w10[kp], c11 = p_w11[kp];
      bool yi0 = (unsigned)y0 < 128u, yi1 = (unsigned)(y0 + 1) < 128u;
      bool xi0 = (unsigned)x0 < 128u, xi1 = (unsigned)(x0 + 1) < 128u;
      const unsigned short* pbase = hb + ((((long)(y0 << 7) + x0) << 5) + cq * 8);
      u16x8 z = {0, 0, 0, 0, 0, 0, 0, 0};
      u16x8 v00 = (yi0 && xi0) ? *(const u16x8*)pbase          : z;
      u16x8 v01 = (yi0 && xi1) ? *(const u16x8*)(pbase + 32)   : z;
      u16x8 v10 = (yi1 && xi0) ? *(const u16x8*)(pbase + 4096) : z;
      u16x8 v11 = (yi1 && xi1) ? *(const u16x8*)(pbase + 4128) : z;
      u16x8 o;
      #pragma unroll
      for (int j = 0; j < 8; ++j) {
        float s = c00 * __uint_as_float((unsigned)(unsigned short)v00[j] << 16)
                + c01 * __uint_as_float((unsigned)(unsigned short)v01[j] << 16)
                + c10 * __uint_as_float((unsigned)(unsigned short)v10[j] << 16)
                + c11 * __uint_as_float((unsigned)(unsigned short)v11[j] << 16);
        o[j] = f2bf(s);
      }
      *(u16x8*)(&S[k][pix][cq * 8]) = o;
    }
    bf16x8 af0[9], af1[9];
    #pragma unroll
    for (int k = 0; k < 9; ++k) {
      long wbase = ((((long)(cg * 9 + k) * 4 + lhi) * 128) + w * 32 + lan15) * 8;
      af0[k] = *(const bf16x8*)(wdefA + wbase);
      af1[k] = *(const bf16x8*)(wdefA + wbase + 128);   // +16 oc
    }
    __syncthreads();
    #pragma unroll
    for (int k = 0; k < 9; ++k) {
      #pragma unroll
      for (int nt = 0; nt < 2; ++nt) {
        bf16x8 bfv = *(const bf16x8*)(&S[k][nt * 16 + lan15][lhi * 8]);
        acc[0][nt] = __builtin_amdgcn_mfma_f32_16x16x32_bf16(af0[k], bfv, acc[0][nt], 0, 0, 0);
        acc[1][nt] = __builtin_amdgcn_mfma_f32_16x16x32_bf16(af1[k], bfv, acc[1][nt], 0, 0, 0);
      }
    }
  }
  #pragma unroll
  for (int mt = 0; mt < 2; ++mt)
    #pragma unroll
    for (int reg = 0; reg < 4; ++reg) {
      int oc = w * 32 + mt * 16 + lhi * 4 + reg;
      long obase = ((long)(b * 128 + oc) << 14) + (h << 7) + w0;
      out[obase + lan15]      = acc[mt][0][reg];
      out[obase + 16 + lan15] = acc[mt][1][reg];
    }
}

// ---------------- K8: plain bn+relu (final output) --------------------------
__global__ void k_bnrelu(const float4* __restrict__ src, const float* __restrict__ mean,
                         const float* __restrict__ rstd, const float* __restrict__ g,
                         const float* __restrict__ be, float4* __restrict__ dst) {
  int i = blockIdx.x * 256 + threadIdx.x;   // over 1,048,576 float4
  if (i >= 1048576) return;
  int c = (i >> 12) & 127;
  float sc = rstd[c] * g[c];
  float bb = be[c] - mean[c] * sc;
  float4 v = src[i];
  v.x = fmaxf(v.x * sc + bb, 0.f);
  v.y = fmaxf(v.y * sc + bb, 0.f);
  v.z = fmaxf(v.z * sc + bb, 0.f);
  v.w = fmaxf(v.w * sc + bb, 0.f);
  dst[i] = v;
}

// ---------------- launcher --------------------------------------------------
extern "C" void kernel_launch(void* const* d_in, const int* in_sizes, int n_in,
                              void* d_out, int out_size, void* d_ws, size_t ws_size,
                              hipStream_t stream) {
  const float* x      = (const float*)d_in[0];
  const float* skip   = (const float*)d_in[1];
  const float* w_up   = (const float*)d_in[2];
  const float* b_up   = (const float*)d_in[3];
  const float* w_ref  = (const float*)d_in[4];
  const float* b_ref  = (const float*)d_in[5];
  const float* g1     = (const float*)d_in[6];
  const float* be1    = (const float*)d_in[7];
  const float* w_offh = (const float*)d_in[8];
  const float* b_offh = (const float*)d_in[9];
  const float* w_offv = (const float*)d_in[10];
  const float* b_offv = (const float*)d_in[11];
  const float* w_mask = (const float*)d_in[12];
  const float* b_mask = (const float*)d_in[13];
  const float* w_def  = (const float*)d_in[14];
  const float* g2     = (const float*)d_in[15];
  const float* be2    = (const float*)d_in[16];

  char* W = (char*)d_ws;
  unsigned short* catT  = (unsigned short*)W;                 // 16,777,216 B
  float*          tmp1  = (float*)(W + 16777216);             // 16 MB
  unsigned short* hbufT = (unsigned short*)(W + 33554432);    // 8,388,608 B
  float*          offb  = (float*)(W + 41943040);             // 2,359,296 B
  float*          mskb  = (float*)(W + 44302336);             // 1,179,648 B
  float*          stat  = (float*)(W + 45481984);             // 2,048 B
  unsigned short* wbT   = (unsigned short*)(W + 45484032);    // 589,824 B
  unsigned short* wOM   = (unsigned short*)(W + 46073856);    // 479,232 B
  unsigned short* wdefA = (unsigned short*)(W + 46553088);    // 294,912 B
  float*          dpre  = (float*)W;                          // alias catT (dead)

  hipLaunchKernelGGL(k_wrefT, dim3(1152), dim3(256), 0, stream, w_ref, wbT);
  hipLaunchKernelGGL(k_womT, dim3(936), dim3(256), 0, stream, w_offh, w_offv, w_mask, wOM);
  hipLaunchKernelGGL(k_wdefA, dim3(576), dim3(256), 0, stream, w_def, wdefA);
  hipLaunchKernelGGL(k_upsampleT, dim3(1024), dim3(256), 0, stream, x, w_up, b_up, catT);
  hipLaunchKernelGGL(k_skipT, dim3(2048), dim3(256), 0, stream, skip, catT);
  hipLaunchKernelGGL(k_conv3m, dim3(512), dim3(256), 0, stream, catT, wbT, b_ref, tmp1);
  hipLaunchKernelGGL(k_bnstats, dim3(128), dim3(256), 0, stream, tmp1, stat, stat + 128);
  hipLaunchKernelGGL(k_bnrelu2, dim3(2048), dim3(256), 0, stream, tmp1, stat, stat + 128,
                     g1, be1, hbufT);
  hipLaunchKernelGGL(k_offmaskd, dim3(512), dim3(256), 0, stream, hbufT, wOM,
                     b_offh, b_offv, b_mask, offb, mskb);
  hipLaunchKernelGGL(k_deformm, dim3(1024), dim3(256), 0, stream, hbufT, offb, mskb,
                     wdefA, dpre);
  hipLaunchKernelGGL(k_bnstats, dim3(128), dim3(256), 0, stream, dpre, stat + 256, stat + 384);
  hipLaunchKernelGGL(k_bnrelu, dim3(4096), dim3(256), 0, stream,
                     (const float4*)dpre, stat + 256, stat + 384, g2, be2, (float4*)d_out);
}

// Round 6
// 243.564 us; speedup vs baseline: 8.0888x; 1.0085x over previous
//
#include <hip/hip_runtime.h>
#include <hip/hip_bf16.h>

typedef __attribute__((ext_vector_type(8))) short bf16x8;
typedef __attribute__((ext_vector_type(4))) float f32x4;
typedef __attribute__((ext_vector_type(8))) unsigned short u16x8;

static __device__ __forceinline__ unsigned short f2bf(float f) {
  union { float f; unsigned u; } v; v.f = f;
  unsigned r = v.u + 0x7fff + ((v.u >> 16) & 1);
  return (unsigned short)(r >> 16);
}

// ---------------- K1: transposed-conv 2x2 s2 -> catT chunks 0..3 (bf16) -----
__global__ void k_upsampleT(const float* __restrict__ x, const float* __restrict__ w_up,
                            const float* __restrict__ b_up, unsigned short* __restrict__ catT) {
  int bid = blockIdx.x;            // 2 * 64 * 8 = 1024
  int wt = bid & 7;
  int hh = (bid >> 3) & 63;
  int b  = bid >> 9;
  int t = threadIdx.x;
  __shared__ float xs[256][8];
  int ww0 = wt * 8;
  int pix = t & 7, icb = t >> 3;
  #pragma unroll
  for (int r = 0; r < 8; ++r) {
    int ic = r * 32 + icb;
    xs[ic][pix] = x[((b * 256 + ic) * 64 + hh) * 64 + ww0 + pix];
  }
  __syncthreads();
  int oc = t & 127, g = t >> 7;    // g = kh
  float bias = b_up[oc];
  float acc0[8], acc1[8];
  #pragma unroll
  for (int p = 0; p < 8; ++p) { acc0[p] = bias; acc1[p] = bias; }
  for (int i = 0; i < 256; ++i) {
    float wv0 = w_up[((i * 128 + oc) * 2 + g) * 2 + 0];
    float wv1 = w_up[((i * 128 + oc) * 2 + g) * 2 + 1];
    #pragma unroll
    for (int p = 0; p < 8; ++p) {
      float xv = xs[i][p];
      acc0[p] += xv * wv0;
      acc1[p] += xv * wv1;
    }
  }
  int h = 2 * hh + g;
  int cg = oc >> 5, icl = oc & 31;
  long plane = ((long)(b * 8 + cg) << 14) + (h << 7);
  #pragma unroll
  for (int p = 0; p < 8; ++p) {
    int w0c = 2 * (ww0 + p);
    catT[((plane + w0c) << 5) + icl]     = f2bf(acc0[p]);
    catT[((plane + w0c + 1) << 5) + icl] = f2bf(acc1[p]);
  }
}

// ---------------- K1b: skip -> catT chunks 4..7 (bf16, LDS transpose) -------
__global__ void k_skipT(const float* __restrict__ skip, unsigned short* __restrict__ catT) {
  int bid = blockIdx.x;            // 2 * 4 * 128 * 2 = 2048
  int xb = bid & 1;
  int y  = (bid >> 1) & 127;
  int cg = (bid >> 8) & 3;
  int b  = bid >> 10;
  int t = threadIdx.x;
  __shared__ float ts[32][65];
  int x = t & 63, c4 = t >> 6, x0 = xb * 64;
  #pragma unroll
  for (int p = 0; p < 8; ++p) {
    int c = p * 4 + c4;
    ts[c][x] = skip[(((long)(b * 128 + cg * 32 + c)) << 14) + (y << 7) + x0 + x];
  }
  __syncthreads();
  int ic = t & 31, xg = t >> 5;
  long plane = ((long)(b * 8 + 4 + cg) << 14) + (y << 7) + x0;
  #pragma unroll
  for (int q = 0; q < 8; ++q) {
    int xx = xg * 8 + q;
    catT[((plane + xx) << 5) + ic] = f2bf(ts[ic][xx]);
  }
}

// ---------------- weight repack: w_ref -> wbT[tap][oc][ic] bf16 -------------
__global__ void k_wrefT(const float* __restrict__ wr, unsigned short* __restrict__ wbT) {
  int idx = blockIdx.x * 256 + threadIdx.x;   // 294,912
  int tap = idx >> 15;
  int rem = idx & 32767;
  int oc = rem >> 8, ic = rem & 255;
  wbT[idx] = f2bf(wr[(oc * 256 + ic) * 9 + tap]);
}

// ---------------- weight build: wOM[39][48][128] bf16 -----------------------
__global__ void k_womT(const float* __restrict__ wh, const float* __restrict__ wv,
                       const float* __restrict__ wm, unsigned short* __restrict__ wOM) {
  int idx = blockIdx.x * 256 + threadIdx.x;   // 239,616 = 39*48*128
  int tap = idx / 6144;
  int rem = idx - tap * 6144;
  int j = rem >> 7, ic = rem & 127;
  float v = 0.f;
  if (tap < 15) {
    if (j < 18) v = wh[(j * 128 + ic) * 15 + tap];
  } else if (tap < 30) {
    if (j < 18) v = wv[(j * 128 + ic) * 15 + (tap - 15)];
  } else {
    if (j >= 18 && j < 27) v = wm[((j - 18) * 128 + ic) * 9 + (tap - 30)];
  }
  wOM[idx] = f2bf(v);
}

// ---------------- weight repack: w_def -> MFMA-A fragment order bf16 --------
// wdefA[((ks*4 + lhi)*128 + oc)*8 + j]  where ks = cg*9+k, channel = cg*32+lhi*8+j
__global__ void k_wdefA(const float* __restrict__ wd, unsigned short* __restrict__ wdefA) {
  int idx = blockIdx.x * 256 + threadIdx.x;   // 147,456
  if (idx >= 147456) return;
  int j   = idx & 7;
  int oc  = (idx >> 3) & 127;
  int lhi = (idx >> 10) & 3;
  int ks  = idx >> 12;               // 0..35
  int k = ks % 9, cg = ks / 9;
  int c = cg * 32 + lhi * 8 + j;
  wdefA[idx] = f2bf(wd[(oc * 128 + c) * 9 + k]);
}

// ---------------- K2: 3x3 conv 256->128 via MFMA bf16 -----------------------
__global__ __launch_bounds__(256, 2)
void k_conv3m(const unsigned short* __restrict__ catT, const unsigned short* __restrict__ wbT,
              const float* __restrict__ br, float* __restrict__ out) {
  int bid = blockIdx.x;            // 2 * 128 * 2 = 512
  int xt = bid & 1;
  int y  = (bid >> 1) & 127;
  int b  = bid >> 8;
  int x0 = xt * 64;
  int t = threadIdx.x;
  int l = t & 63, w = t >> 6;
  __shared__ unsigned short xs[3 * 66 * 40];   // [r][c][ic pad 40] 15,840 B
  f32x4 acc[2][4];
  #pragma unroll
  for (int m = 0; m < 2; ++m)
    #pragma unroll
    for (int n = 0; n < 4; ++n)
      #pragma unroll
      for (int r = 0; r < 4; ++r) acc[m][n][r] = 0.f;
  const unsigned short* catb = catT + ((long)b << 22);   // b*8*16384*32
  int lan15 = l & 15, lhi = l >> 4;
  for (int cg = 0; cg < 8; ++cg) {
    __syncthreads();
    for (int j = t; j < 792; j += 256) {       // 3*66*4 granules
      int g = j & 3;
      int rc = j >> 2;
      int c = rc % 66, r = rc / 66;
      int gy = y + r - 1, gx = x0 + c - 1;
      u16x8 v = {0, 0, 0, 0, 0, 0, 0, 0};
      if ((unsigned)gy < 128u && (unsigned)gx < 128u)
        v = *(const u16x8*)(catb + ((((long)cg << 14) + (gy << 7) + gx) << 5) + g * 8);
      *(u16x8*)(xs + (r * 66 + c) * 40 + g * 8) = v;
    }
    bf16x8 af[2][9];
    int kbase = cg * 32 + lhi * 8;
    #pragma unroll
    for (int mt = 0; mt < 2; ++mt)
      #pragma unroll
      for (int tap = 0; tap < 9; ++tap)
        af[mt][tap] = *(const bf16x8*)(wbT + ((tap * 128 + w * 32 + mt * 16 + lan15) * 256 + kbase));
    __syncthreads();
    #pragma unroll
    for (int tap = 0; tap < 9; ++tap) {
      int ky = tap / 3, kx = tap % 3;
      #pragma unroll
      for (int nt = 0; nt < 4; ++nt) {
        int c = nt * 16 + lan15 + kx;
        bf16x8 bfv = *(const bf16x8*)(xs + ((ky * 66 + c) * 40) + lhi * 8);
        acc[0][nt] = __builtin_amdgcn_mfma_f32_16x16x32_bf16(af[0][tap], bfv, acc[0][nt], 0, 0, 0);
        acc[1][nt] = __builtin_amdgcn_mfma_f32_16x16x32_bf16(af[1][tap], bfv, acc[1][nt], 0, 0, 0);
      }
    }
  }
  #pragma unroll
  for (int mt = 0; mt < 2; ++mt)
    #pragma unroll
    for (int reg = 0; reg < 4; ++reg) {
      int oc = w * 32 + mt * 16 + lhi * 4 + reg;
      float bias = br[oc];
      long obase = ((long)(b * 128 + oc) << 14) + (y << 7);
      #pragma unroll
      for (int nt = 0; nt < 4; ++nt)
        out[obase + x0 + nt * 16 + lan15] = acc[mt][nt][reg] + bias;
    }
}

// ---------------- K3/K7: per-channel batch-norm stats -----------------------
__global__ void k_bnstats(const float* __restrict__ src, float* __restrict__ mean,
                          float* __restrict__ rstd) {
  int c = blockIdx.x, t = threadIdx.x;
  float s = 0.f, s2 = 0.f;
  for (int b = 0; b < 2; ++b) {
    const float4* p4 = (const float4*)(src + ((long)(b * 128 + c) << 14));
    for (int i = t; i < 4096; i += 256) {
      float4 v = p4[i];
      s  += v.x + v.y + v.z + v.w;
      s2 += v.x * v.x + v.y * v.y + v.z * v.z + v.w * v.w;
    }
  }
  #pragma unroll
  for (int off = 32; off; off >>= 1) {
    s  += __shfl_down(s, off);
    s2 += __shfl_down(s2, off);
  }
  __shared__ float as[4], as2[4];
  int wid = t >> 6;
  if ((t & 63) == 0) { as[wid] = s; as2[wid] = s2; }
  __syncthreads();
  if (t == 0) {
    float S = as[0] + as[1] + as[2] + as[3];
    float S2 = as2[0] + as2[1] + as2[2] + as2[3];
    float m = S / 32768.f;
    float var = S2 / 32768.f - m * m;
    mean[c] = m;
    rstd[c] = rsqrtf(var + 1e-5f);
  }
}

// ---------------- K4: bn+relu -> hbufT bf16 chunked only --------------------
__global__ void k_bnrelu2(const float* __restrict__ tmp1, const float* __restrict__ mean,
                          const float* __restrict__ rstd, const float* __restrict__ g,
                          const float* __restrict__ be, unsigned short* __restrict__ hbufT) {
  int bid = blockIdx.x;            // 2048
  int xb = bid & 1;
  int y  = (bid >> 1) & 127;
  int cg = (bid >> 8) & 3;
  int b  = bid >> 10;
  int t = threadIdx.x;
  __shared__ float ts[32][65];
  int x = t & 63, c4 = t >> 6, x0 = xb * 64;
  #pragma unroll
  for (int p = 0; p < 8; ++p) {
    int c = p * 4 + c4;
    int ch = cg * 32 + c;
    float sc = rstd[ch] * g[ch];
    float bb = be[ch] - mean[ch] * sc;
    long idx = ((long)(b * 128 + ch) << 14) + (y << 7) + x0 + x;
    ts[c][x] = fmaxf(tmp1[idx] * sc + bb, 0.f);
  }
  __syncthreads();
  int ic = t & 31, xg = t >> 5;
  long plane = ((long)(b * 4 + cg) << 14) + (y << 7) + x0;
  #pragma unroll
  for (int q = 0; q < 8; ++q) {
    int xx = xg * 8 + q;
    hbufT[((plane + xx) << 5) + ic] = f2bf(ts[ic][xx]);
  }
}

// ---------------- K5: offsets + mask via MFMA bf16, direct-from-global ------
// grid 1024; block = 32 px, 4 waves: wave w -> tile=(w&1) (16 px), kh=(w>>1) (K half)
__global__ __launch_bounds__(256, 4)
void k_offmaskd(const unsigned short* __restrict__ hbufT, const unsigned short* __restrict__ wOM,
                const float* __restrict__ bh, const float* __restrict__ bv,
                const float* __restrict__ bm,
                float* __restrict__ off, float* __restrict__ msk) {
  int bid = blockIdx.x;
  int swz = (bid & 7) * 128 + (bid >> 3);   // XCD-chunked, bijective (1024%8==0)
  int b   = swz >> 9;                       // 512 work-blocks per batch
  int px0 = (swz & 511) * 32;
  int t = threadIdx.x;
  int l = t & 63, w = t >> 6;
  int tile = w & 1, kh = w >> 1;
  int lan15 = l & 15, lhi = l >> 4;
  int px = px0 + tile * 16;
  int y = px >> 7, x0 = px & 127;
  int x = x0 + lan15;

  f32x4 acc0, acc1;
  #pragma unroll
  for (int r = 0; r < 4; ++r) { acc0[r] = 0.f; acc1[r] = 0.f; }

  // this wave's two channel chunks: cg = kh*2, kh*2+1
  const unsigned short* hb = hbufT + ((long)b << 21) + ((long)(kh * 2) << 19);
  const u16x8 z = {0, 0, 0, 0, 0, 0, 0, 0};

#define OM_STEP(tap, gy, gx, DO0) do {                                                   \
    int _gy = (gy), _gx = (gx);                                                          \
    bool _valid = ((unsigned)_gy < 128u) & ((unsigned)_gx < 128u);                       \
    const unsigned short* _bp = hb + ((((long)_gy * 128 + _gx) << 5) + lhi * 8);         \
    u16x8 _b0 = _valid ? *(const u16x8*)_bp : z;                                         \
    u16x8 _b1 = _valid ? *(const u16x8*)(_bp + (1L << 19)) : z;                          \
    const unsigned short* _ap = wOM + ((tap) * 48 + lan15) * 128 + kh * 64 + lhi * 8;    \
    acc1 = __builtin_amdgcn_mfma_f32_16x16x32_bf16(*(const bf16x8*)(_ap + 2048),         \
                                                   (bf16x8)_b0, acc1, 0, 0, 0);          \
    acc1 = __builtin_amdgcn_mfma_f32_16x16x32_bf16(*(const bf16x8*)(_ap + 2080),         \
                                                   (bf16x8)_b1, acc1, 0, 0, 0);          \
    if (DO0) {                                                                           \
      acc0 = __builtin_amdgcn_mfma_f32_16x16x32_bf16(*(const bf16x8*)(_ap),              \
                                                     (bf16x8)_b0, acc0, 0, 0, 0);        \
      acc0 = __builtin_amdgcn_mfma_f32_16x16x32_bf16(*(const bf16x8*)(_ap + 32),         \
                                                     (bf16x8)_b1, acc0, 0, 0, 0);        \
    }                                                                                    \
  } while (0)

  #pragma unroll
  for (int tap = 0; tap < 15; ++tap)        // 1x15 horizontal taps
    OM_STEP(tap, y, x + tap - 7, true);
  #pragma unroll
  for (int tap = 15; tap < 30; ++tap)       // 15x1 vertical taps
    OM_STEP(tap, y + tap - 22, x, true);
  #pragma unroll
  for (int tap = 30; tap < 39; ++tap)       // 3x3 mask taps (j rows 16..31 only)
    OM_STEP(tap, y + (tap - 30) / 3 - 1, x + (tap - 30) % 3 - 1, false);
#undef OM_STEP

  __shared__ f32x4 red[2][2][4][16];   // [tile][acc0/1][lhi][px] = 4 KB
  if (kh == 1) {
    red[tile][0][lhi][lan15] = acc0;
    red[tile][1][lhi][lan15] = acc1;
  }
  __syncthreads();
  if (kh == 0) {
    f32x4 r0 = red[tile][0][lhi][lan15];
    f32x4 r1 = red[tile][1][lhi][lan15];
    int sp = (y << 7) + x;
    #pragma unroll
    for (int reg = 0; reg < 4; ++reg) {
      int j0 = lhi * 4 + reg;        // 0..15, all offsets
      off[((long)(b * 18 + j0) << 14) + sp] = acc0[reg] + r0[reg] + bh[j0] + bv[j0];
      int j1 = 16 + lhi * 4 + reg;   // 16..31
      float v = acc1[reg] + r1[reg];
      if (j1 < 18) {
        off[((long)(b * 18 + j1) << 14) + sp] = v + bh[j1] + bv[j1];
      } else if (j1 < 27) {
        int jm = j1 - 18;
        msk[((long)(b * 9 + jm) << 14) + sp] = 1.f / (1.f + expf(-(v + bm[jm])));
      }
    }
  }
}

// ---------------- K6: deformable 3x3 conv via MFMA bf16 ---------------------
__global__ __launch_bounds__(256, 2)
void k_deformm(const unsigned short* __restrict__ hbufT, const float* __restrict__ off,
               const float* __restrict__ msk, const unsigned short* __restrict__ wdefA,
               float* __restrict__ out) {
  int bid = blockIdx.x;            // 2 * 128 * 4 = 1024
  int xt = bid & 3;
  int h  = (bid >> 2) & 127;
  int b  = bid >> 9;
  int w0 = xt * 32;
  int t = threadIdx.x;
  int l = t & 63, w = t >> 6;
  int lan15 = l & 15, lhi = l >> 4;

  __shared__ __align__(16) unsigned short S[9][32][40];  // 23,040 B
  __shared__ int   p_y0[288], p_x0[288];
  __shared__ float p_w00[288], p_w01[288], p_w10[288], p_w11[288];

  for (int idx = t; idx < 288; idx += 256) {
    int k = idx >> 5, pix = idx & 31;
    int sp = (h << 7) + w0 + pix;
    float dy = off[((long)(b * 18 + 2 * k) << 14) + sp];
    float dx = off[((long)(b * 18 + 2 * k + 1) << 14) + sp];
    float m  = msk[((long)(b * 9 + k) << 14) + sp];
    float y  = dy + (float)(h + k / 3 - 1);
    float xx = dx + (float)(w0 + pix + (k % 3) - 1);
    float y0f = floorf(y), x0f = floorf(xx);
    float wy = y - y0f, wx = xx - x0f;
    p_y0[idx] = (int)y0f; p_x0[idx] = (int)x0f;
    p_w00[idx] = (1.f - wy) * (1.f - wx) * m;
    p_w01[idx] = (1.f - wy) * wx * m;
    p_w10[idx] = wy * (1.f - wx) * m;
    p_w11[idx] = wy * wx * m;
  }

  f32x4 acc[2][2];
  #pragma unroll
  for (int m = 0; m < 2; ++m)
    #pragma unroll
    for (int n = 0; n < 2; ++n)
      #pragma unroll
      for (int r = 0; r < 4; ++r) acc[m][n][r] = 0.f;

  for (int cg = 0; cg < 4; ++cg) {
    __syncthreads();   // offsets ready (cg=0); previous MFMA reads done (cg>0)
    const unsigned short* hb = hbufT + (((long)(b * 4 + cg)) << 19);
    for (int idx = t; idx < 1152; idx += 256) {   // 9k * 32pix * 4cq
      int cq = idx & 3, pix = (idx >> 2) & 31, k = idx >> 7;
      int kp = (k << 5) + pix;
      int y0 = p_y0[kp], x0 = p_x0[kp];
      float c00 = p_w00[kp], c01 = p_w01[kp], c10 = p_w10[kp], c11 = p_w11[kp];
      bool yi0 = (unsigned)y0 < 128u, yi1 = (unsigned)(y0 + 1) < 128u;
      bool xi0 = (unsigned)x0 < 128u, xi1 = (unsigned)(x0 + 1) < 128u;
      const unsigned short* pbase = hb + ((((long)(y0 << 7) + x0) << 5) + cq * 8);
      u16x8 z = {0, 0, 0, 0, 0, 0, 0, 0};
      u16x8 v00 = (yi0 && xi0) ? *(const u16x8*)pbase          : z;
      u16x8 v01 = (yi0 && xi1) ? *(const u16x8*)(pbase + 32)   : z;
      u16x8 v10 = (yi1 && xi0) ? *(const u16x8*)(pbase + 4096) : z;
      u16x8 v11 = (yi1 && xi1) ? *(const u16x8*)(pbase + 4128) : z;
      u16x8 o;
      #pragma unroll
      for (int j = 0; j < 8; ++j) {
        float s = c00 * __uint_as_float((unsigned)(unsigned short)v00[j] << 16)
                + c01 * __uint_as_float((unsigned)(unsigned short)v01[j] << 16)
                + c10 * __uint_as_float((unsigned)(unsigned short)v10[j] << 16)
                + c11 * __uint_as_float((unsigned)(unsigned short)v11[j] << 16);
        o[j] = f2bf(s);
      }
      *(u16x8*)(&S[k][pix][cq * 8]) = o;
    }
    bf16x8 af0[9], af1[9];
    #pragma unroll
    for (int k = 0; k < 9; ++k) {
      long wbase = ((((long)(cg * 9 + k) * 4 + lhi) * 128) + w * 32 + lan15) * 8;
      af0[k] = *(const bf16x8*)(wdefA + wbase);
      af1[k] = *(const bf16x8*)(wdefA + wbase + 128);   // +16 oc
    }
    __syncthreads();
    #pragma unroll
    for (int k = 0; k < 9; ++k) {
      #pragma unroll
      for (int nt = 0; nt < 2; ++nt) {
        bf16x8 bfv = *(const bf16x8*)(&S[k][nt * 16 + lan15][lhi * 8]);
        acc[0][nt] = __builtin_amdgcn_mfma_f32_16x16x32_bf16(af0[k], bfv, acc[0][nt], 0, 0, 0);
        acc[1][nt] = __builtin_amdgcn_mfma_f32_16x16x32_bf16(af1[k], bfv, acc[1][nt], 0, 0, 0);
      }
    }
  }
  #pragma unroll
  for (int mt = 0; mt < 2; ++mt)
    #pragma unroll
    for (int reg = 0; reg < 4; ++reg) {
      int oc = w * 32 + mt * 16 + lhi * 4 + reg;
      long obase = ((long)(b * 128 + oc) << 14) + (h << 7) + w0;
      out[obase + lan15]      = acc[mt][0][reg];
      out[obase + 16 + lan15] = acc[mt][1][reg];
    }
}

// ---------------- K8: plain bn+relu (final output) --------------------------
__global__ void k_bnrelu(const float4* __restrict__ src, const float* __restrict__ mean,
                         const float* __restrict__ rstd, const float* __restrict__ g,
                         const float* __restrict__ be, float4* __restrict__ dst) {
  int i = blockIdx.x * 256 + threadIdx.x;   // over 1,048,576 float4
  if (i >= 1048576) return;
  int c = (i >> 12) & 127;
  float sc = rstd[c] * g[c];
  float bb = be[c] - mean[c] * sc;
  float4 v = src[i];
  v.x = fmaxf(v.x * sc + bb, 0.f);
  v.y = fmaxf(v.y * sc + bb, 0.f);
  v.z = fmaxf(v.z * sc + bb, 0.f);
  v.w = fmaxf(v.w * sc + bb, 0.f);
  dst[i] = v;
}

// ---------------- launcher --------------------------------------------------
extern "C" void kernel_launch(void* const* d_in, const int* in_sizes, int n_in,
                              void* d_out, int out_size, void* d_ws, size_t ws_size,
                              hipStream_t stream) {
  const float* x      = (const float*)d_in[0];
  const float* skip   = (const float*)d_in[1];
  const float* w_up   = (const float*)d_in[2];
  const float* b_up   = (const float*)d_in[3];
  const float* w_ref  = (const float*)d_in[4];
  const float* b_ref  = (const float*)d_in[5];
  const float* g1     = (const float*)d_in[6];
  const float* be1    = (const float*)d_in[7];
  const float* w_offh = (const float*)d_in[8];
  const float* b_offh = (const float*)d_in[9];
  const float* w_offv = (const float*)d_in[10];
  const float* b_offv = (const float*)d_in[11];
  const float* w_mask = (const float*)d_in[12];
  const float* b_mask = (const float*)d_in[13];
  const float* w_def  = (const float*)d_in[14];
  const float* g2     = (const float*)d_in[15];
  const float* be2    = (const float*)d_in[16];

  char* W = (char*)d_ws;
  unsigned short* catT  = (unsigned short*)W;                 // 16,777,216 B
  float*          tmp1  = (float*)(W + 16777216);             // 16 MB
  unsigned short* hbufT = (unsigned short*)(W + 33554432);    // 8,388,608 B
  float*          offb  = (float*)(W + 41943040);             // 2,359,296 B
  float*          mskb  = (float*)(W + 44302336);             // 1,179,648 B
  float*          stat  = (float*)(W + 45481984);             // 2,048 B
  unsigned short* wbT   = (unsigned short*)(W + 45484032);    // 589,824 B
  unsigned short* wOM   = (unsigned short*)(W + 46073856);    // 479,232 B
  unsigned short* wdefA = (unsigned short*)(W + 46553088);    // 294,912 B
  float*          dpre  = (float*)W;                          // alias catT (dead)

  hipLaunchKernelGGL(k_wrefT, dim3(1152), dim3(256), 0, stream, w_ref, wbT);
  hipLaunchKernelGGL(k_womT, dim3(936), dim3(256), 0, stream, w_offh, w_offv, w_mask, wOM);
  hipLaunchKernelGGL(k_wdefA, dim3(576), dim3(256), 0, stream, w_def, wdefA);
  hipLaunchKernelGGL(k_upsampleT, dim3(1024), dim3(256), 0, stream, x, w_up, b_up, catT);
  hipLaunchKernelGGL(k_skipT, dim3(2048), dim3(256), 0, stream, skip, catT);
  hipLaunchKernelGGL(k_conv3m, dim3(512), dim3(256), 0, stream, catT, wbT, b_ref, tmp1);
  hipLaunchKernelGGL(k_bnstats, dim3(128), dim3(256), 0, stream, tmp1, stat, stat + 128);
  hipLaunchKernelGGL(k_bnrelu2, dim3(2048), dim3(256), 0, stream, tmp1, stat, stat + 128,
                     g1, be1, hbufT);
  hipLaunchKernelGGL(k_offmaskd, dim3(1024), dim3(256), 0, stream, hbufT, wOM,
                     b_offh, b_offv, b_mask, offb, mskb);
  hipLaunchKernelGGL(k_deformm, dim3(1024), dim3(256), 0, stream, hbufT, offb, mskb,
                     wdefA, dpre);
  hipLaunchKernelGGL(k_bnstats, dim3(128), dim3(256), 0, stream, dpre, stat + 256, stat + 384);
  hipLaunchKernelGGL(k_bnrelu, dim3(4096), dim3(256), 0, stream,
                     (const float4*)dpre, stat + 256, stat + 384, g2, be2, (float4*)d_out);
}

// Round 7
// 201.057 us; speedup vs baseline: 9.7990x; 1.2114x over previous
//
#include <hip/hip_runtime.h>
#include <hip/hip_bf16.h>

typedef __attribute__((ext_vector_type(8))) short bf16x8;
typedef __attribute__((ext_vector_type(4))) float f32x4;
typedef __attribute__((ext_vector_type(8))) unsigned short u16x8;

static __device__ __forceinline__ unsigned short f2bf(float f) {
  union { float f; unsigned u; } v; v.f = f;
  unsigned r = v.u + 0x7fff + ((v.u >> 16) & 1);
  return (unsigned short)(r >> 16);
}

// ---------------- K1: transposed-conv 2x2 s2 -> catT chunks 0..3 (bf16) -----
__global__ void k_upsampleT(const float* __restrict__ x, const float* __restrict__ w_up,
                            const float* __restrict__ b_up, unsigned short* __restrict__ catT) {
  int bid = blockIdx.x;            // 2 * 64 * 8 = 1024
  int wt = bid & 7;
  int hh = (bid >> 3) & 63;
  int b  = bid >> 9;
  int t = threadIdx.x;
  __shared__ float xs[256][8];
  int ww0 = wt * 8;
  int pix = t & 7, icb = t >> 3;
  #pragma unroll
  for (int r = 0; r < 8; ++r) {
    int ic = r * 32 + icb;
    xs[ic][pix] = x[((b * 256 + ic) * 64 + hh) * 64 + ww0 + pix];
  }
  __syncthreads();
  int oc = t & 127, g = t >> 7;    // g = kh
  float bias = b_up[oc];
  float acc0[8], acc1[8];
  #pragma unroll
  for (int p = 0; p < 8; ++p) { acc0[p] = bias; acc1[p] = bias; }
  for (int i = 0; i < 256; ++i) {
    float wv0 = w_up[((i * 128 + oc) * 2 + g) * 2 + 0];
    float wv1 = w_up[((i * 128 + oc) * 2 + g) * 2 + 1];
    #pragma unroll
    for (int p = 0; p < 8; ++p) {
      float xv = xs[i][p];
      acc0[p] += xv * wv0;
      acc1[p] += xv * wv1;
    }
  }
  int h = 2 * hh + g;
  int cg = oc >> 5, icl = oc & 31;
  long plane = ((long)(b * 8 + cg) << 14) + (h << 7);
  #pragma unroll
  for (int p = 0; p < 8; ++p) {
    int w0c = 2 * (ww0 + p);
    catT[((plane + w0c) << 5) + icl]     = f2bf(acc0[p]);
    catT[((plane + w0c + 1) << 5) + icl] = f2bf(acc1[p]);
  }
}

// ---------------- K1b: skip -> catT chunks 4..7 (bf16, LDS transpose) -------
__global__ void k_skipT(const float* __restrict__ skip, unsigned short* __restrict__ catT) {
  int bid = blockIdx.x;            // 2 * 4 * 128 * 2 = 2048
  int xb = bid & 1;
  int y  = (bid >> 1) & 127;
  int cg = (bid >> 8) & 3;
  int b  = bid >> 10;
  int t = threadIdx.x;
  __shared__ float ts[32][65];
  int x = t & 63, c4 = t >> 6, x0 = xb * 64;
  #pragma unroll
  for (int p = 0; p < 8; ++p) {
    int c = p * 4 + c4;
    ts[c][x] = skip[(((long)(b * 128 + cg * 32 + c)) << 14) + (y << 7) + x0 + x];
  }
  __syncthreads();
  int ic = t & 31, xg = t >> 5;
  long plane = ((long)(b * 8 + 4 + cg) << 14) + (y << 7) + x0;
  #pragma unroll
  for (int q = 0; q < 8; ++q) {
    int xx = xg * 8 + q;
    catT[((plane + xx) << 5) + ic] = f2bf(ts[ic][xx]);
  }
}

// ---------------- weight repack: w_ref -> wbT[tap][oc][ic] bf16 -------------
__global__ void k_wrefT(const float* __restrict__ wr, unsigned short* __restrict__ wbT) {
  int idx = blockIdx.x * 256 + threadIdx.x;   // 294,912
  int tap = idx >> 15;
  int rem = idx & 32767;
  int oc = rem >> 8, ic = rem & 255;
  wbT[idx] = f2bf(wr[(oc * 256 + ic) * 9 + tap]);
}

// ---------------- weight build: wOM[39][48][128] bf16 -----------------------
__global__ void k_womT(const float* __restrict__ wh, const float* __restrict__ wv,
                       const float* __restrict__ wm, unsigned short* __restrict__ wOM) {
  int idx = blockIdx.x * 256 + threadIdx.x;   // 239,616 = 39*48*128
  int tap = idx / 6144;
  int rem = idx - tap * 6144;
  int j = rem >> 7, ic = rem & 127;
  float v = 0.f;
  if (tap < 15) {
    if (j < 18) v = wh[(j * 128 + ic) * 15 + tap];
  } else if (tap < 30) {
    if (j < 18) v = wv[(j * 128 + ic) * 15 + (tap - 15)];
  } else {
    if (j >= 18 && j < 27) v = wm[((j - 18) * 128 + ic) * 9 + (tap - 30)];
  }
  wOM[idx] = f2bf(v);
}

// ---------------- weight repack: w_def -> MFMA-A fragment order bf16 --------
// wdefA[((ks*4 + lhi)*128 + oc)*8 + j]  where ks = cg*9+k, channel = cg*32+lhi*8+j
__global__ void k_wdefA(const float* __restrict__ wd, unsigned short* __restrict__ wdefA) {
  int idx = blockIdx.x * 256 + threadIdx.x;   // 147,456
  if (idx >= 147456) return;
  int j   = idx & 7;
  int oc  = (idx >> 3) & 127;
  int lhi = (idx >> 10) & 3;
  int ks  = idx >> 12;               // 0..35
  int k = ks % 9, cg = ks / 9;
  int c = cg * 32 + lhi * 8 + j;
  wdefA[idx] = f2bf(wd[(oc * 128 + c) * 9 + k]);
}

// ---------------- K2: 3x3 conv 256->128 via MFMA bf16 -----------------------
__global__ __launch_bounds__(256, 2)
void k_conv3m(const unsigned short* __restrict__ catT, const unsigned short* __restrict__ wbT,
              const float* __restrict__ br, float* __restrict__ out) {
  int bid = blockIdx.x;            // 2 * 128 * 2 = 512
  int xt = bid & 1;
  int y  = (bid >> 1) & 127;
  int b  = bid >> 8;
  int x0 = xt * 64;
  int t = threadIdx.x;
  int l = t & 63, w = t >> 6;
  __shared__ unsigned short xs[3 * 66 * 40];   // [r][c][ic pad 40] 15,840 B
  f32x4 acc[2][4];
  #pragma unroll
  for (int m = 0; m < 2; ++m)
    #pragma unroll
    for (int n = 0; n < 4; ++n)
      #pragma unroll
      for (int r = 0; r < 4; ++r) acc[m][n][r] = 0.f;
  const unsigned short* catb = catT + ((long)b << 22);   // b*8*16384*32
  int lan15 = l & 15, lhi = l >> 4;
  for (int cg = 0; cg < 8; ++cg) {
    __syncthreads();
    for (int j = t; j < 792; j += 256) {       // 3*66*4 granules
      int g = j & 3;
      int rc = j >> 2;
      int c = rc % 66, r = rc / 66;
      int gy = y + r - 1, gx = x0 + c - 1;
      u16x8 v = {0, 0, 0, 0, 0, 0, 0, 0};
      if ((unsigned)gy < 128u && (unsigned)gx < 128u)
        v = *(const u16x8*)(catb + ((((long)cg << 14) + (gy << 7) + gx) << 5) + g * 8);
      *(u16x8*)(xs + (r * 66 + c) * 40 + g * 8) = v;
    }
    bf16x8 af[2][9];
    int kbase = cg * 32 + lhi * 8;
    #pragma unroll
    for (int mt = 0; mt < 2; ++mt)
      #pragma unroll
      for (int tap = 0; tap < 9; ++tap)
        af[mt][tap] = *(const bf16x8*)(wbT + ((tap * 128 + w * 32 + mt * 16 + lan15) * 256 + kbase));
    __syncthreads();
    #pragma unroll
    for (int tap = 0; tap < 9; ++tap) {
      int ky = tap / 3, kx = tap % 3;
      #pragma unroll
      for (int nt = 0; nt < 4; ++nt) {
        int c = nt * 16 + lan15 + kx;
        bf16x8 bfv = *(const bf16x8*)(xs + ((ky * 66 + c) * 40) + lhi * 8);
        acc[0][nt] = __builtin_amdgcn_mfma_f32_16x16x32_bf16(af[0][tap], bfv, acc[0][nt], 0, 0, 0);
        acc[1][nt] = __builtin_amdgcn_mfma_f32_16x16x32_bf16(af[1][tap], bfv, acc[1][nt], 0, 0, 0);
      }
    }
  }
  #pragma unroll
  for (int mt = 0; mt < 2; ++mt)
    #pragma unroll
    for (int reg = 0; reg < 4; ++reg) {
      int oc = w * 32 + mt * 16 + lhi * 4 + reg;
      float bias = br[oc];
      long obase = ((long)(b * 128 + oc) << 14) + (y << 7);
      #pragma unroll
      for (int nt = 0; nt < 4; ++nt)
        out[obase + x0 + nt * 16 + lan15] = acc[mt][nt][reg] + bias;
    }
}

// ---------------- K3/K7: per-channel batch-norm stats -----------------------
__global__ void k_bnstats(const float* __restrict__ src, float* __restrict__ mean,
                          float* __restrict__ rstd) {
  int c = blockIdx.x, t = threadIdx.x;
  float s = 0.f, s2 = 0.f;
  for (int b = 0; b < 2; ++b) {
    const float4* p4 = (const float4*)(src + ((long)(b * 128 + c) << 14));
    for (int i = t; i < 4096; i += 256) {
      float4 v = p4[i];
      s  += v.x + v.y + v.z + v.w;
      s2 += v.x * v.x + v.y * v.y + v.z * v.z + v.w * v.w;
    }
  }
  #pragma unroll
  for (int off = 32; off; off >>= 1) {
    s  += __shfl_down(s, off);
    s2 += __shfl_down(s2, off);
  }
  __shared__ float as[4], as2[4];
  int wid = t >> 6;
  if ((t & 63) == 0) { as[wid] = s; as2[wid] = s2; }
  __syncthreads();
  if (t == 0) {
    float S = as[0] + as[1] + as[2] + as[3];
    float S2 = as2[0] + as2[1] + as2[2] + as2[3];
    float m = S / 32768.f;
    float var = S2 / 32768.f - m * m;
    mean[c] = m;
    rstd[c] = rsqrtf(var + 1e-5f);
  }
}

// ---------------- K4: bn+relu -> hbufT bf16 chunked only --------------------
__global__ void k_bnrelu2(const float* __restrict__ tmp1, const float* __restrict__ mean,
                          const float* __restrict__ rstd, const float* __restrict__ g,
                          const float* __restrict__ be, unsigned short* __restrict__ hbufT) {
  int bid = blockIdx.x;            // 2048
  int xb = bid & 1;
  int y  = (bid >> 1) & 127;
  int cg = (bid >> 8) & 3;
  int b  = bid >> 10;
  int t = threadIdx.x;
  __shared__ float ts[32][65];
  int x = t & 63, c4 = t >> 6, x0 = xb * 64;
  #pragma unroll
  for (int p = 0; p < 8; ++p) {
    int c = p * 4 + c4;
    int ch = cg * 32 + c;
    float sc = rstd[ch] * g[ch];
    float bb = be[ch] - mean[ch] * sc;
    long idx = ((long)(b * 128 + ch) << 14) + (y << 7) + x0 + x;
    ts[c][x] = fmaxf(tmp1[idx] * sc + bb, 0.f);
  }
  __syncthreads();
  int ic = t & 31, xg = t >> 5;
  long plane = ((long)(b * 4 + cg) << 14) + (y << 7) + x0;
  #pragma unroll
  for (int q = 0; q < 8; ++q) {
    int xx = xg * 8 + q;
    hbufT[((plane + xx) << 5) + ic] = f2bf(ts[ic][xx]);
  }
}

// ---------------- K5: offsets + mask via MFMA bf16, LDS-staged A ------------
// grid 512; block = 64 px (4 waves x 16 px), full K per wave.
// A (wOM weights) staged per block in groups of 4 taps (32 KB LDS, XOR-swizzled).
__global__ __launch_bounds__(256, 2)
void k_offmasks(const unsigned short* __restrict__ hbufT, const unsigned short* __restrict__ wOM,
                const float* __restrict__ bh, const float* __restrict__ bv,
                const float* __restrict__ bm,
                float* __restrict__ off, float* __restrict__ msk) {
  int bid = blockIdx.x;
  int swz = (bid & 7) * 64 + (bid >> 3);   // XCD-chunked, bijective (512 = 8*64)
  int b   = swz >> 8;                      // 256 work-blocks per batch
  int px0 = (swz & 255) * 64;
  int t = threadIdx.x;
  int l = t & 63, w = t >> 6;
  int lan15 = l & 15, lhi = l >> 4;
  int px = px0 + w * 16;
  int y = px >> 7, x0 = px & 127;
  int x = x0 + lan15;

  __shared__ unsigned short As[4 * 32 * 128];   // 32 KB, rows XOR-swizzled

  f32x4 acc0, acc1;
  #pragma unroll
  for (int r = 0; r < 4; ++r) { acc0[r] = 0.f; acc1[r] = 0.f; }

  const unsigned short* hb = hbufT + ((long)b << 21);
  const u16x8 z = {0, 0, 0, 0, 0, 0, 0, 0};
  int swz0 = (lan15 & 7) << 3;                  // short-granule XOR for this lane's j rows

  for (int grp = 0; grp < 10; ++grp) {
    int tap0 = grp * 4;
    __syncthreads();                            // previous group's LDS reads done
    #pragma unroll
    for (int it = 0; it < 8; ++it) {            // stage 4 taps x 32 j x 128 ch
      int i = it * 256 + t;
      int tl = i >> 9, rem = i & 511;
      int j = rem >> 4, g16 = rem & 15;
      int tap = tap0 + tl;
      u16x8 v = z;
      if (tap < 39) v = *(const u16x8*)(wOM + ((tap * 48 + j) << 7) + g16 * 8);
      *(u16x8*)(As + tl * 4096 + j * 128 + ((g16 ^ (j & 7)) << 3)) = v;
    }
    __syncthreads();
    #pragma unroll
    for (int tl = 0; tl < 4; ++tl) {
      int tap = tap0 + tl;
      if (tap < 39) {
        int ky = (tap < 15) ? 0 : ((tap < 30) ? (tap - 22) : ((tap - 30) / 3 - 1));
        int kx = (tap < 15) ? (tap - 7) : ((tap < 30) ? 0 : ((tap - 30) % 3 - 1));
        int gy = y + ky, gx = x + kx;
        bool valid = ((unsigned)gy < 128u) & ((unsigned)gx < 128u);
        const unsigned short* bp = hb + ((((long)(gy << 7) + gx) << 5) + lhi * 8);
        bool do0 = tap < 30;
        const unsigned short* a0base = As + tl * 4096 + lan15 * 128;
        const unsigned short* a1base = a0base + 16 * 128;
        #pragma unroll
        for (int cg = 0; cg < 4; ++cg) {
          u16x8 bv8 = valid ? *(const u16x8*)(bp + ((long)cg << 19)) : z;
          bf16x8 bf = (bf16x8)bv8;
          int aoff = (((cg << 2) + lhi) ^ (lan15 & 7)) << 3;
          acc1 = __builtin_amdgcn_mfma_f32_16x16x32_bf16(*(const bf16x8*)(a1base + aoff),
                                                         bf, acc1, 0, 0, 0);
          if (do0)
            acc0 = __builtin_amdgcn_mfma_f32_16x16x32_bf16(*(const bf16x8*)(a0base + aoff),
                                                           bf, acc0, 0, 0, 0);
        }
      }
    }
  }

  int sp = (y << 7) + x;
  #pragma unroll
  for (int reg = 0; reg < 4; ++reg) {
    int j0 = lhi * 4 + reg;        // 0..15, all offsets
    off[((long)(b * 18 + j0) << 14) + sp] = acc0[reg] + bh[j0] + bv[j0];
    int j1 = 16 + lhi * 4 + reg;   // 16..31
    float v = acc1[reg];
    if (j1 < 18) {
      off[((long)(b * 18 + j1) << 14) + sp] = v + bh[j1] + bv[j1];
    } else if (j1 < 27) {
      int jm = j1 - 18;
      msk[((long)(b * 9 + jm) << 14) + sp] = 1.f / (1.f + expf(-(v + bm[jm])));
    }
  }
}

// ---------------- K6: deformable 3x3 conv via MFMA bf16 ---------------------
__global__ __launch_bounds__(256, 2)
void k_deformm(const unsigned short* __restrict__ hbufT, const float* __restrict__ off,
               const float* __restrict__ msk, const unsigned short* __restrict__ wdefA,
               float* __restrict__ out) {
  int bid = blockIdx.x;            // 2 * 128 * 4 = 1024
  int xt = bid & 3;
  int h  = (bid >> 2) & 127;
  int b  = bid >> 9;
  int w0 = xt * 32;
  int t = threadIdx.x;
  int l = t & 63, w = t >> 6;
  int lan15 = l & 15, lhi = l >> 4;

  __shared__ __align__(16) unsigned short S[9][32][40];  // 23,040 B
  __shared__ int   p_y0[288], p_x0[288];
  __shared__ float p_w00[288], p_w01[288], p_w10[288], p_w11[288];

  for (int idx = t; idx < 288; idx += 256) {
    int k = idx >> 5, pix = idx & 31;
    int sp = (h << 7) + w0 + pix;
    float dy = off[((long)(b * 18 + 2 * k) << 14) + sp];
    float dx = off[((long)(b * 18 + 2 * k + 1) << 14) + sp];
    float m  = msk[((long)(b * 9 + k) << 14) + sp];
    float y  = dy + (float)(h + k / 3 - 1);
    float xx = dx + (float)(w0 + pix + (k % 3) - 1);
    float y0f = floorf(y), x0f = floorf(xx);
    float wy = y - y0f, wx = xx - x0f;
    p_y0[idx] = (int)y0f; p_x0[idx] = (int)x0f;
    p_w00[idx] = (1.f - wy) * (1.f - wx) * m;
    p_w01[idx] = (1.f - wy) * wx * m;
    p_w10[idx] = wy * (1.f - wx) * m;
    p_w11[idx] = wy * wx * m;
  }

  f32x4 acc[2][2];
  #pragma unroll
  for (int m = 0; m < 2; ++m)
    #pragma unroll
    for (int n = 0; n < 2; ++n)
      #pragma unroll
      for (int r = 0; r < 4; ++r) acc[m][n][r] = 0.f;

  for (int cg = 0; cg < 4; ++cg) {
    __syncthreads();   // offsets ready (cg=0); previous MFMA reads done (cg>0)
    const unsigned short* hb = hbufT + (((long)(b * 4 + cg)) << 19);
    for (int idx = t; idx < 1152; idx += 256) {   // 9k * 32pix * 4cq
      int cq = idx & 3, pix = (idx >> 2) & 31, k = idx >> 7;
      int kp = (k << 5) + pix;
      int y0 = p_y0[kp], x0 = p_x0[kp];
      float c00 = p_w00[kp], c01 = p_w01[kp], c10 = p_w10[kp], c11 = p_w11[kp];
      bool yi0 = (unsigned)y0 < 128u, yi1 = (unsigned)(y0 + 1) < 128u;
      bool xi0 = (unsigned)x0 < 128u, xi1 = (unsigned)(x0 + 1) < 128u;
      const unsigned short* pbase = hb + ((((long)(y0 << 7) + x0) << 5) + cq * 8);
      u16x8 z = {0, 0, 0, 0, 0, 0, 0, 0};
      u16x8 v00 = (yi0 && xi0) ? *(const u16x8*)pbase          : z;
      u16x8 v01 = (yi0 && xi1) ? *(const u16x8*)(pbase + 32)   : z;
      u16x8 v10 = (yi1 && xi0) ? *(const u16x8*)(pbase + 4096) : z;
      u16x8 v11 = (yi1 && xi1) ? *(const u16x8*)(pbase + 4128) : z;
      u16x8 o;
      #pragma unroll
      for (int j = 0; j < 8; ++j) {
        float s = c00 * __uint_as_float((unsigned)(unsigned short)v00[j] << 16)
                + c01 * __uint_as_float((unsigned)(unsigned short)v01[j] << 16)
                + c10 * __uint_as_float((unsigned)(unsigned short)v10[j] << 16)
                + c11 * __uint_as_float((unsigned)(unsigned short)v11[j] << 16);
        o[j] = f2bf(s);
      }
      *(u16x8*)(&S[k][pix][cq * 8]) = o;
    }
    bf16x8 af0[9], af1[9];
    #pragma unroll
    for (int k = 0; k < 9; ++k) {
      long wbase = ((((long)(cg * 9 + k) * 4 + lhi) * 128) + w * 32 + lan15) * 8;
      af0[k] = *(const bf16x8*)(wdefA + wbase);
      af1[k] = *(const bf16x8*)(wdefA + wbase + 128);   // +16 oc
    }
    __syncthreads();
    #pragma unroll
    for (int k = 0; k < 9; ++k) {
      #pragma unroll
      for (int nt = 0; nt < 2; ++nt) {
        bf16x8 bfv = *(const bf16x8*)(&S[k][nt * 16 + lan15][lhi * 8]);
        acc[0][nt] = __builtin_amdgcn_mfma_f32_16x16x32_bf16(af0[k], bfv, acc[0][nt], 0, 0, 0);
        acc[1][nt] = __builtin_amdgcn_mfma_f32_16x16x32_bf16(af1[k], bfv, acc[1][nt], 0, 0, 0);
      }
    }
  }
  #pragma unroll
  for (int mt = 0; mt < 2; ++mt)
    #pragma unroll
    for (int reg = 0; reg < 4; ++reg) {
      int oc = w * 32 + mt * 16 + lhi * 4 + reg;
      long obase = ((long)(b * 128 + oc) << 14) + (h << 7) + w0;
      out[obase + lan15]      = acc[mt][0][reg];
      out[obase + 16 + lan15] = acc[mt][1][reg];
    }
}

// ---------------- K8: plain bn+relu (final output) --------------------------
__global__ void k_bnrelu(const float4* __restrict__ src, const float* __restrict__ mean,
                         const float* __restrict__ rstd, const float* __restrict__ g,
                         const float* __restrict__ be, float4* __restrict__ dst) {
  int i = blockIdx.x * 256 + threadIdx.x;   // over 1,048,576 float4
  if (i >= 1048576) return;
  int c = (i >> 12) & 127;
  float sc = rstd[c] * g[c];
  float bb = be[c] - mean[c] * sc;
  float4 v = src[i];
  v.x = fmaxf(v.x * sc + bb, 0.f);
  v.y = fmaxf(v.y * sc + bb, 0.f);
  v.z = fmaxf(v.z * sc + bb, 0.f);
  v.w = fmaxf(v.w * sc + bb, 0.f);
  dst[i] = v;
}

// ---------------- launcher --------------------------------------------------
extern "C" void kernel_launch(void* const* d_in, const int* in_sizes, int n_in,
                              void* d_out, int out_size, void* d_ws, size_t ws_size,
                              hipStream_t stream) {
  const float* x      = (const float*)d_in[0];
  const float* skip   = (const float*)d_in[1];
  const float* w_up   = (const float*)d_in[2];
  const float* b_up   = (const float*)d_in[3];
  const float* w_ref  = (const float*)d_in[4];
  const float* b_ref  = (const float*)d_in[5];
  const float* g1     = (const float*)d_in[6];
  const float* be1    = (const float*)d_in[7];
  const float* w_offh = (const float*)d_in[8];
  const float* b_offh = (const float*)d_in[9];
  const float* w_offv = (const float*)d_in[10];
  const float* b_offv = (const float*)d_in[11];
  const float* w_mask = (const float*)d_in[12];
  const float* b_mask = (const float*)d_in[13];
  const float* w_def  = (const float*)d_in[14];
  const float* g2     = (const float*)d_in[15];
  const float* be2    = (const float*)d_in[16];

  char* W = (char*)d_ws;
  unsigned short* catT  = (unsigned short*)W;                 // 16,777,216 B
  float*          tmp1  = (float*)(W + 16777216);             // 16 MB
  unsigned short* hbufT = (unsigned short*)(W + 33554432);    // 8,388,608 B
  float*          offb  = (float*)(W + 41943040);             // 2,359,296 B
  float*          mskb  = (float*)(W + 44302336);             // 1,179,648 B
  float*          stat  = (float*)(W + 45481984);             // 2,048 B
  unsigned short* wbT   = (unsigned short*)(W + 45484032);    // 589,824 B
  unsigned short* wOM   = (unsigned short*)(W + 46073856);    // 479,232 B
  unsigned short* wdefA = (unsigned short*)(W + 46553088);    // 294,912 B
  float*          dpre  = (float*)W;                          // alias catT (dead)

  hipLaunchKernelGGL(k_wrefT, dim3(1152), dim3(256), 0, stream, w_ref, wbT);
  hipLaunchKernelGGL(k_womT, dim3(936), dim3(256), 0, stream, w_offh, w_offv, w_mask, wOM);
  hipLaunchKernelGGL(k_wdefA, dim3(576), dim3(256), 0, stream, w_def, wdefA);
  hipLaunchKernelGGL(k_upsampleT, dim3(1024), dim3(256), 0, stream, x, w_up, b_up, catT);
  hipLaunchKernelGGL(k_skipT, dim3(2048), dim3(256), 0, stream, skip, catT);
  hipLaunchKernelGGL(k_conv3m, dim3(512), dim3(256), 0, stream, catT, wbT, b_ref, tmp1);
  hipLaunchKernelGGL(k_bnstats, dim3(128), dim3(256), 0, stream, tmp1, stat, stat + 128);
  hipLaunchKernelGGL(k_bnrelu2, dim3(2048), dim3(256), 0, stream, tmp1, stat, stat + 128,
                     g1, be1, hbufT);
  hipLaunchKernelGGL(k_offmasks, dim3(512), dim3(256), 0, stream, hbufT, wOM,
                     b_offh, b_offv, b_mask, offb, mskb);
  hipLaunchKernelGGL(k_deformm, dim3(1024), dim3(256), 0, stream, hbufT, offb, mskb,
                     wdefA, dpre);
  hipLaunchKernelGGL(k_bnstats, dim3(128), dim3(256), 0, stream, dpre, stat + 256, stat + 384);
  hipLaunchKernelGGL(k_bnrelu, dim3(4096), dim3(256), 0, stream,
                     (const float4*)dpre, stat + 256, stat + 384, g2, be2, (float4*)d_out);
}

// Round 8
// 187.071 us; speedup vs baseline: 10.5315x; 1.0748x over previous
//
#include <hip/hip_runtime.h>
#include <hip/hip_bf16.h>

typedef __attribute__((ext_vector_type(8))) short bf16x8;
typedef __attribute__((ext_vector_type(4))) float f32x4;
typedef __attribute__((ext_vector_type(8))) unsigned short u16x8;

static __device__ __forceinline__ unsigned short f2bf(float f) {
  union { float f; unsigned u; } v; v.f = f;
  unsigned r = v.u + 0x7fff + ((v.u >> 16) & 1);
  return (unsigned short)(r >> 16);
}

// ---------------- weight repack: w_up -> wupA[tap][oc][ic] bf16 -------------
__global__ void k_wupA(const float* __restrict__ wu, unsigned short* __restrict__ wupA) {
  int idx = blockIdx.x * 256 + threadIdx.x;   // 131,072 = 4*128*256
  int ic = idx & 255, oc = (idx >> 8) & 127, tap = idx >> 15;
  wupA[idx] = f2bf(wu[(ic * 128 + oc) * 4 + tap]);
}

// ---------------- K1: transposed-conv 2x2 s2 via MFMA -> catT chunks 0..3 ---
// grid 256 = 2b * 64hh * 2half; block 4 waves, wave = one tap (kh,kw)
__global__ __launch_bounds__(256, 2)
void k_upsampleM(const float* __restrict__ x, const unsigned short* __restrict__ wupA,
                 const float* __restrict__ b_up, unsigned short* __restrict__ catT) {
  int bid = blockIdx.x;
  int half = bid & 1;
  int hh = (bid >> 1) & 63;
  int b  = bid >> 7;
  int ww0 = half * 32;
  int t = threadIdx.x;
  int l = t & 63, w = t >> 6;      // w = tap
  int kh = w >> 1, kw = w & 1;
  int lan15 = l & 15, lhi = l >> 4;
  __shared__ unsigned short xs[32][264];   // [px][ic pad 8] 16,896 B

  {  // stage: thread t = ic, 32 consecutive px
    int ic = t;
    const float4* xp = (const float4*)(x + (((long)(b * 256 + ic)) << 12) + (hh << 6) + ww0);
    #pragma unroll
    for (int q = 0; q < 8; ++q) {
      float4 v = xp[q];
      xs[q * 4 + 0][ic] = f2bf(v.x);
      xs[q * 4 + 1][ic] = f2bf(v.y);
      xs[q * 4 + 2][ic] = f2bf(v.z);
      xs[q * 4 + 3][ic] = f2bf(v.w);
    }
  }
  __syncthreads();

  f32x4 acc[8][2];
  #pragma unroll
  for (int m = 0; m < 8; ++m)
    #pragma unroll
    for (int n = 0; n < 2; ++n)
      #pragma unroll
      for (int r = 0; r < 4; ++r) acc[m][n][r] = 0.f;

  const unsigned short* ab = wupA + ((w * 128 + lan15) << 8) + lhi * 8;
  #pragma unroll
  for (int kc = 0; kc < 8; ++kc) {
    bf16x8 b0 = *(const bf16x8*)(&xs[lan15][kc * 32 + lhi * 8]);
    bf16x8 b1 = *(const bf16x8*)(&xs[16 + lan15][kc * 32 + lhi * 8]);
    #pragma unroll
    for (int mt = 0; mt < 8; ++mt) {
      bf16x8 af = *(const bf16x8*)(ab + (mt << 12) + kc * 32);
      acc[mt][0] = __builtin_amdgcn_mfma_f32_16x16x32_bf16(af, b0, acc[mt][0], 0, 0, 0);
      acc[mt][1] = __builtin_amdgcn_mfma_f32_16x16x32_bf16(af, b1, acc[mt][1], 0, 0, 0);
    }
  }

  int oh = 2 * hh + kh;
  #pragma unroll
  for (int mt = 0; mt < 8; ++mt) {
    int ocb = mt * 16 + lhi * 4;
    float4 bias = *(const float4*)(b_up + ocb);
    int cg = ocb >> 5, icl = ocb & 31;
    long plane = ((long)(b * 8 + cg) << 14) + (oh << 7);
    #pragma unroll
    for (int nt = 0; nt < 2; ++nt) {
      int ow = 2 * (ww0 + nt * 16 + lan15) + kw;
      unsigned u0 = (unsigned)f2bf(acc[mt][nt][0] + bias.x)
                  | ((unsigned)f2bf(acc[mt][nt][1] + bias.y) << 16);
      unsigned u1 = (unsigned)f2bf(acc[mt][nt][2] + bias.z)
                  | ((unsigned)f2bf(acc[mt][nt][3] + bias.w) << 16);
      uint2 pk; pk.x = u0; pk.y = u1;
      *(uint2*)(catT + ((plane + ow) << 5) + icl) = pk;
    }
  }
}

// ---------------- K1b: skip -> catT chunks 4..7 (bf16, LDS transpose) -------
__global__ void k_skipT(const float* __restrict__ skip, unsigned short* __restrict__ catT) {
  int bid = blockIdx.x;            // 2 * 4 * 128 * 2 = 2048
  int xb = bid & 1;
  int y  = (bid >> 1) & 127;
  int cg = (bid >> 8) & 3;
  int b  = bid >> 10;
  int t = threadIdx.x;
  __shared__ float ts[32][65];
  int x = t & 63, c4 = t >> 6, x0 = xb * 64;
  #pragma unroll
  for (int p = 0; p < 8; ++p) {
    int c = p * 4 + c4;
    ts[c][x] = skip[(((long)(b * 128 + cg * 32 + c)) << 14) + (y << 7) + x0 + x];
  }
  __syncthreads();
  int ic = t & 31, xg = t >> 5;
  long plane = ((long)(b * 8 + 4 + cg) << 14) + (y << 7) + x0;
  #pragma unroll
  for (int q = 0; q < 8; ++q) {
    int xx = xg * 8 + q;
    catT[((plane + xx) << 5) + ic] = f2bf(ts[ic][xx]);
  }
}

// ---------------- weight repack: w_ref -> wbT[tap][oc][ic] bf16 -------------
__global__ void k_wrefT(const float* __restrict__ wr, unsigned short* __restrict__ wbT) {
  int idx = blockIdx.x * 256 + threadIdx.x;   // 294,912
  int tap = idx >> 15;
  int rem = idx & 32767;
  int oc = rem >> 8, ic = rem & 255;
  wbT[idx] = f2bf(wr[(oc * 256 + ic) * 9 + tap]);
}

// ---------------- weight build: wOM[39][48][128] bf16 -----------------------
__global__ void k_womT(const float* __restrict__ wh, const float* __restrict__ wv,
                       const float* __restrict__ wm, unsigned short* __restrict__ wOM) {
  int idx = blockIdx.x * 256 + threadIdx.x;   // 239,616 = 39*48*128
  int tap = idx / 6144;
  int rem = idx - tap * 6144;
  int j = rem >> 7, ic = rem & 127;
  float v = 0.f;
  if (tap < 15) {
    if (j < 18) v = wh[(j * 128 + ic) * 15 + tap];
  } else if (tap < 30) {
    if (j < 18) v = wv[(j * 128 + ic) * 15 + (tap - 15)];
  } else {
    if (j >= 18 && j < 27) v = wm[((j - 18) * 128 + ic) * 9 + (tap - 30)];
  }
  wOM[idx] = f2bf(v);
}

// ---------------- weight repack: w_def -> MFMA-A fragment order bf16 --------
__global__ void k_wdefA(const float* __restrict__ wd, unsigned short* __restrict__ wdefA) {
  int idx = blockIdx.x * 256 + threadIdx.x;   // 147,456
  if (idx >= 147456) return;
  int j   = idx & 7;
  int oc  = (idx >> 3) & 127;
  int lhi = (idx >> 10) & 3;
  int ks  = idx >> 12;               // 0..35
  int k = ks % 9, cg = ks / 9;
  int c = cg * 32 + lhi * 8 + j;
  wdefA[idx] = f2bf(wd[(oc * 128 + c) * 9 + k]);
}

// ---------------- K2: 3x3 conv 256->128 via MFMA, full-row blocks -----------
// grid 256 = 2b * 128y; block = 128 px row x 128 oc; reg-staged LDS dbuf
__global__ __launch_bounds__(256, 1)
void k_conv3r(const unsigned short* __restrict__ catT, const unsigned short* __restrict__ wbT,
              const float* __restrict__ br, float* __restrict__ out) {
  int bid = blockIdx.x;
  int y = bid & 127, b = bid >> 7;
  int t = threadIdx.x;
  int l = t & 63, w = t >> 6;
  int lan15 = l & 15, lhi = l >> 4;
  __shared__ unsigned short xs[3 * 130 * 40];   // 31,200 B
  const u16x8 z = {0, 0, 0, 0, 0, 0, 0, 0};
  f32x4 acc[2][8];
  #pragma unroll
  for (int m = 0; m < 2; ++m)
    #pragma unroll
    for (int n = 0; n < 8; ++n)
      #pragma unroll
      for (int r = 0; r < 4; ++r) acc[m][n][r] = 0.f;
  const unsigned short* catb = catT + ((long)b << 22);

  // prologue: stage cg=0
  #pragma unroll
  for (int it = 0; it < 7; ++it) {
    int idx = it * 256 + t;
    if (idx < 1560) {
      int g = idx & 3, rc = idx >> 2;
      int r = rc / 130, c = rc - r * 130;
      int gy = y + r - 1, gx = c - 1;
      u16x8 v = z;
      if ((unsigned)gy < 128u && (unsigned)gx < 128u)
        v = *(const u16x8*)(catb + (((long)(gy << 7) + gx) << 5) + g * 8);
      *(u16x8*)(xs + (r * 130 + c) * 40 + g * 8) = v;
    }
  }
  __syncthreads();

  for (int cg = 0; cg < 8; ++cg) {
    // issue next-cg global loads into registers (latency hides under MFMA)
    u16x8 pre[7];
    if (cg < 7) {
      #pragma unroll
      for (int it = 0; it < 7; ++it) {
        int idx = it * 256 + t;
        pre[it] = z;
        if (idx < 1560) {
          int g = idx & 3, rc = idx >> 2;
          int r = rc / 130, c = rc - r * 130;
          int gy = y + r - 1, gx = c - 1;
          if ((unsigned)gy < 128u && (unsigned)gx < 128u)
            pre[it] = *(const u16x8*)(catb + ((((long)(cg + 1) << 14) + (gy << 7) + gx) << 5) + g * 8);
        }
      }
    }
    // A-fragments for this cg
    bf16x8 af[2][9];
    #pragma unroll
    for (int mt = 0; mt < 2; ++mt)
      #pragma unroll
      for (int tap = 0; tap < 9; ++tap)
        af[mt][tap] = *(const bf16x8*)(wbT + ((tap * 128 + w * 32 + mt * 16 + lan15) << 8) + cg * 32 + lhi * 8);
    // MFMA over the staged row
    #pragma unroll
    for (int tap = 0; tap < 9; ++tap) {
      int ky = tap / 3, kx = tap % 3;
      #pragma unroll
      for (int nt = 0; nt < 8; ++nt) {
        int c = nt * 16 + lan15 + kx;
        bf16x8 bfv = *(const bf16x8*)(xs + (ky * 130 + c) * 40 + lhi * 8);
        acc[0][nt] = __builtin_amdgcn_mfma_f32_16x16x32_bf16(af[0][tap], bfv, acc[0][nt], 0, 0, 0);
        acc[1][nt] = __builtin_amdgcn_mfma_f32_16x16x32_bf16(af[1][tap], bfv, acc[1][nt], 0, 0, 0);
      }
    }
    __syncthreads();   // all waves done reading xs
    if (cg < 7) {
      #pragma unroll
      for (int it = 0; it < 7; ++it) {
        int idx = it * 256 + t;
        if (idx < 1560) {
          int g = idx & 3, rc = idx >> 2;
          int r = rc / 130, c = rc - r * 130;
          *(u16x8*)(xs + (r * 130 + c) * 40 + g * 8) = pre[it];
        }
      }
      __syncthreads(); // xs ready for next cg
    }
  }

  #pragma unroll
  for (int mt = 0; mt < 2; ++mt)
    #pragma unroll
    for (int reg = 0; reg < 4; ++reg) {
      int oc = w * 32 + mt * 16 + lhi * 4 + reg;
      float bias = br[oc];
      long obase = ((long)(b * 128 + oc) << 14) + (y << 7);
      #pragma unroll
      for (int nt = 0; nt < 8; ++nt)
        out[obase + nt * 16 + lan15] = acc[mt][nt][reg] + bias;
    }
}

// ---------------- K3/K7: per-channel batch-norm stats -----------------------
__global__ void k_bnstats(const float* __restrict__ src, float* __restrict__ mean,
                          float* __restrict__ rstd) {
  int c = blockIdx.x, t = threadIdx.x;
  float s = 0.f, s2 = 0.f;
  for (int b = 0; b < 2; ++b) {
    const float4* p4 = (const float4*)(src + ((long)(b * 128 + c) << 14));
    for (int i = t; i < 4096; i += 256) {
      float4 v = p4[i];
      s  += v.x + v.y + v.z + v.w;
      s2 += v.x * v.x + v.y * v.y + v.z * v.z + v.w * v.w;
    }
  }
  #pragma unroll
  for (int off = 32; off; off >>= 1) {
    s  += __shfl_down(s, off);
    s2 += __shfl_down(s2, off);
  }
  __shared__ float as[4], as2[4];
  int wid = t >> 6;
  if ((t & 63) == 0) { as[wid] = s; as2[wid] = s2; }
  __syncthreads();
  if (t == 0) {
    float S = as[0] + as[1] + as[2] + as[3];
    float S2 = as2[0] + as2[1] + as2[2] + as2[3];
    float m = S / 32768.f;
    float var = S2 / 32768.f - m * m;
    mean[c] = m;
    rstd[c] = rsqrtf(var + 1e-5f);
  }
}

// ---------------- K4: bn+relu -> hbufT bf16 chunked only --------------------
__global__ void k_bnrelu2(const float* __restrict__ tmp1, const float* __restrict__ mean,
                          const float* __restrict__ rstd, const float* __restrict__ g,
                          const float* __restrict__ be, unsigned short* __restrict__ hbufT) {
  int bid = blockIdx.x;            // 2048
  int xb = bid & 1;
  int y  = (bid >> 1) & 127;
  int cg = (bid >> 8) & 3;
  int b  = bid >> 10;
  int t = threadIdx.x;
  __shared__ float ts[32][65];
  int x = t & 63, c4 = t >> 6, x0 = xb * 64;
  #pragma unroll
  for (int p = 0; p < 8; ++p) {
    int c = p * 4 + c4;
    int ch = cg * 32 + c;
    float sc = rstd[ch] * g[ch];
    float bb = be[ch] - mean[ch] * sc;
    long idx = ((long)(b * 128 + ch) << 14) + (y << 7) + x0 + x;
    ts[c][x] = fmaxf(tmp1[idx] * sc + bb, 0.f);
  }
  __syncthreads();
  int ic = t & 31, xg = t >> 5;
  long plane = ((long)(b * 4 + cg) << 14) + (y << 7) + x0;
  #pragma unroll
  for (int q = 0; q < 8; ++q) {
    int xx = xg * 8 + q;
    hbufT[((plane + xx) << 5) + ic] = f2bf(ts[ic][xx]);
  }
}

// ---------------- K5: offsets + mask via MFMA bf16, LDS-staged A ------------
__global__ __launch_bounds__(256, 2)
void k_offmasks(const unsigned short* __restrict__ hbufT, const unsigned short* __restrict__ wOM,
                const float* __restrict__ bh, const float* __restrict__ bv,
                const float* __restrict__ bm,
                float* __restrict__ off, float* __restrict__ msk) {
  int bid = blockIdx.x;
  int swz = (bid & 7) * 64 + (bid >> 3);   // XCD-chunked, bijective (512 = 8*64)
  int b   = swz >> 8;                      // 256 work-blocks per batch
  int px0 = (swz & 255) * 64;
  int t = threadIdx.x;
  int l = t & 63, w = t >> 6;
  int lan15 = l & 15, lhi = l >> 4;
  int px = px0 + w * 16;
  int y = px >> 7, x0 = px & 127;
  int x = x0 + lan15;

  __shared__ unsigned short As[4 * 32 * 128];   // 32 KB, rows XOR-swizzled

  f32x4 acc0, acc1;
  #pragma unroll
  for (int r = 0; r < 4; ++r) { acc0[r] = 0.f; acc1[r] = 0.f; }

  const unsigned short* hb = hbufT + ((long)b << 21);
  const u16x8 z = {0, 0, 0, 0, 0, 0, 0, 0};

  for (int grp = 0; grp < 10; ++grp) {
    int tap0 = grp * 4;
    __syncthreads();                            // previous group's LDS reads done
    #pragma unroll
    for (int it = 0; it < 8; ++it) {            // stage 4 taps x 32 j x 128 ch
      int i = it * 256 + t;
      int tl = i >> 9, rem = i & 511;
      int j = rem >> 4, g16 = rem & 15;
      int tap = tap0 + tl;
      u16x8 v = z;
      if (tap < 39) v = *(const u16x8*)(wOM + ((tap * 48 + j) << 7) + g16 * 8);
      *(u16x8*)(As + tl * 4096 + j * 128 + ((g16 ^ (j & 7)) << 3)) = v;
    }
    __syncthreads();
    #pragma unroll
    for (int tl = 0; tl < 4; ++tl) {
      int tap = tap0 + tl;
      if (tap < 39) {
        int ky = (tap < 15) ? 0 : ((tap < 30) ? (tap - 22) : ((tap - 30) / 3 - 1));
        int kx = (tap < 15) ? (tap - 7) : ((tap < 30) ? 0 : ((tap - 30) % 3 - 1));
        int gy = y + ky, gx = x + kx;
        bool valid = ((unsigned)gy < 128u) & ((unsigned)gx < 128u);
        const unsigned short* bp = hb + ((((long)(gy << 7) + gx) << 5) + lhi * 8);
        bool do0 = tap < 30;
        const unsigned short* a0base = As + tl * 4096 + lan15 * 128;
        const unsigned short* a1base = a0base + 16 * 128;
        #pragma unroll
        for (int cg = 0; cg < 4; ++cg) {
          u16x8 bv8 = valid ? *(const u16x8*)(bp + ((long)cg << 19)) : z;
          bf16x8 bf = (bf16x8)bv8;
          int aoff = (((cg << 2) + lhi) ^ (lan15 & 7)) << 3;
          acc1 = __builtin_amdgcn_mfma_f32_16x16x32_bf16(*(const bf16x8*)(a1base + aoff),
                                                         bf, acc1, 0, 0, 0);
          if (do0)
            acc0 = __builtin_amdgcn_mfma_f32_16x16x32_bf16(*(const bf16x8*)(a0base + aoff),
                                                           bf, acc0, 0, 0, 0);
        }
      }
    }
  }

  int sp = (y << 7) + x;
  #pragma unroll
  for (int reg = 0; reg < 4; ++reg) {
    int j0 = lhi * 4 + reg;        // 0..15, all offsets
    off[((long)(b * 18 + j0) << 14) + sp] = acc0[reg] + bh[j0] + bv[j0];
    int j1 = 16 + lhi * 4 + reg;   // 16..31
    float v = acc1[reg];
    if (j1 < 18) {
      off[((long)(b * 18 + j1) << 14) + sp] = v + bh[j1] + bv[j1];
    } else if (j1 < 27) {
      int jm = j1 - 18;
      msk[((long)(b * 9 + jm) << 14) + sp] = 1.f / (1.f + expf(-(v + bm[jm])));
    }
  }
}

// ---------------- K6: deformable 3x3 conv via MFMA bf16 ---------------------
__global__ __launch_bounds__(256, 2)
void k_deformm(const unsigned short* __restrict__ hbufT, const float* __restrict__ off,
               const float* __restrict__ msk, const unsigned short* __restrict__ wdefA,
               float* __restrict__ out) {
  int bid = blockIdx.x;            // 2 * 128 * 4 = 1024
  int xt = bid & 3;
  int h  = (bid >> 2) & 127;
  int b  = bid >> 9;
  int w0 = xt * 32;
  int t = threadIdx.x;
  int l = t & 63, w = t >> 6;
  int lan15 = l & 15, lhi = l >> 4;

  __shared__ __align__(16) unsigned short S[9][32][40];  // 23,040 B
  __shared__ int   p_y0[288], p_x0[288];
  __shared__ float p_w00[288], p_w01[288], p_w10[288], p_w11[288];

  for (int idx = t; idx < 288; idx += 256) {
    int k = idx >> 5, pix = idx & 31;
    int sp = (h << 7) + w0 + pix;
    float dy = off[((long)(b * 18 + 2 * k) << 14) + sp];
    float dx = off[((long)(b * 18 + 2 * k + 1) << 14) + sp];
    float m  = msk[((long)(b * 9 + k) << 14) + sp];
    float y  = dy + (float)(h + k / 3 - 1);
    float xx = dx + (float)(w0 + pix + (k % 3) - 1);
    float y0f = floorf(y), x0f = floorf(xx);
    float wy = y - y0f, wx = xx - x0f;
    p_y0[idx] = (int)y0f; p_x0[idx] = (int)x0f;
    p_w00[idx] = (1.f - wy) * (1.f - wx) * m;
    p_w01[idx] = (1.f - wy) * wx * m;
    p_w10[idx] = wy * (1.f - wx) * m;
    p_w11[idx] = wy * wx * m;
  }

  f32x4 acc[2][2];
  #pragma unroll
  for (int m = 0; m < 2; ++m)
    #pragma unroll
    for (int n = 0; n < 2; ++n)
      #pragma unroll
      for (int r = 0; r < 4; ++r) acc[m][n][r] = 0.f;

  for (int cg = 0; cg < 4; ++cg) {
    __syncthreads();   // offsets ready (cg=0); previous MFMA reads done (cg>0)
    const unsigned short* hb = hbufT + (((long)(b * 4 + cg)) << 19);
    for (int idx = t; idx < 1152; idx += 256) {   // 9k * 32pix * 4cq
      int cq = idx & 3, pix = (idx >> 2) & 31, k = idx >> 7;
      int kp = (k << 5) + pix;
      int y0 = p_y0[kp], x0 = p_x0[kp];
      float c00 = p_w00[kp], c01 = p_w01[kp], c10 = p_w10[kp], c11 = p_w11[kp];
      bool yi0 = (unsigned)y0 < 128u, yi1 = (unsigned)(y0 + 1) < 128u;
      bool xi0 = (unsigned)x0 < 128u, xi1 = (unsigned)(x0 + 1) < 128u;
      const unsigned short* pbase = hb + ((((long)(y0 << 7) + x0) << 5) + cq * 8);
      u16x8 z = {0, 0, 0, 0, 0, 0, 0, 0};
      u16x8 v00 = (yi0 && xi0) ? *(const u16x8*)pbase          : z;
      u16x8 v01 = (yi0 && xi1) ? *(const u16x8*)(pbase + 32)   : z;
      u16x8 v10 = (yi1 && xi0) ? *(const u16x8*)(pbase + 4096) : z;
      u16x8 v11 = (yi1 && xi1) ? *(const u16x8*)(pbase + 4128) : z;
      u16x8 o;
      #pragma unroll
      for (int j = 0; j < 8; ++j) {
        float s = c00 * __uint_as_float((unsigned)(unsigned short)v00[j] << 16)
                + c01 * __uint_as_float((unsigned)(unsigned short)v01[j] << 16)
                + c10 * __uint_as_float((unsigned)(unsigned short)v10[j] << 16)
                + c11 * __uint_as_float((unsigned)(unsigned short)v11[j] << 16);
        o[j] = f2bf(s);
      }
      *(u16x8*)(&S[k][pix][cq * 8]) = o;
    }
    bf16x8 af0[9], af1[9];
    #pragma unroll
    for (int k = 0; k < 9; ++k) {
      long wbase = ((((long)(cg * 9 + k) * 4 + lhi) * 128) + w * 32 + lan15) * 8;
      af0[k] = *(const bf16x8*)(wdefA + wbase);
      af1[k] = *(const bf16x8*)(wdefA + wbase + 128);   // +16 oc
    }
    __syncthreads();
    #pragma unroll
    for (int k = 0; k < 9; ++k) {
      #pragma unroll
      for (int nt = 0; nt < 2; ++nt) {
        bf16x8 bfv = *(const bf16x8*)(&S[k][nt * 16 + lan15][lhi * 8]);
        acc[0][nt] = __builtin_amdgcn_mfma_f32_16x16x32_bf16(af0[k], bfv, acc[0][nt], 0, 0, 0);
        acc[1][nt] = __builtin_amdgcn_mfma_f32_16x16x32_bf16(af1[k], bfv, acc[1][nt], 0, 0, 0);
      }
    }
  }
  #pragma unroll
  for (int mt = 0; mt < 2; ++mt)
    #pragma unroll
    for (int reg = 0; reg < 4; ++reg) {
      int oc = w * 32 + mt * 16 + lhi * 4 + reg;
      long obase = ((long)(b * 128 + oc) << 14) + (h << 7) + w0;
      out[obase + lan15]      = acc[mt][0][reg];
      out[obase + 16 + lan15] = acc[mt][1][reg];
    }
}

// ---------------- K8: plain bn+relu (final output) --------------------------
__global__ void k_bnrelu(const float4* __restrict__ src, const float* __restrict__ mean,
                         const float* __restrict__ rstd, const float* __restrict__ g,
                         const float* __restrict__ be, float4* __restrict__ dst) {
  int i = blockIdx.x * 256 + threadIdx.x;   // over 1,048,576 float4
  if (i >= 1048576) return;
  int c = (i >> 12) & 127;
  float sc = rstd[c] * g[c];
  float bb = be[c] - mean[c] * sc;
  float4 v = src[i];
  v.x = fmaxf(v.x * sc + bb, 0.f);
  v.y = fmaxf(v.y * sc + bb, 0.f);
  v.z = fmaxf(v.z * sc + bb, 0.f);
  v.w = fmaxf(v.w * sc + bb, 0.f);
  dst[i] = v;
}

// ---------------- launcher --------------------------------------------------
extern "C" void kernel_launch(void* const* d_in, const int* in_sizes, int n_in,
                              void* d_out, int out_size, void* d_ws, size_t ws_size,
                              hipStream_t stream) {
  const float* x      = (const float*)d_in[0];
  const float* skip   = (const float*)d_in[1];
  const float* w_up   = (const float*)d_in[2];
  const float* b_up   = (const float*)d_in[3];
  const float* w_ref  = (const float*)d_in[4];
  const float* b_ref  = (const float*)d_in[5];
  const float* g1     = (const float*)d_in[6];
  const float* be1    = (const float*)d_in[7];
  const float* w_offh = (const float*)d_in[8];
  const float* b_offh = (const float*)d_in[9];
  const float* w_offv = (const float*)d_in[10];
  const float* b_offv = (const float*)d_in[11];
  const float* w_mask = (const float*)d_in[12];
  const float* b_mask = (const float*)d_in[13];
  const float* w_def  = (const float*)d_in[14];
  const float* g2     = (const float*)d_in[15];
  const float* be2    = (const float*)d_in[16];

  char* W = (char*)d_ws;
  unsigned short* catT  = (unsigned short*)W;                 // 16,777,216 B
  float*          tmp1  = (float*)(W + 16777216);             // 16 MB
  unsigned short* hbufT = (unsigned short*)(W + 33554432);    // 8,388,608 B
  float*          offb  = (float*)(W + 41943040);             // 2,359,296 B
  float*          mskb  = (float*)(W + 44302336);             // 1,179,648 B
  float*          stat  = (float*)(W + 45481984);             // 2,048 B
  unsigned short* wbT   = (unsigned short*)(W + 45484032);    // 589,824 B
  unsigned short* wOM   = (unsigned short*)(W + 46073856);    // 479,232 B
  unsigned short* wdefA = (unsigned short*)(W + 46553088);    // 294,912 B
  unsigned short* wupA  = (unsigned short*)(W + 46848000);    // 262,144 B
  float*          dpre  = (float*)W;                          // alias catT (dead)

  hipLaunchKernelGGL(k_wrefT, dim3(1152), dim3(256), 0, stream, w_ref, wbT);
  hipLaunchKernelGGL(k_womT, dim3(936), dim3(256), 0, stream, w_offh, w_offv, w_mask, wOM);
  hipLaunchKernelGGL(k_wdefA, dim3(576), dim3(256), 0, stream, w_def, wdefA);
  hipLaunchKernelGGL(k_wupA, dim3(512), dim3(256), 0, stream, w_up, wupA);
  hipLaunchKernelGGL(k_upsampleM, dim3(256), dim3(256), 0, stream, x, wupA, b_up, catT);
  hipLaunchKernelGGL(k_skipT, dim3(2048), dim3(256), 0, stream, skip, catT);
  hipLaunchKernelGGL(k_conv3r, dim3(256), dim3(256), 0, stream, catT, wbT, b_ref, tmp1);
  hipLaunchKernelGGL(k_bnstats, dim3(128), dim3(256), 0, stream, tmp1, stat, stat + 128);
  hipLaunchKernelGGL(k_bnrelu2, dim3(2048), dim3(256), 0, stream, tmp1, stat, stat + 128,
                     g1, be1, hbufT);
  hipLaunchKernelGGL(k_offmasks, dim3(512), dim3(256), 0, stream, hbufT, wOM,
                     b_offh, b_offv, b_mask, offb, mskb);
  hipLaunchKernelGGL(k_deformm, dim3(1024), dim3(256), 0, stream, hbufT, offb, mskb,
                     wdefA, dpre);
  hipLaunchKernelGGL(k_bnstats, dim3(128), dim3(256), 0, stream, dpre, stat + 256, stat + 384);
  hipLaunchKernelGGL(k_bnrelu, dim3(4096), dim3(256), 0, stream,
                     (const float4*)dpre, stat + 256, stat + 384, g2, be2, (float4*)d_out);
}

// Round 9
// 184.908 us; speedup vs baseline: 10.6548x; 1.0117x over previous
//
#include <hip/hip_runtime.h>
#include <hip/hip_bf16.h>

typedef __attribute__((ext_vector_type(8))) short bf16x8;
typedef __attribute__((ext_vector_type(4))) float f32x4;
typedef __attribute__((ext_vector_type(8))) unsigned short u16x8;

static __device__ __forceinline__ unsigned short f2bf(float f) {
  union { float f; unsigned u; } v; v.f = f;
  unsigned r = v.u + 0x7fff + ((v.u >> 16) & 1);
  return (unsigned short)(r >> 16);
}

// ---------------- weight repack: w_up -> wupA[tap][oc][ic] bf16 -------------
__global__ void k_wupA(const float* __restrict__ wu, unsigned short* __restrict__ wupA) {
  int idx = blockIdx.x * 256 + threadIdx.x;   // 131,072 = 4*128*256
  int ic = idx & 255, oc = (idx >> 8) & 127, tap = idx >> 15;
  wupA[idx] = f2bf(wu[(ic * 128 + oc) * 4 + tap]);
}

// ---------------- K1: transposed-conv 2x2 s2 via MFMA -> catT chunks 0..3 ---
__global__ __launch_bounds__(256, 2)
void k_upsampleM(const float* __restrict__ x, const unsigned short* __restrict__ wupA,
                 const float* __restrict__ b_up, unsigned short* __restrict__ catT) {
  int bid = blockIdx.x;
  int half = bid & 1;
  int hh = (bid >> 1) & 63;
  int b  = bid >> 7;
  int ww0 = half * 32;
  int t = threadIdx.x;
  int l = t & 63, w = t >> 6;      // w = tap
  int kh = w >> 1, kw = w & 1;
  int lan15 = l & 15, lhi = l >> 4;
  __shared__ unsigned short xs[32][264];   // [px][ic pad 8] 16,896 B

  {  // stage: thread t = ic, 32 consecutive px
    int ic = t;
    const float4* xp = (const float4*)(x + (((long)(b * 256 + ic)) << 12) + (hh << 6) + ww0);
    #pragma unroll
    for (int q = 0; q < 8; ++q) {
      float4 v = xp[q];
      xs[q * 4 + 0][ic] = f2bf(v.x);
      xs[q * 4 + 1][ic] = f2bf(v.y);
      xs[q * 4 + 2][ic] = f2bf(v.z);
      xs[q * 4 + 3][ic] = f2bf(v.w);
    }
  }
  __syncthreads();

  f32x4 acc[8][2];
  #pragma unroll
  for (int m = 0; m < 8; ++m)
    #pragma unroll
    for (int n = 0; n < 2; ++n)
      #pragma unroll
      for (int r = 0; r < 4; ++r) acc[m][n][r] = 0.f;

  const unsigned short* ab = wupA + ((w * 128 + lan15) << 8) + lhi * 8;
  #pragma unroll
  for (int kc = 0; kc < 8; ++kc) {
    bf16x8 b0 = *(const bf16x8*)(&xs[lan15][kc * 32 + lhi * 8]);
    bf16x8 b1 = *(const bf16x8*)(&xs[16 + lan15][kc * 32 + lhi * 8]);
    #pragma unroll
    for (int mt = 0; mt < 8; ++mt) {
      bf16x8 af = *(const bf16x8*)(ab + (mt << 12) + kc * 32);
      acc[mt][0] = __builtin_amdgcn_mfma_f32_16x16x32_bf16(af, b0, acc[mt][0], 0, 0, 0);
      acc[mt][1] = __builtin_amdgcn_mfma_f32_16x16x32_bf16(af, b1, acc[mt][1], 0, 0, 0);
    }
  }

  int oh = 2 * hh + kh;
  #pragma unroll
  for (int mt = 0; mt < 8; ++mt) {
    int ocb = mt * 16 + lhi * 4;
    float4 bias = *(const float4*)(b_up + ocb);
    int cg = ocb >> 5, icl = ocb & 31;
    long plane = ((long)(b * 8 + cg) << 14) + (oh << 7);
    #pragma unroll
    for (int nt = 0; nt < 2; ++nt) {
      int ow = 2 * (ww0 + nt * 16 + lan15) + kw;
      unsigned u0 = (unsigned)f2bf(acc[mt][nt][0] + bias.x)
                  | ((unsigned)f2bf(acc[mt][nt][1] + bias.y) << 16);
      unsigned u1 = (unsigned)f2bf(acc[mt][nt][2] + bias.z)
                  | ((unsigned)f2bf(acc[mt][nt][3] + bias.w) << 16);
      uint2 pk; pk.x = u0; pk.y = u1;
      *(uint2*)(catT + ((plane + ow) << 5) + icl) = pk;
    }
  }
}

// ---------------- K1b: skip -> catT chunks 4..7 (bf16, LDS transpose) -------
__global__ void k_skipT(const float* __restrict__ skip, unsigned short* __restrict__ catT) {
  int bid = blockIdx.x;            // 2 * 4 * 128 * 2 = 2048
  int xb = bid & 1;
  int y  = (bid >> 1) & 127;
  int cg = (bid >> 8) & 3;
  int b  = bid >> 10;
  int t = threadIdx.x;
  __shared__ float ts[32][65];
  int x = t & 63, c4 = t >> 6, x0 = xb * 64;
  #pragma unroll
  for (int p = 0; p < 8; ++p) {
    int c = p * 4 + c4;
    ts[c][x] = skip[(((long)(b * 128 + cg * 32 + c)) << 14) + (y << 7) + x0 + x];
  }
  __syncthreads();
  int ic = t & 31, xg = t >> 5;
  long plane = ((long)(b * 8 + 4 + cg) << 14) + (y << 7) + x0;
  #pragma unroll
  for (int q = 0; q < 8; ++q) {
    int xx = xg * 8 + q;
    catT[((plane + xx) << 5) + ic] = f2bf(ts[ic][xx]);
  }
}

// ---------------- weight repack: w_ref -> wbT[tap][oc][ic] bf16 -------------
__global__ void k_wrefT(const float* __restrict__ wr, unsigned short* __restrict__ wbT) {
  int idx = blockIdx.x * 256 + threadIdx.x;   // 294,912
  int tap = idx >> 15;
  int rem = idx & 32767;
  int oc = rem >> 8, ic = rem & 255;
  wbT[idx] = f2bf(wr[(oc * 256 + ic) * 9 + tap]);
}

// ---------------- weight build: wOM[39][48][128] bf16 -----------------------
__global__ void k_womT(const float* __restrict__ wh, const float* __restrict__ wv,
                       const float* __restrict__ wm, unsigned short* __restrict__ wOM) {
  int idx = blockIdx.x * 256 + threadIdx.x;   // 239,616 = 39*48*128
  int tap = idx / 6144;
  int rem = idx - tap * 6144;
  int j = rem >> 7, ic = rem & 127;
  float v = 0.f;
  if (tap < 15) {
    if (j < 18) v = wh[(j * 128 + ic) * 15 + tap];
  } else if (tap < 30) {
    if (j < 18) v = wv[(j * 128 + ic) * 15 + (tap - 15)];
  } else {
    if (j >= 18 && j < 27) v = wm[((j - 18) * 128 + ic) * 9 + (tap - 30)];
  }
  wOM[idx] = f2bf(v);
}

// ---------------- weight repack: w_def -> MFMA-A fragment order bf16 --------
__global__ void k_wdefA(const float* __restrict__ wd, unsigned short* __restrict__ wdefA) {
  int idx = blockIdx.x * 256 + threadIdx.x;   // 147,456
  if (idx >= 147456) return;
  int j   = idx & 7;
  int oc  = (idx >> 3) & 127;
  int lhi = (idx >> 10) & 3;
  int ks  = idx >> 12;               // 0..35
  int k = ks % 9, cg = ks / 9;
  int c = cg * 32 + lhi * 8 + j;
  wdefA[idx] = f2bf(wd[(oc * 128 + c) * 9 + k]);
}

// ---------------- K2: 3x3 conv 256->128 via MFMA, 8-wave full-row blocks ----
// grid 256 = 2b * 128y (XCD-swizzled); 512 threads; wave = 32oc x 64px
__global__ __launch_bounds__(512, 2)
void k_conv3w(const unsigned short* __restrict__ catT, const unsigned short* __restrict__ wbT,
              const float* __restrict__ br, float* __restrict__ out) {
  int bid = blockIdx.x;
  int swz = (bid & 7) * 32 + (bid >> 3);   // XCD-chunked, bijective (256 = 8*32)
  int y = swz & 127, b = swz >> 7;
  int t = threadIdx.x;
  int l = t & 63, w = t >> 6;              // 8 waves
  int ocg = w & 3, xh = w >> 2;
  int oc0 = ocg * 32, px0 = xh * 64;
  int lan15 = l & 15, lhi = l >> 4;
  __shared__ unsigned short xs[3 * 130 * 40];   // 31,200 B
  const u16x8 z = {0, 0, 0, 0, 0, 0, 0, 0};
  f32x4 acc[2][4];
  #pragma unroll
  for (int m = 0; m < 2; ++m)
    #pragma unroll
    for (int n = 0; n < 4; ++n)
      #pragma unroll
      for (int r = 0; r < 4; ++r) acc[m][n][r] = 0.f;
  const unsigned short* catb = catT + ((long)b << 22);

  // prologue: stage cg=0 (1560 granules over 512 threads)
  #pragma unroll
  for (int it = 0; it < 4; ++it) {
    int idx = it * 512 + t;
    if (idx < 1560) {
      int g = idx & 3, rc = idx >> 2;
      int r = rc / 130, c = rc - r * 130;
      int gy = y + r - 1, gx = c - 1;
      u16x8 v = z;
      if ((unsigned)gy < 128u && (unsigned)gx < 128u)
        v = *(const u16x8*)(catb + (((long)(gy << 7) + gx) << 5) + g * 8);
      *(u16x8*)(xs + (r * 130 + c) * 40 + g * 8) = v;
    }
  }
  __syncthreads();

  for (int cg = 0; cg < 8; ++cg) {
    // issue next-cg global loads into registers
    u16x8 pre[4];
    if (cg < 7) {
      #pragma unroll
      for (int it = 0; it < 4; ++it) {
        int idx = it * 512 + t;
        pre[it] = z;
        if (idx < 1560) {
          int g = idx & 3, rc = idx >> 2;
          int r = rc / 130, c = rc - r * 130;
          int gy = y + r - 1, gx = c - 1;
          if ((unsigned)gy < 128u && (unsigned)gx < 128u)
            pre[it] = *(const u16x8*)(catb + ((((long)(cg + 1) << 14) + (gy << 7) + gx) << 5) + g * 8);
        }
      }
    }
    // A-fragments for this cg (resident in regs across the MFMA phase)
    bf16x8 af[2][9];
    #pragma unroll
    for (int mt = 0; mt < 2; ++mt)
      #pragma unroll
      for (int tap = 0; tap < 9; ++tap)
        af[mt][tap] = *(const bf16x8*)(wbT + ((tap * 128 + oc0 + mt * 16 + lan15) << 8) + cg * 32 + lhi * 8);
    #pragma unroll
    for (int tap = 0; tap < 9; ++tap) {
      int ky = tap / 3, kx = tap % 3;
      #pragma unroll
      for (int nt = 0; nt < 4; ++nt) {
        int c = px0 + nt * 16 + lan15 + kx;
        bf16x8 bfv = *(const bf16x8*)(xs + (ky * 130 + c) * 40 + lhi * 8);
        acc[0][nt] = __builtin_amdgcn_mfma_f32_16x16x32_bf16(af[0][tap], bfv, acc[0][nt], 0, 0, 0);
        acc[1][nt] = __builtin_amdgcn_mfma_f32_16x16x32_bf16(af[1][tap], bfv, acc[1][nt], 0, 0, 0);
      }
    }
    __syncthreads();   // all waves done reading xs
    if (cg < 7) {
      #pragma unroll
      for (int it = 0; it < 4; ++it) {
        int idx = it * 512 + t;
        if (idx < 1560) {
          int g = idx & 3, rc = idx >> 2;
          int r = rc / 130, c = rc - r * 130;
          *(u16x8*)(xs + (r * 130 + c) * 40 + g * 8) = pre[it];
        }
      }
      __syncthreads(); // xs ready for next cg
    }
  }

  #pragma unroll
  for (int mt = 0; mt < 2; ++mt)
    #pragma unroll
    for (int reg = 0; reg < 4; ++reg) {
      int oc = oc0 + mt * 16 + lhi * 4 + reg;
      float bias = br[oc];
      long obase = ((long)(b * 128 + oc) << 14) + (y << 7) + px0;
      #pragma unroll
      for (int nt = 0; nt < 4; ++nt)
        out[obase + nt * 16 + lan15] = acc[mt][nt][reg] + bias;
    }
}

// ---------------- K3/K7: per-channel batch-norm stats -----------------------
__global__ void k_bnstats(const float* __restrict__ src, float* __restrict__ mean,
                          float* __restrict__ rstd) {
  int c = blockIdx.x, t = threadIdx.x;
  float s = 0.f, s2 = 0.f;
  for (int b = 0; b < 2; ++b) {
    const float4* p4 = (const float4*)(src + ((long)(b * 128 + c) << 14));
    for (int i = t; i < 4096; i += 256) {
      float4 v = p4[i];
      s  += v.x + v.y + v.z + v.w;
      s2 += v.x * v.x + v.y * v.y + v.z * v.z + v.w * v.w;
    }
  }
  #pragma unroll
  for (int off = 32; off; off >>= 1) {
    s  += __shfl_down(s, off);
    s2 += __shfl_down(s2, off);
  }
  __shared__ float as[4], as2[4];
  int wid = t >> 6;
  if ((t & 63) == 0) { as[wid] = s; as2[wid] = s2; }
  __syncthreads();
  if (t == 0) {
    float S = as[0] + as[1] + as[2] + as[3];
    float S2 = as2[0] + as2[1] + as2[2] + as2[3];
    float m = S / 32768.f;
    float var = S2 / 32768.f - m * m;
    mean[c] = m;
    rstd[c] = rsqrtf(var + 1e-5f);
  }
}

// ---------------- K4: bn+relu -> hbufT bf16 chunked only --------------------
__global__ void k_bnrelu2(const float* __restrict__ tmp1, const float* __restrict__ mean,
                          const float* __restrict__ rstd, const float* __restrict__ g,
                          const float* __restrict__ be, unsigned short* __restrict__ hbufT) {
  int bid = blockIdx.x;            // 2048
  int xb = bid & 1;
  int y  = (bid >> 1) & 127;
  int cg = (bid >> 8) & 3;
  int b  = bid >> 10;
  int t = threadIdx.x;
  __shared__ float ts[32][65];
  int x = t & 63, c4 = t >> 6, x0 = xb * 64;
  #pragma unroll
  for (int p = 0; p < 8; ++p) {
    int c = p * 4 + c4;
    int ch = cg * 32 + c;
    float sc = rstd[ch] * g[ch];
    float bb = be[ch] - mean[ch] * sc;
    long idx = ((long)(b * 128 + ch) << 14) + (y << 7) + x0 + x;
    ts[c][x] = fmaxf(tmp1[idx] * sc + bb, 0.f);
  }
  __syncthreads();
  int ic = t & 31, xg = t >> 5;
  long plane = ((long)(b * 4 + cg) << 14) + (y << 7) + x0;
  #pragma unroll
  for (int q = 0; q < 8; ++q) {
    int xx = xg * 8 + q;
    hbufT[((plane + xx) << 5) + ic] = f2bf(ts[ic][xx]);
  }
}

// ---------------- K5: offsets + mask via MFMA bf16, LDS-staged A ------------
__global__ __launch_bounds__(256, 2)
void k_offmasks(const unsigned short* __restrict__ hbufT, const unsigned short* __restrict__ wOM,
                const float* __restrict__ bh, const float* __restrict__ bv,
                const float* __restrict__ bm,
                float* __restrict__ off, float* __restrict__ msk) {
  int bid = blockIdx.x;
  int swz = (bid & 7) * 64 + (bid >> 3);   // XCD-chunked, bijective (512 = 8*64)
  int b   = swz >> 8;                      // 256 work-blocks per batch
  int px0 = (swz & 255) * 64;
  int t = threadIdx.x;
  int l = t & 63, w = t >> 6;
  int lan15 = l & 15, lhi = l >> 4;
  int px = px0 + w * 16;
  int y = px >> 7, x0 = px & 127;
  int x = x0 + lan15;

  __shared__ unsigned short As[4 * 32 * 128];   // 32 KB, rows XOR-swizzled

  f32x4 acc0, acc1;
  #pragma unroll
  for (int r = 0; r < 4; ++r) { acc0[r] = 0.f; acc1[r] = 0.f; }

  const unsigned short* hb = hbufT + ((long)b << 21);
  const u16x8 z = {0, 0, 0, 0, 0, 0, 0, 0};

  for (int grp = 0; grp < 10; ++grp) {
    int tap0 = grp * 4;
    __syncthreads();                            // previous group's LDS reads done
    #pragma unroll
    for (int it = 0; it < 8; ++it) {            // stage 4 taps x 32 j x 128 ch
      int i = it * 256 + t;
      int tl = i >> 9, rem = i & 511;
      int j = rem >> 4, g16 = rem & 15;
      int tap = tap0 + tl;
      u16x8 v = z;
      if (tap < 39) v = *(const u16x8*)(wOM + ((tap * 48 + j) << 7) + g16 * 8);
      *(u16x8*)(As + tl * 4096 + j * 128 + ((g16 ^ (j & 7)) << 3)) = v;
    }
    __syncthreads();
    #pragma unroll
    for (int tl = 0; tl < 4; ++tl) {
      int tap = tap0 + tl;
      if (tap < 39) {
        int ky = (tap < 15) ? 0 : ((tap < 30) ? (tap - 22) : ((tap - 30) / 3 - 1));
        int kx = (tap < 15) ? (tap - 7) : ((tap < 30) ? 0 : ((tap - 30) % 3 - 1));
        int gy = y + ky, gx = x + kx;
        bool valid = ((unsigned)gy < 128u) & ((unsigned)gx < 128u);
        const unsigned short* bp = hb + ((((long)(gy << 7) + gx) << 5) + lhi * 8);
        bool do0 = tap < 30;
        const unsigned short* a0base = As + tl * 4096 + lan15 * 128;
        const unsigned short* a1base = a0base + 16 * 128;
        #pragma unroll
        for (int cg = 0; cg < 4; ++cg) {
          u16x8 bv8 = valid ? *(const u16x8*)(bp + ((long)cg << 19)) : z;
          bf16x8 bf = (bf16x8)bv8;
          int aoff = (((cg << 2) + lhi) ^ (lan15 & 7)) << 3;
          acc1 = __builtin_amdgcn_mfma_f32_16x16x32_bf16(*(const bf16x8*)(a1base + aoff),
                                                         bf, acc1, 0, 0, 0);
          if (do0)
            acc0 = __builtin_amdgcn_mfma_f32_16x16x32_bf16(*(const bf16x8*)(a0base + aoff),
                                                           bf, acc0, 0, 0, 0);
        }
      }
    }
  }

  int sp = (y << 7) + x;
  #pragma unroll
  for (int reg = 0; reg < 4; ++reg) {
    int j0 = lhi * 4 + reg;        // 0..15, all offsets
    off[((long)(b * 18 + j0) << 14) + sp] = acc0[reg] + bh[j0] + bv[j0];
    int j1 = 16 + lhi * 4 + reg;   // 16..31
    float v = acc1[reg];
    if (j1 < 18) {
      off[((long)(b * 18 + j1) << 14) + sp] = v + bh[j1] + bv[j1];
    } else if (j1 < 27) {
      int jm = j1 - 18;
      msk[((long)(b * 9 + jm) << 14) + sp] = 1.f / (1.f + expf(-(v + bm[jm])));
    }
  }
}

// ---------------- K6: deformable 3x3 conv via MFMA bf16 ---------------------
__global__ __launch_bounds__(256, 2)
void k_deformm(const unsigned short* __restrict__ hbufT, const float* __restrict__ off,
               const float* __restrict__ msk, const unsigned short* __restrict__ wdefA,
               float* __restrict__ out) {
  int bid = blockIdx.x;            // 2 * 128 * 4 = 1024
  int xt = bid & 3;
  int h  = (bid >> 2) & 127;
  int b  = bid >> 9;
  int w0 = xt * 32;
  int t = threadIdx.x;
  int l = t & 63, w = t >> 6;
  int lan15 = l & 15, lhi = l >> 4;

  __shared__ __align__(16) unsigned short S[9][32][40];  // 23,040 B
  __shared__ int   p_y0[288], p_x0[288];
  __shared__ float p_w00[288], p_w01[288], p_w10[288], p_w11[288];

  for (int idx = t; idx < 288; idx += 256) {
    int k = idx >> 5, pix = idx & 31;
    int sp = (h << 7) + w0 + pix;
    float dy = off[((long)(b * 18 + 2 * k) << 14) + sp];
    float dx = off[((long)(b * 18 + 2 * k + 1) << 14) + sp];
    float m  = msk[((long)(b * 9 + k) << 14) + sp];
    float y  = dy + (float)(h + k / 3 - 1);
    float xx = dx + (float)(w0 + pix + (k % 3) - 1);
    float y0f = floorf(y), x0f = floorf(xx);
    float wy = y - y0f, wx = xx - x0f;
    p_y0[idx] = (int)y0f; p_x0[idx] = (int)x0f;
    p_w00[idx] = (1.f - wy) * (1.f - wx) * m;
    p_w01[idx] = (1.f - wy) * wx * m;
    p_w10[idx] = wy * (1.f - wx) * m;
    p_w11[idx] = wy * wx * m;
  }

  f32x4 acc[2][2];
  #pragma unroll
  for (int m = 0; m < 2; ++m)
    #pragma unroll
    for (int n = 0; n < 2; ++n)
      #pragma unroll
      for (int r = 0; r < 4; ++r) acc[m][n][r] = 0.f;

  for (int cg = 0; cg < 4; ++cg) {
    __syncthreads();   // offsets ready (cg=0); previous MFMA reads done (cg>0)
    const unsigned short* hb = hbufT + (((long)(b * 4 + cg)) << 19);
    for (int idx = t; idx < 1152; idx += 256) {   // 9k * 32pix * 4cq
      int cq = idx & 3, pix = (idx >> 2) & 31, k = idx >> 7;
      int kp = (k << 5) + pix;
      int y0 = p_y0[kp], x0 = p_x0[kp];
      float c00 = p_w00[kp], c01 = p_w01[kp], c10 = p_w10[kp], c11 = p_w11[kp];
      bool yi0 = (unsigned)y0 < 128u, yi1 = (unsigned)(y0 + 1) < 128u;
      bool xi0 = (unsigned)x0 < 128u, xi1 = (unsigned)(x0 + 1) < 128u;
      const unsigned short* pbase = hb + ((((long)(y0 << 7) + x0) << 5) + cq * 8);
      u16x8 z = {0, 0, 0, 0, 0, 0, 0, 0};
      u16x8 v00 = (yi0 && xi0) ? *(const u16x8*)pbase          : z;
      u16x8 v01 = (yi0 && xi1) ? *(const u16x8*)(pbase + 32)   : z;
      u16x8 v10 = (yi1 && xi0) ? *(const u16x8*)(pbase + 4096) : z;
      u16x8 v11 = (yi1 && xi1) ? *(const u16x8*)(pbase + 4128) : z;
      u16x8 o;
      #pragma unroll
      for (int j = 0; j < 8; ++j) {
        float s = c00 * __uint_as_float((unsigned)(unsigned short)v00[j] << 16)
                + c01 * __uint_as_float((unsigned)(unsigned short)v01[j] << 16)
                + c10 * __uint_as_float((unsigned)(unsigned short)v10[j] << 16)
                + c11 * __uint_as_float((unsigned)(unsigned short)v11[j] << 16);
        o[j] = f2bf(s);
      }
      *(u16x8*)(&S[k][pix][cq * 8]) = o;
    }
    bf16x8 af0[9], af1[9];
    #pragma unroll
    for (int k = 0; k < 9; ++k) {
      long wbase = ((((long)(cg * 9 + k) * 4 + lhi) * 128) + w * 32 + lan15) * 8;
      af0[k] = *(const bf16x8*)(wdefA + wbase);
      af1[k] = *(const bf16x8*)(wdefA + wbase + 128);   // +16 oc
    }
    __syncthreads();
    #pragma unroll
    for (int k = 0; k < 9; ++k) {
      #pragma unroll
      for (int nt = 0; nt < 2; ++nt) {
        bf16x8 bfv = *(const bf16x8*)(&S[k][nt * 16 + lan15][lhi * 8]);
        acc[0][nt] = __builtin_amdgcn_mfma_f32_16x16x32_bf16(af0[k], bfv, acc[0][nt], 0, 0, 0);
        acc[1][nt] = __builtin_amdgcn_mfma_f32_16x16x32_bf16(af1[k], bfv, acc[1][nt], 0, 0, 0);
      }
    }
  }
  #pragma unroll
  for (int mt = 0; mt < 2; ++mt)
    #pragma unroll
    for (int reg = 0; reg < 4; ++reg) {
      int oc = w * 32 + mt * 16 + lhi * 4 + reg;
      long obase = ((long)(b * 128 + oc) << 14) + (h << 7) + w0;
      out[obase + lan15]      = acc[mt][0][reg];
      out[obase + 16 + lan15] = acc[mt][1][reg];
    }
}

// ---------------- K8: plain bn+relu (final output) --------------------------
__global__ void k_bnrelu(const float4* __restrict__ src, const float* __restrict__ mean,
                         const float* __restrict__ rstd, const float* __restrict__ g,
                         const float* __restrict__ be, float4* __restrict__ dst) {
  int i = blockIdx.x * 256 + threadIdx.x;   // over 1,048,576 float4
  if (i >= 1048576) return;
  int c = (i >> 12) & 127;
  float sc = rstd[c] * g[c];
  float bb = be[c] - mean[c] * sc;
  float4 v = src[i];
  v.x = fmaxf(v.x * sc + bb, 0.f);
  v.y = fmaxf(v.y * sc + bb, 0.f);
  v.z = fmaxf(v.z * sc + bb, 0.f);
  v.w = fmaxf(v.w * sc + bb, 0.f);
  dst[i] = v;
}

// ---------------- launcher --------------------------------------------------
extern "C" void kernel_launch(void* const* d_in, const int* in_sizes, int n_in,
                              void* d_out, int out_size, void* d_ws, size_t ws_size,
                              hipStream_t stream) {
  const float* x      = (const float*)d_in[0];
  const float* skip   = (const float*)d_in[1];
  const float* w_up   = (const float*)d_in[2];
  const float* b_up   = (const float*)d_in[3];
  const float* w_ref  = (const float*)d_in[4];
  const float* b_ref  = (const float*)d_in[5];
  const float* g1     = (const float*)d_in[6];
  const float* be1    = (const float*)d_in[7];
  const float* w_offh = (const float*)d_in[8];
  const float* b_offh = (const float*)d_in[9];
  const float* w_offv = (const float*)d_in[10];
  const float* b_offv = (const float*)d_in[11];
  const float* w_mask = (const float*)d_in[12];
  const float* b_mask = (const float*)d_in[13];
  const float* w_def  = (const float*)d_in[14];
  const float* g2     = (const float*)d_in[15];
  const float* be2    = (const float*)d_in[16];

  char* W = (char*)d_ws;
  unsigned short* catT  = (unsigned short*)W;                 // 16,777,216 B
  float*          tmp1  = (float*)(W + 16777216);             // 16 MB
  unsigned short* hbufT = (unsigned short*)(W + 33554432);    // 8,388,608 B
  float*          offb  = (float*)(W + 41943040);             // 2,359,296 B
  float*          mskb  = (float*)(W + 44302336);             // 1,179,648 B
  float*          stat  = (float*)(W + 45481984);             // 2,048 B
  unsigned short* wbT   = (unsigned short*)(W + 45484032);    // 589,824 B
  unsigned short* wOM   = (unsigned short*)(W + 46073856);    // 479,232 B
  unsigned short* wdefA = (unsigned short*)(W + 46553088);    // 294,912 B
  unsigned short* wupA  = (unsigned short*)(W + 46848000);    // 262,144 B
  float*          dpre  = (float*)W;                          // alias catT (dead)

  hipLaunchKernelGGL(k_wrefT, dim3(1152), dim3(256), 0, stream, w_ref, wbT);
  hipLaunchKernelGGL(k_womT, dim3(936), dim3(256), 0, stream, w_offh, w_offv, w_mask, wOM);
  hipLaunchKernelGGL(k_wdefA, dim3(576), dim3(256), 0, stream, w_def, wdefA);
  hipLaunchKernelGGL(k_wupA, dim3(512), dim3(256), 0, stream, w_up, wupA);
  hipLaunchKernelGGL(k_upsampleM, dim3(256), dim3(256), 0, stream, x, wupA, b_up, catT);
  hipLaunchKernelGGL(k_skipT, dim3(2048), dim3(256), 0, stream, skip, catT);
  hipLaunchKernelGGL(k_conv3w, dim3(256), dim3(512), 0, stream, catT, wbT, b_ref, tmp1);
  hipLaunchKernelGGL(k_bnstats, dim3(128), dim3(256), 0, stream, tmp1, stat, stat + 128);
  hipLaunchKernelGGL(k_bnrelu2, dim3(2048), dim3(256), 0, stream, tmp1, stat, stat + 128,
                     g1, be1, hbufT);
  hipLaunchKernelGGL(k_offmasks, dim3(512), dim3(256), 0, stream, hbufT, wOM,
                     b_offh, b_offv, b_mask, offb, mskb);
  hipLaunchKernelGGL(k_deformm, dim3(1024), dim3(256), 0, stream, hbufT, offb, mskb,
                     wdefA, dpre);
  hipLaunchKernelGGL(k_bnstats, dim3(128), dim3(256), 0, stream, dpre, stat + 256, stat + 384);
  hipLaunchKernelGGL(k_bnrelu, dim3(4096), dim3(256), 0, stream,
                     (const float4*)dpre, stat + 256, stat + 384, g2, be2, (float4*)d_out);
}